// Round 5
// baseline (993.853 us; speedup 1.0000x reference)
//
#include <hip/hip_runtime.h>
#include <hip/hip_bf16.h>
#include <math.h>

#define BATCH 2
#define SEQ   2048
#define EMB   2048
#define NH    16
#define HD    128

typedef __attribute__((ext_vector_type(8))) short short8;
typedef __attribute__((ext_vector_type(4))) float floatx4;

__device__ inline void async_load16(const void* g, void* l) {
    __builtin_amdgcn_global_load_lds(
        (const __attribute__((address_space(1))) unsigned int*)g,
        (__attribute__((address_space(3))) unsigned int*)l, 16, 0, 0);
}

__device__ inline unsigned short bf16_bits(float f) {
    __hip_bfloat16 b = __float2bfloat16(f);
    return *(unsigned short*)&b;
}
__device__ inline void split_bf16(float f, unsigned short& h, unsigned short& l) {
    __hip_bfloat16 hb = __float2bfloat16(f);
    h = *(unsigned short*)&hb;
    float r = f - __bfloat162float(hb);
    __hip_bfloat16 lb = __float2bfloat16(r);
    l = *(unsigned short*)&lb;
}

// ======================= plain bf16 MFMA GEMM (m97 structure) =======================
#define GT 128
#define GK 32

__global__ __launch_bounds__(256) void gemm_bf16(
    const unsigned short* __restrict__ A,
    const unsigned short* __restrict__ Bt,
    float* __restrict__ C, int M, int N, int K)
{
    __shared__ unsigned short As[GT * GK];
    __shared__ unsigned short Bs[GT * GK];

    const int tid  = threadIdx.x;
    const int w    = tid >> 6;
    const int lane = tid & 63;
    const int wr   = w >> 1, wc = w & 1;
    const int row0 = blockIdx.y * GT;
    const int col0 = blockIdx.x * GT;

    floatx4 acc[4][4];
    #pragma unroll
    for (int i = 0; i < 4; i++)
        #pragma unroll
        for (int j = 0; j < 4; j++)
            acc[i][j] = (floatx4){0.f, 0.f, 0.f, 0.f};

    const int srow  = lane >> 2;
    const int skoff = (lane & 3) * 8;
    const int fm = lane & 15;
    const int fk = (lane >> 4) * 8;

    for (int k0 = 0; k0 < K; k0 += GK) {
        #pragma unroll
        for (int t = 0; t < 2; t++) {
            const int c = w * 2 + t;
            async_load16(A  + (size_t)(row0 + c * 16 + srow) * K + k0 + skoff, (char*)As + c * 1024);
            async_load16(Bt + (size_t)(col0 + c * 16 + srow) * K + k0 + skoff, (char*)Bs + c * 1024);
        }
        __syncthreads();

        short8 af[4], bf[4];
        #pragma unroll
        for (int i = 0; i < 4; i++) {
            af[i] = *(const short8*)&As[(wr * 64 + i * 16 + fm) * GK + fk];
            bf[i] = *(const short8*)&Bs[(wc * 64 + i * 16 + fm) * GK + fk];
        }
        #pragma unroll
        for (int i = 0; i < 4; i++)
            #pragma unroll
            for (int j = 0; j < 4; j++)
                acc[i][j] = __builtin_amdgcn_mfma_f32_16x16x32_bf16(af[i], bf[j], acc[i][j], 0, 0, 0);
        __syncthreads();
    }

    const int quad = lane >> 4;
    #pragma unroll
    for (int i = 0; i < 4; i++)
        #pragma unroll
        for (int j = 0; j < 4; j++) {
            const size_t base = (size_t)(row0 + wr * 64 + i * 16 + quad * 4) * N
                              + col0 + wc * 64 + j * 16 + fm;
            #pragma unroll
            for (int r = 0; r < 4; r++)
                C[base + (size_t)r * N] = acc[i][j][r];
        }
}

// ======================= split (hi/lo) bf16 MFMA GEMM =======================
__global__ __launch_bounds__(256) void gemm_bf16_split(
    const unsigned short* __restrict__ Ah, const unsigned short* __restrict__ Al,
    const unsigned short* __restrict__ Bh, const unsigned short* __restrict__ Bl,
    float* __restrict__ C, int M, int N, int K)
{
    __shared__ unsigned short AsH[GT * GK], AsL[GT * GK];
    __shared__ unsigned short BsH[GT * GK], BsL[GT * GK];

    const int tid  = threadIdx.x;
    const int w    = tid >> 6;
    const int lane = tid & 63;
    const int wr   = w >> 1, wc = w & 1;
    const int row0 = blockIdx.y * GT;
    const int col0 = blockIdx.x * GT;

    floatx4 acc[4][4];
    #pragma unroll
    for (int i = 0; i < 4; i++)
        #pragma unroll
        for (int j = 0; j < 4; j++)
            acc[i][j] = (floatx4){0.f, 0.f, 0.f, 0.f};

    const int srow  = lane >> 2;
    const int skoff = (lane & 3) * 8;
    const int fm = lane & 15;
    const int fk = (lane >> 4) * 8;

    for (int k0 = 0; k0 < K; k0 += GK) {
        #pragma unroll
        for (int t = 0; t < 2; t++) {
            const int c = w * 2 + t;
            const size_t ao = (size_t)(row0 + c * 16 + srow) * K + k0 + skoff;
            const size_t bo = (size_t)(col0 + c * 16 + srow) * K + k0 + skoff;
            async_load16(Ah + ao, (char*)AsH + c * 1024);
            async_load16(Al + ao, (char*)AsL + c * 1024);
            async_load16(Bh + bo, (char*)BsH + c * 1024);
            async_load16(Bl + bo, (char*)BsL + c * 1024);
        }
        __syncthreads();

        short8 afh[4], afl[4], bfh[4], bfl[4];
        #pragma unroll
        for (int i = 0; i < 4; i++) {
            const int arow = (wr * 64 + i * 16 + fm) * GK + fk;
            const int brow = (wc * 64 + i * 16 + fm) * GK + fk;
            afh[i] = *(const short8*)&AsH[arow];
            afl[i] = *(const short8*)&AsL[arow];
            bfh[i] = *(const short8*)&BsH[brow];
            bfl[i] = *(const short8*)&BsL[brow];
        }
        #pragma unroll
        for (int i = 0; i < 4; i++)
            #pragma unroll
            for (int j = 0; j < 4; j++) {
                acc[i][j] = __builtin_amdgcn_mfma_f32_16x16x32_bf16(afh[i], bfh[j], acc[i][j], 0, 0, 0);
                acc[i][j] = __builtin_amdgcn_mfma_f32_16x16x32_bf16(afh[i], bfl[j], acc[i][j], 0, 0, 0);
                acc[i][j] = __builtin_amdgcn_mfma_f32_16x16x32_bf16(afl[i], bfh[j], acc[i][j], 0, 0, 0);
            }
        __syncthreads();
    }

    const int quad = lane >> 4;
    #pragma unroll
    for (int i = 0; i < 4; i++)
        #pragma unroll
        for (int j = 0; j < 4; j++) {
            const size_t base = (size_t)(row0 + wr * 64 + i * 16 + quad * 4) * N
                              + col0 + wc * 64 + j * 16 + fm;
            #pragma unroll
            for (int r = 0; r < 4; r++)
                C[base + (size_t)r * N] = acc[i][j][r];
        }
}

// ======================= casts / weight prep =======================
__global__ __launch_bounds__(256) void cast_split_f32(
    const float* __restrict__ in, unsigned short* __restrict__ hi,
    unsigned short* __restrict__ lo, int n)
{
    int i = (blockIdx.x * 256 + threadIdx.x) * 4;
    if (i >= n) return;
    float4 v = *(const float4*)&in[i];
    ushort4 h, l;
    split_bf16(v.x, h.x, l.x);
    split_bf16(v.y, h.y, l.y);
    split_bf16(v.z, h.z, l.z);
    split_bf16(v.w, h.w, l.w);
    *(ushort4*)&hi[i] = h;
    *(ushort4*)&lo[i] = l;
}

__global__ __launch_bounds__(256) void transpose_cast(
    const float* __restrict__ W, unsigned short* __restrict__ Wt, int K, int N)
{
    __shared__ float tile[32][33];
    const int k0 = blockIdx.y * 32, n0 = blockIdx.x * 32;
    const int tx = threadIdx.x, ty = threadIdx.y;
    #pragma unroll
    for (int i = 0; i < 4; i++)
        tile[ty + i * 8][tx] = W[(size_t)(k0 + ty + i * 8) * N + n0 + tx];
    __syncthreads();
    #pragma unroll
    for (int i = 0; i < 4; i++)
        Wt[(size_t)(n0 + ty + i * 8) * K + k0 + tx] = bf16_bits(tile[tx][ty + i * 8]);
}

__global__ __launch_bounds__(256) void transpose_cast_split(
    const float* __restrict__ W, unsigned short* __restrict__ WtH,
    unsigned short* __restrict__ WtL, int K, int N)
{
    __shared__ float tile[32][33];
    const int k0 = blockIdx.y * 32, n0 = blockIdx.x * 32;
    const int tx = threadIdx.x, ty = threadIdx.y;
    #pragma unroll
    for (int i = 0; i < 4; i++)
        tile[ty + i * 8][tx] = W[(size_t)(k0 + ty + i * 8) * N + n0 + tx];
    __syncthreads();
    #pragma unroll
    for (int i = 0; i < 4; i++) {
        unsigned short h, l;
        split_bf16(tile[tx][ty + i * 8], h, l);
        size_t idx = (size_t)(n0 + ty + i * 8) * K + k0 + tx;
        WtH[idx] = h;
        WtL[idx] = l;
    }
}

// ======================= prep_qk: rmsnorm + split + head-major relayout =======================
__global__ __launch_bounds__(256) void prep_qk(
    const float* __restrict__ in, const float* __restrict__ scale,
    unsigned short* __restrict__ hi, unsigned short* __restrict__ lo, int swz)
{
    __shared__ float ws4[4];
    const int r = blockIdx.x * 2 + (threadIdx.x >> 7);
    const int d = threadIdx.x & 127;
    const int b = r >> 15;
    const int s = (r >> 4) & 2047;
    const int h = r & 15;
    const float v = in[(size_t)r * 128 + d];
    float ss = v * v;
    #pragma unroll
    for (int off = 1; off < 64; off <<= 1) ss += __shfl_xor(ss, off, 64);
    if ((threadIdx.x & 63) == 0) ws4[threadIdx.x >> 6] = ss;
    __syncthreads();
    const int g = (threadIdx.x >> 7) << 1;
    const float inv = rsqrtf((ws4[g] + ws4[g + 1]) * (1.0f / HD) + 1e-6f);
    const float val = v * inv * scale[d];
    unsigned short hb, lb;
    split_bf16(val, hb, lb);
    const int dd = swz ? (((((d >> 3) ^ (s & 15))) << 3) | (d & 7)) : d;
    const size_t o = ((size_t)(b * NH + h) * SEQ + s) * 128 + dd;
    hi[o] = hb;
    lo[o] = lb;
}

// ======================= prep_v =======================
__global__ __launch_bounds__(256) void prep_v(
    const float* __restrict__ v, unsigned short* __restrict__ Vt)
{
    __shared__ unsigned short T[128][72];
    const int bh = blockIdx.y, ktile = blockIdx.x;
    const int b = bh >> 4, h = bh & 15;
    const int key = threadIdx.x >> 2, dg = threadIdx.x & 3;
    const size_t vrow = ((size_t)(b * SEQ + ktile * 64 + key) * NH + h) * 128;
    #pragma unroll
    for (int i2 = 0; i2 < 8; i2++) {
        const int d0 = dg * 4 + i2 * 16;
        float4 x = *(const float4*)&v[vrow + d0];
        T[d0 + 0][key] = bf16_bits(x.x);
        T[d0 + 1][key] = bf16_bits(x.y);
        T[d0 + 2][key] = bf16_bits(x.z);
        T[d0 + 3][key] = bf16_bits(x.w);
    }
    __syncthreads();
    const int d = threadIdx.x >> 1, half = threadIdx.x & 1;
    const size_t obase = ((size_t)bh * 32 + ktile) * 8192 + (size_t)d * 64;
    #pragma unroll
    for (int cc = 0; cc < 4; cc++) {
        const int cs = half * 4 + cc;
        const int kb = (cs ^ (d & 7)) << 3;
        short8 val = *(const short8*)&T[d][kb];
        *(short8*)&Vt[obase + cs * 8] = val;
    }
}

// ======================= MFMA flash attention v9 =======================
// EXACT v4 structure (512 threads = 8 waves, ATQ=256/32 rows per wave, ATK=64,
// double-buffered KV staging, ONE barrier per tile, grid (8,32) = 256 blocks,
// LDS 128 KB -> 1 block/CU) + two validated zero-memory-impact grafts:
//   T5: s_setprio(1) around QK and PV MFMA clusters
//   T13: defer-max (skip alpha/rescale when __all(mx <= m_old + 8))
#define ATQ 256
#define ATK 64

__global__ __launch_bounds__(512, 1) void attn9(
    const unsigned short* __restrict__ Qh, const unsigned short* __restrict__ Ql,
    const unsigned short* __restrict__ Kh, const unsigned short* __restrict__ Kl,
    const unsigned short* __restrict__ Vt, __hip_bfloat16* __restrict__ AO)
{
    __shared__ unsigned short KsH[2][ATK * 128];   // 32 KB  [key][d'] (chunk ^= key&15)
    __shared__ unsigned short KsL[2][ATK * 128];   // 32 KB
    __shared__ unsigned short Vts[2][HD * 64];     // 32 KB  [d][key'] (chunk ^= d&7)
    __shared__ unsigned short Ps[ATQ * 64];        // 32 KB  P[row][key'] (chunk ^= row&7)

    const int tid  = threadIdx.x;
    const int w    = tid >> 6;        // 0..7
    const int lane = tid & 63;
    const int quad = lane >> 4;
    const int fm   = lane & 15;
    const int bh = blockIdx.y;
    const int b = bh >> 4, h = bh & 15;
    const int q0 = blockIdx.x * ATQ;

    const size_t hbase = (size_t)(b * NH + h) * SEQ;

    // ---- Q fragments (pre-split bf16); wave owns rows w*32..w*32+31 ----
    short8 qh[2][4], ql[2][4];
    #pragma unroll
    for (int i = 0; i < 2; i++) {
        const size_t row = hbase + q0 + w * 32 + i * 16 + fm;
        #pragma unroll
        for (int kc = 0; kc < 4; kc++) {
            const size_t off = row * 128 + kc * 32 + quad * 8;
            qh[i][kc] = *(const short8*)&Qh[off];
            ql[i][kc] = *(const short8*)&Ql[off];
        }
    }

    floatx4 oacc[2][8];
    #pragma unroll
    for (int i = 0; i < 2; i++)
        #pragma unroll
        for (int df = 0; df < 8; df++)
            oacc[i][df] = (floatx4){0.f, 0.f, 0.f, 0.f};
    float m_[2][4], l_[2][4];
    #pragma unroll
    for (int i = 0; i < 2; i++)
        #pragma unroll
        for (int r = 0; r < 4; r++) { m_[i][r] = -1e30f; l_[i][r] = 0.f; }

    const unsigned short* gkh0 = Kh + hbase * 128;
    const unsigned short* gkl0 = Kl + hbase * 128;
    const unsigned short* gvt0 = Vt + (size_t)bh * 32 * 8192;

    // staging: 48 chunks of 1 KB (KsH 16, KsL 16, Vts 16); wave w -> chunks w*6..w*6+5
    const int ch0 = w * 6;

    // ---- prologue: stage tile 0 into buffer 0 ----
    #pragma unroll
    for (int c = 0; c < 6; c++) {
        const int ch = ch0 + c;
        const size_t go = (size_t)(ch & 15) * 512 + lane * 8;
        if (ch < 16)      async_load16(gkh0 + go, (char*)KsH[0] + ch * 1024);
        else if (ch < 32) async_load16(gkl0 + go, (char*)KsL[0] + (ch - 16) * 1024);
        else              async_load16(gvt0 + go, (char*)Vts[0] + (ch - 32) * 1024);
    }
    __syncthreads();   // drain: tile 0 staged

    for (int ktile = 0; ktile < SEQ / ATK; ktile++) {
        const int cur = ktile & 1;

        // ---- prefetch tile t+1 into other buffer (drained by end-of-tile barrier) ----
        if (ktile + 1 < SEQ / ATK) {
            const unsigned short* gkh = gkh0 + (size_t)(ktile + 1) * ATK * 128;
            const unsigned short* gkl = gkl0 + (size_t)(ktile + 1) * ATK * 128;
            const unsigned short* gvt = gvt0 + (size_t)(ktile + 1) * 8192;
            #pragma unroll
            for (int c = 0; c < 6; c++) {
                const int ch = ch0 + c;
                const size_t go = (size_t)(ch & 15) * 512 + lane * 8;
                if (ch < 16)      async_load16(gkh + go, (char*)KsH[1 - cur] + ch * 1024);
                else if (ch < 32) async_load16(gkl + go, (char*)KsL[1 - cur] + (ch - 16) * 1024);
                else              async_load16(gvt + go, (char*)Vts[1 - cur] + (ch - 32) * 1024);
            }
        }

        // ---- S = Q K^T (3-term hi/lo) from buffer cur ----
        floatx4 sacc[2][4];
        #pragma unroll
        for (int i = 0; i < 2; i++)
            #pragma unroll
            for (int jf = 0; jf < 4; jf++)
                sacc[i][jf] = (floatx4){0.f, 0.f, 0.f, 0.f};
        __builtin_amdgcn_s_setprio(1);
        #pragma unroll
        for (int kc = 0; kc < 4; kc++)
            #pragma unroll
            for (int jf = 0; jf < 4; jf++) {
                const int koff = (jf * 16 + fm) * 128 + (((kc * 4 + quad) ^ fm) << 3);
                short8 kh8 = *(const short8*)&KsH[cur][koff];
                short8 kl8 = *(const short8*)&KsL[cur][koff];
                #pragma unroll
                for (int i = 0; i < 2; i++) {
                    sacc[i][jf] = __builtin_amdgcn_mfma_f32_16x16x32_bf16(qh[i][kc], kh8, sacc[i][jf], 0, 0, 0);
                    sacc[i][jf] = __builtin_amdgcn_mfma_f32_16x16x32_bf16(qh[i][kc], kl8, sacc[i][jf], 0, 0, 0);
                    sacc[i][jf] = __builtin_amdgcn_mfma_f32_16x16x32_bf16(ql[i][kc], kh8, sacc[i][jf], 0, 0, 0);
                }
            }
        __builtin_amdgcn_s_setprio(0);

        // ---- online softmax (registers) with defer-max (THR=8) ----
        #pragma unroll
        for (int i = 0; i < 2; i++)
            #pragma unroll
            for (int r = 0; r < 4; r++) {
                float mx = fmaxf(fmaxf(sacc[i][0][r], sacc[i][1][r]),
                                 fmaxf(sacc[i][2][r], sacc[i][3][r]));
                mx = fmaxf(mx, __shfl_xor(mx, 1, 64));
                mx = fmaxf(mx, __shfl_xor(mx, 2, 64));
                mx = fmaxf(mx, __shfl_xor(mx, 4, 64));
                mx = fmaxf(mx, __shfl_xor(mx, 8, 64));
                const float mold = m_[i][r];
                if (__all(mx <= mold + 8.0f)) {
                    // defer: keep m_old, skip alpha + O-rescale; P bounded by e^8
                    float rs = 0.f;
                    #pragma unroll
                    for (int jf = 0; jf < 4; jf++) {
                        float p = __expf(sacc[i][jf][r] - mold);
                        sacc[i][jf][r] = p;
                        rs += p;
                    }
                    rs += __shfl_xor(rs, 1, 64);
                    rs += __shfl_xor(rs, 2, 64);
                    rs += __shfl_xor(rs, 4, 64);
                    rs += __shfl_xor(rs, 8, 64);
                    l_[i][r] += rs;
                } else {
                    const float mnew = fmaxf(mold, mx);
                    const float al = __expf(mold - mnew);
                    m_[i][r] = mnew;
                    float rs = 0.f;
                    #pragma unroll
                    for (int jf = 0; jf < 4; jf++) {
                        float p = __expf(sacc[i][jf][r] - mnew);
                        sacc[i][jf][r] = p;
                        rs += p;
                    }
                    rs += __shfl_xor(rs, 1, 64);
                    rs += __shfl_xor(rs, 2, 64);
                    rs += __shfl_xor(rs, 4, 64);
                    rs += __shfl_xor(rs, 8, 64);
                    l_[i][r] = l_[i][r] * al + rs;
                    #pragma unroll
                    for (int df = 0; df < 8; df++)
                        oacc[i][df][r] *= al;
                }
            }

        // ---- P -> bf16 into Ps (own rows; wave-local ordering, no barrier) ----
        #pragma unroll
        for (int i = 0; i < 2; i++)
            #pragma unroll
            for (int jf = 0; jf < 4; jf++)
                #pragma unroll
                for (int r = 0; r < 4; r++) {
                    const int row = w * 32 + i * 16 + quad * 4 + r;
                    const int chunk = jf * 2 + (fm >> 3);
                    const int colp = ((chunk ^ (row & 7)) << 3) | (fm & 7);
                    Ps[row * 64 + colp] = bf16_bits(sacc[i][jf][r]);
                }

        // ---- O += P V from buffer cur ----
        __builtin_amdgcn_s_setprio(1);
        #pragma unroll
        for (int kc2 = 0; kc2 < 2; kc2++) {
            short8 ap[2];
            #pragma unroll
            for (int i = 0; i < 2; i++) {
                const int row = w * 32 + i * 16 + fm;
                ap[i] = *(const short8*)&Ps[row * 64 + (((kc2 * 4 + quad) ^ (row & 7)) << 3)];
            }
            #pragma unroll
            for (int df = 0; df < 8; df++) {
                const int d = df * 16 + fm;
                short8 bv = *(const short8*)&Vts[cur][d * 64 + (((kc2 * 4 + quad) ^ (d & 7)) << 3)];
                #pragma unroll
                for (int i = 0; i < 2; i++)
                    oacc[i][df] = __builtin_amdgcn_mfma_f32_16x16x32_bf16(ap[i], bv, oacc[i][df], 0, 0, 0);
            }
        }
        __builtin_amdgcn_s_setprio(0);

        // single barrier per tile: drains prefetch + protects buffer swap
        __syncthreads();
    }

    // ---- epilogue: AO bf16 [b,s,h,d] ----
    const size_t obase = ((size_t)b * SEQ * NH + h) * HD;
    const size_t rstr = (size_t)NH * HD;
    float linv[2][4];
    #pragma unroll
    for (int i = 0; i < 2; i++)
        #pragma unroll
        for (int r = 0; r < 4; r++) linv[i][r] = 1.0f / l_[i][r];
    #pragma unroll
    for (int i = 0; i < 2; i++)
        #pragma unroll
        for (int df = 0; df < 8; df++)
            #pragma unroll
            for (int r = 0; r < 4; r++) {
                const int row = q0 + w * 32 + i * 16 + quad * 4 + r;
                const int d = df * 16 + fm;
                AO[obase + (size_t)row * rstr + d] = __float2bfloat16(oacc[i][df][r] * linv[i][r]);
            }
}

// ======================= launch =======================
extern "C" void kernel_launch(void* const* d_in, const int* in_sizes, int n_in,
                              void* d_out, int out_size, void* d_ws, size_t ws_size,
                              hipStream_t stream) {
    const float* x  = (const float*)d_in[0];
    const float* wq = (const float*)d_in[1];
    const float* wk = (const float*)d_in[2];
    const float* wv = (const float*)d_in[3];
    const float* wo = (const float*)d_in[4];
    const float* q_scale = (const float*)d_in[5];
    const float* k_scale = (const float*)d_in[6];
    float* out = (float*)d_out;

    const size_t T = (size_t)BATCH * SEQ * NH * HD;   // 8388608
    const size_t W = (size_t)EMB * NH * HD;           // 4194304

    float* q = (float*)d_ws;                          // fp32 [b,s,h,d]
    float* k = q + T;
    float* v = k + T;
    unsigned short* xh   = (unsigned short*)(v + T);  // reused as Qh after GEMMs
    unsigned short* xl   = xh + T;                    // reused as Ql
    unsigned short* aob  = xl + T;
    unsigned short* Kh   = aob + T;
    unsigned short* Kl   = Kh + T;
    unsigned short* Vtb  = Kl + T;
    unsigned short* wqTh = Vtb + T;
    unsigned short* wqTl = wqTh + W;
    unsigned short* wkTh = wqTl + W;
    unsigned short* wkTl = wkTh + W;
    unsigned short* wvT  = wkTl + W;
    unsigned short* woT  = wvT + W;

    const int M = BATCH * SEQ;   // 4096
    const int N = NH * HD;       // 2048
    const int K = EMB;           // 2048

    cast_split_f32<<<(int)(T / 4 + 255) / 256, 256, 0, stream>>>(x, xh, xl, (int)T);
    dim3 tblk(32, 8);
    transpose_cast_split<<<dim3(N / 32, K / 32), tblk, 0, stream>>>(wq, wqTh, wqTl, K, N);
    transpose_cast_split<<<dim3(N / 32, K / 32), tblk, 0, stream>>>(wk, wkTh, wkTl, K, N);
    transpose_cast<<<dim3(N / 32, K / 32), tblk, 0, stream>>>(wv, wvT, K, N);
    transpose_cast<<<dim3(EMB / 32, (NH * HD) / 32), tblk, 0, stream>>>(wo, woT, NH * HD, EMB);

    dim3 ggrid(N / GT, M / GT);
    gemm_bf16_split<<<ggrid, 256, 0, stream>>>(xh, xl, wqTh, wqTl, q, M, N, K);
    gemm_bf16_split<<<ggrid, 256, 0, stream>>>(xh, xl, wkTh, wkTl, k, M, N, K);
    gemm_bf16<<<ggrid, 256, 0, stream>>>(xh, wvT, v, M, N, K);

    unsigned short* Qh = xh;
    unsigned short* Ql = xl;
    prep_qk<<<(int)(T / 128 / 2), 256, 0, stream>>>(q, q_scale, Qh, Ql, 0);
    prep_qk<<<(int)(T / 128 / 2), 256, 0, stream>>>(k, k_scale, Kh, Kl, 1);
    prep_v<<<dim3(SEQ / ATK, BATCH * NH), 256, 0, stream>>>(v, Vtb);

    attn9<<<dim3(SEQ / ATQ, BATCH * NH), 512, 0, stream>>>(Qh, Ql, Kh, Kl, Vtb, (__hip_bfloat16*)aob);

    gemm_bf16<<<dim3(EMB / GT, M / GT), 256, 0, stream>>>(aob, woT, out, M, EMB, NH * HD);
}

// Round 6
// 821.757 us; speedup vs baseline: 1.2094x; 1.2094x over previous
//
#include <hip/hip_runtime.h>
#include <hip/hip_bf16.h>
#include <math.h>

#define BATCH 2
#define SEQ   2048
#define EMB   2048
#define NH    16
#define HD    128

typedef __attribute__((ext_vector_type(8))) short short8;
typedef __attribute__((ext_vector_type(4))) float floatx4;

__device__ inline void async_load16(const void* g, void* l) {
    __builtin_amdgcn_global_load_lds(
        (const __attribute__((address_space(1))) unsigned int*)g,
        (__attribute__((address_space(3))) unsigned int*)l, 16, 0, 0);
}

__device__ inline unsigned short bf16_bits(float f) {
    __hip_bfloat16 b = __float2bfloat16(f);
    return *(unsigned short*)&b;
}
__device__ inline void split_bf16(float f, unsigned short& h, unsigned short& l) {
    __hip_bfloat16 hb = __float2bfloat16(f);
    h = *(unsigned short*)&hb;
    float r = f - __bfloat162float(hb);
    __hip_bfloat16 lb = __float2bfloat16(r);
    l = *(unsigned short*)&lb;
}

// ======================= plain bf16 MFMA GEMM (m97 structure) =======================
#define GT 128
#define GK 32

__global__ __launch_bounds__(256) void gemm_bf16(
    const unsigned short* __restrict__ A,
    const unsigned short* __restrict__ Bt,
    float* __restrict__ C, int M, int N, int K)
{
    __shared__ unsigned short As[GT * GK];
    __shared__ unsigned short Bs[GT * GK];

    const int tid  = threadIdx.x;
    const int w    = tid >> 6;
    const int lane = tid & 63;
    const int wr   = w >> 1, wc = w & 1;
    const int row0 = blockIdx.y * GT;
    const int col0 = blockIdx.x * GT;

    floatx4 acc[4][4];
    #pragma unroll
    for (int i = 0; i < 4; i++)
        #pragma unroll
        for (int j = 0; j < 4; j++)
            acc[i][j] = (floatx4){0.f, 0.f, 0.f, 0.f};

    const int srow  = lane >> 2;
    const int skoff = (lane & 3) * 8;
    const int fm = lane & 15;
    const int fk = (lane >> 4) * 8;

    for (int k0 = 0; k0 < K; k0 += GK) {
        #pragma unroll
        for (int t = 0; t < 2; t++) {
            const int c = w * 2 + t;
            async_load16(A  + (size_t)(row0 + c * 16 + srow) * K + k0 + skoff, (char*)As + c * 1024);
            async_load16(Bt + (size_t)(col0 + c * 16 + srow) * K + k0 + skoff, (char*)Bs + c * 1024);
        }
        __syncthreads();

        short8 af[4], bf[4];
        #pragma unroll
        for (int i = 0; i < 4; i++) {
            af[i] = *(const short8*)&As[(wr * 64 + i * 16 + fm) * GK + fk];
            bf[i] = *(const short8*)&Bs[(wc * 64 + i * 16 + fm) * GK + fk];
        }
        #pragma unroll
        for (int i = 0; i < 4; i++)
            #pragma unroll
            for (int j = 0; j < 4; j++)
                acc[i][j] = __builtin_amdgcn_mfma_f32_16x16x32_bf16(af[i], bf[j], acc[i][j], 0, 0, 0);
        __syncthreads();
    }

    const int quad = lane >> 4;
    #pragma unroll
    for (int i = 0; i < 4; i++)
        #pragma unroll
        for (int j = 0; j < 4; j++) {
            const size_t base = (size_t)(row0 + wr * 64 + i * 16 + quad * 4) * N
                              + col0 + wc * 64 + j * 16 + fm;
            #pragma unroll
            for (int r = 0; r < 4; r++)
                C[base + (size_t)r * N] = acc[i][j][r];
        }
}

// ======================= fused Q+K split (hi/lo) GEMM =======================
// 512 threads = 8 waves. Waves 0-3 compute the q-tile, waves 4-7 the k-tile,
// sharing ONE staged A (Ah/Al) per K-step. Staging: 48 x 1KB chunks -> 6/wave.
// LDS 48 KB. Same 2-barrier-per-K-step schedule as the proven split kernel.
__global__ __launch_bounds__(512) void gemm_qk_split(
    const unsigned short* __restrict__ Ah, const unsigned short* __restrict__ Al,
    const unsigned short* __restrict__ BqH, const unsigned short* __restrict__ BqL,
    const unsigned short* __restrict__ BkH, const unsigned short* __restrict__ BkL,
    float* __restrict__ Cq, float* __restrict__ Ck, int M, int N, int K)
{
    __shared__ unsigned short AsH[GT * GK], AsL[GT * GK];
    __shared__ unsigned short BsQH[GT * GK], BsQL[GT * GK];
    __shared__ unsigned short BsKH[GT * GK], BsKL[GT * GK];

    const int tid  = threadIdx.x;
    const int w    = tid >> 6;          // 0..7
    const int lane = tid & 63;
    const int half = w >> 2;            // 0 = q, 1 = k
    const int wr   = (w >> 1) & 1, wc = w & 1;
    const int row0 = blockIdx.y * GT;
    const int col0 = blockIdx.x * GT;

    floatx4 acc[4][4];
    #pragma unroll
    for (int i = 0; i < 4; i++)
        #pragma unroll
        for (int j = 0; j < 4; j++)
            acc[i][j] = (floatx4){0.f, 0.f, 0.f, 0.f};

    const int srow  = lane >> 2;
    const int skoff = (lane & 3) * 8;
    const int fm = lane & 15;
    const int fk = (lane >> 4) * 8;

    for (int k0 = 0; k0 < K; k0 += GK) {
        #pragma unroll
        for (int c = 0; c < 6; c++) {
            const int ch  = w * 6 + c;          // 0..47
            const int sub = ch & 7;             // chunk within buffer
            const size_t aoff = (size_t)(row0 + sub * 16 + srow) * K + k0 + skoff;
            const size_t boff = (size_t)(col0 + sub * 16 + srow) * K + k0 + skoff;
            switch (ch >> 3) {
                case 0: async_load16(Ah  + aoff, (char*)AsH  + sub * 1024); break;
                case 1: async_load16(Al  + aoff, (char*)AsL  + sub * 1024); break;
                case 2: async_load16(BqH + boff, (char*)BsQH + sub * 1024); break;
                case 3: async_load16(BqL + boff, (char*)BsQL + sub * 1024); break;
                case 4: async_load16(BkH + boff, (char*)BsKH + sub * 1024); break;
                default: async_load16(BkL + boff, (char*)BsKL + sub * 1024); break;
            }
        }
        __syncthreads();

        short8 afh[4], afl[4], bfh[4], bfl[4];
        #pragma unroll
        for (int i = 0; i < 4; i++) {
            const int arow = (wr * 64 + i * 16 + fm) * GK + fk;
            const int brow = (wc * 64 + i * 16 + fm) * GK + fk;
            afh[i] = *(const short8*)&AsH[arow];
            afl[i] = *(const short8*)&AsL[arow];
            if (half == 0) {
                bfh[i] = *(const short8*)&BsQH[brow];
                bfl[i] = *(const short8*)&BsQL[brow];
            } else {
                bfh[i] = *(const short8*)&BsKH[brow];
                bfl[i] = *(const short8*)&BsKL[brow];
            }
        }
        #pragma unroll
        for (int i = 0; i < 4; i++)
            #pragma unroll
            for (int j = 0; j < 4; j++) {
                acc[i][j] = __builtin_amdgcn_mfma_f32_16x16x32_bf16(afh[i], bfh[j], acc[i][j], 0, 0, 0);
                acc[i][j] = __builtin_amdgcn_mfma_f32_16x16x32_bf16(afh[i], bfl[j], acc[i][j], 0, 0, 0);
                acc[i][j] = __builtin_amdgcn_mfma_f32_16x16x32_bf16(afl[i], bfh[j], acc[i][j], 0, 0, 0);
            }
        __syncthreads();
    }

    float* __restrict__ C = half ? Ck : Cq;
    const int quad = lane >> 4;
    #pragma unroll
    for (int i = 0; i < 4; i++)
        #pragma unroll
        for (int j = 0; j < 4; j++) {
            const size_t base = (size_t)(row0 + wr * 64 + i * 16 + quad * 4) * N
                              + col0 + wc * 64 + j * 16 + fm;
            #pragma unroll
            for (int r = 0; r < 4; r++)
                C[base + (size_t)r * N] = acc[i][j][r];
        }
}

// ======================= casts / weight prep =======================
__global__ __launch_bounds__(256) void cast_split_f32(
    const float* __restrict__ in, unsigned short* __restrict__ hi,
    unsigned short* __restrict__ lo, int n)
{
    int i = (blockIdx.x * 256 + threadIdx.x) * 4;
    if (i >= n) return;
    float4 v = *(const float4*)&in[i];
    ushort4 h, l;
    split_bf16(v.x, h.x, l.x);
    split_bf16(v.y, h.y, l.y);
    split_bf16(v.z, h.z, l.z);
    split_bf16(v.w, h.w, l.w);
    *(ushort4*)&hi[i] = h;
    *(ushort4*)&lo[i] = l;
}

__global__ __launch_bounds__(256) void transpose_cast(
    const float* __restrict__ W, unsigned short* __restrict__ Wt, int K, int N)
{
    __shared__ float tile[32][33];
    const int k0 = blockIdx.y * 32, n0 = blockIdx.x * 32;
    const int tx = threadIdx.x, ty = threadIdx.y;
    #pragma unroll
    for (int i = 0; i < 4; i++)
        tile[ty + i * 8][tx] = W[(size_t)(k0 + ty + i * 8) * N + n0 + tx];
    __syncthreads();
    #pragma unroll
    for (int i = 0; i < 4; i++)
        Wt[(size_t)(n0 + ty + i * 8) * K + k0 + tx] = bf16_bits(tile[tx][ty + i * 8]);
}

__global__ __launch_bounds__(256) void transpose_cast_split(
    const float* __restrict__ W, unsigned short* __restrict__ WtH,
    unsigned short* __restrict__ WtL, int K, int N)
{
    __shared__ float tile[32][33];
    const int k0 = blockIdx.y * 32, n0 = blockIdx.x * 32;
    const int tx = threadIdx.x, ty = threadIdx.y;
    #pragma unroll
    for (int i = 0; i < 4; i++)
        tile[ty + i * 8][tx] = W[(size_t)(k0 + ty + i * 8) * N + n0 + tx];
    __syncthreads();
    #pragma unroll
    for (int i = 0; i < 4; i++) {
        unsigned short h, l;
        split_bf16(tile[tx][ty + i * 8], h, l);
        size_t idx = (size_t)(n0 + ty + i * 8) * K + k0 + tx;
        WtH[idx] = h;
        WtL[idx] = l;
    }
}

// ======================= prep_qk: rmsnorm + split + head-major relayout =======================
__global__ __launch_bounds__(256) void prep_qk(
    const float* __restrict__ in, const float* __restrict__ scale,
    unsigned short* __restrict__ hi, unsigned short* __restrict__ lo, int swz)
{
    __shared__ float ws4[4];
    const int r = blockIdx.x * 2 + (threadIdx.x >> 7);
    const int d = threadIdx.x & 127;
    const int b = r >> 15;
    const int s = (r >> 4) & 2047;
    const int h = r & 15;
    const float v = in[(size_t)r * 128 + d];
    float ss = v * v;
    #pragma unroll
    for (int off = 1; off < 64; off <<= 1) ss += __shfl_xor(ss, off, 64);
    if ((threadIdx.x & 63) == 0) ws4[threadIdx.x >> 6] = ss;
    __syncthreads();
    const int g = (threadIdx.x >> 7) << 1;
    const float inv = rsqrtf((ws4[g] + ws4[g + 1]) * (1.0f / HD) + 1e-6f);
    const float val = v * inv * scale[d];
    unsigned short hb, lb;
    split_bf16(val, hb, lb);
    const int dd = swz ? (((((d >> 3) ^ (s & 15))) << 3) | (d & 7)) : d;
    const size_t o = ((size_t)(b * NH + h) * SEQ + s) * 128 + dd;
    hi[o] = hb;
    lo[o] = lb;
}

// ======================= prep_v =======================
__global__ __launch_bounds__(256) void prep_v(
    const float* __restrict__ v, unsigned short* __restrict__ Vt)
{
    __shared__ unsigned short T[128][72];
    const int bh = blockIdx.y, ktile = blockIdx.x;
    const int b = bh >> 4, h = bh & 15;
    const int key = threadIdx.x >> 2, dg = threadIdx.x & 3;
    const size_t vrow = ((size_t)(b * SEQ + ktile * 64 + key) * NH + h) * 128;
    #pragma unroll
    for (int i2 = 0; i2 < 8; i2++) {
        const int d0 = dg * 4 + i2 * 16;
        float4 x = *(const float4*)&v[vrow + d0];
        T[d0 + 0][key] = bf16_bits(x.x);
        T[d0 + 1][key] = bf16_bits(x.y);
        T[d0 + 2][key] = bf16_bits(x.z);
        T[d0 + 3][key] = bf16_bits(x.w);
    }
    __syncthreads();
    const int d = threadIdx.x >> 1, half = threadIdx.x & 1;
    const size_t obase = ((size_t)bh * 32 + ktile) * 8192 + (size_t)d * 64;
    #pragma unroll
    for (int cc = 0; cc < 4; cc++) {
        const int cs = half * 4 + cc;
        const int kb = (cs ^ (d & 7)) << 3;
        short8 val = *(const short8*)&T[d][kb];
        *(short8*)&Vt[obase + cs * 8] = val;
    }
}

// ======================= MFMA flash attention v4 (verbatim round-0) =======================
// 512 threads = 8 waves (2/SIMD for latency hiding), ATQ=256 (32 q-rows/wave),
// double-buffered KV staging, ONE barrier per tile. Grid (8, 32) = 256 blocks = 1/CU.
// LDS 128 KB -> 1 block/CU (intended). NO setprio / NO defer-max: this kernel's
// performance rests on undisturbed MFMA/VALU wave co-scheduling (v5-v9 all regressed).
#define ATQ 256
#define ATK 64

__global__ __launch_bounds__(512, 1) void attn4(
    const unsigned short* __restrict__ Qh, const unsigned short* __restrict__ Ql,
    const unsigned short* __restrict__ Kh, const unsigned short* __restrict__ Kl,
    const unsigned short* __restrict__ Vt, __hip_bfloat16* __restrict__ AO)
{
    __shared__ unsigned short KsH[2][ATK * 128];   // 32 KB  [key][d'] (chunk ^= key&15)
    __shared__ unsigned short KsL[2][ATK * 128];   // 32 KB
    __shared__ unsigned short Vts[2][HD * 64];     // 32 KB  [d][key'] (chunk ^= d&7)
    __shared__ unsigned short Ps[ATQ * 64];        // 32 KB  P[row][key'] (chunk ^= row&7)

    const int tid  = threadIdx.x;
    const int w    = tid >> 6;        // 0..7
    const int lane = tid & 63;
    const int quad = lane >> 4;
    const int fm   = lane & 15;
    const int bh = blockIdx.y;
    const int b = bh >> 4, h = bh & 15;
    const int q0 = blockIdx.x * ATQ;

    const size_t hbase = (size_t)(b * NH + h) * SEQ;

    // ---- Q fragments (pre-split bf16); wave owns rows w*32..w*32+31 ----
    short8 qh[2][4], ql[2][4];
    #pragma unroll
    for (int i = 0; i < 2; i++) {
        const size_t row = hbase + q0 + w * 32 + i * 16 + fm;
        #pragma unroll
        for (int kc = 0; kc < 4; kc++) {
            const size_t off = row * 128 + kc * 32 + quad * 8;
            qh[i][kc] = *(const short8*)&Qh[off];
            ql[i][kc] = *(const short8*)&Ql[off];
        }
    }

    floatx4 oacc[2][8];
    #pragma unroll
    for (int i = 0; i < 2; i++)
        #pragma unroll
        for (int df = 0; df < 8; df++)
            oacc[i][df] = (floatx4){0.f, 0.f, 0.f, 0.f};
    float m_[2][4], l_[2][4];
    #pragma unroll
    for (int i = 0; i < 2; i++)
        #pragma unroll
        for (int r = 0; r < 4; r++) { m_[i][r] = -1e30f; l_[i][r] = 0.f; }

    const unsigned short* gkh0 = Kh + hbase * 128;
    const unsigned short* gkl0 = Kl + hbase * 128;
    const unsigned short* gvt0 = Vt + (size_t)bh * 32 * 8192;

    // staging: 48 chunks of 1 KB (KsH 16, KsL 16, Vts 16); wave w -> chunks w*6..w*6+5
    const int ch0 = w * 6;

    // ---- prologue: stage tile 0 into buffer 0 ----
    #pragma unroll
    for (int c = 0; c < 6; c++) {
        const int ch = ch0 + c;
        const size_t go = (size_t)(ch & 15) * 512 + lane * 8;
        if (ch < 16)      async_load16(gkh0 + go, (char*)KsH[0] + ch * 1024);
        else if (ch < 32) async_load16(gkl0 + go, (char*)KsL[0] + (ch - 16) * 1024);
        else              async_load16(gvt0 + go, (char*)Vts[0] + (ch - 32) * 1024);
    }
    __syncthreads();   // drain: tile 0 staged

    for (int ktile = 0; ktile < SEQ / ATK; ktile++) {
        const int cur = ktile & 1;

        // ---- prefetch tile t+1 into other buffer (drained by end-of-tile barrier) ----
        if (ktile + 1 < SEQ / ATK) {
            const unsigned short* gkh = gkh0 + (size_t)(ktile + 1) * ATK * 128;
            const unsigned short* gkl = gkl0 + (size_t)(ktile + 1) * ATK * 128;
            const unsigned short* gvt = gvt0 + (size_t)(ktile + 1) * 8192;
            #pragma unroll
            for (int c = 0; c < 6; c++) {
                const int ch = ch0 + c;
                const size_t go = (size_t)(ch & 15) * 512 + lane * 8;
                if (ch < 16)      async_load16(gkh + go, (char*)KsH[1 - cur] + ch * 1024);
                else if (ch < 32) async_load16(gkl + go, (char*)KsL[1 - cur] + (ch - 16) * 1024);
                else              async_load16(gvt + go, (char*)Vts[1 - cur] + (ch - 32) * 1024);
            }
        }

        // ---- S = Q K^T (3-term hi/lo) from buffer cur ----
        floatx4 sacc[2][4];
        #pragma unroll
        for (int i = 0; i < 2; i++)
            #pragma unroll
            for (int jf = 0; jf < 4; jf++)
                sacc[i][jf] = (floatx4){0.f, 0.f, 0.f, 0.f};
        #pragma unroll
        for (int kc = 0; kc < 4; kc++)
            #pragma unroll
            for (int jf = 0; jf < 4; jf++) {
                const int koff = (jf * 16 + fm) * 128 + (((kc * 4 + quad) ^ fm) << 3);
                short8 kh8 = *(const short8*)&KsH[cur][koff];
                short8 kl8 = *(const short8*)&KsL[cur][koff];
                #pragma unroll
                for (int i = 0; i < 2; i++) {
                    sacc[i][jf] = __builtin_amdgcn_mfma_f32_16x16x32_bf16(qh[i][kc], kh8, sacc[i][jf], 0, 0, 0);
                    sacc[i][jf] = __builtin_amdgcn_mfma_f32_16x16x32_bf16(qh[i][kc], kl8, sacc[i][jf], 0, 0, 0);
                    sacc[i][jf] = __builtin_amdgcn_mfma_f32_16x16x32_bf16(ql[i][kc], kh8, sacc[i][jf], 0, 0, 0);
                }
            }

        // ---- online softmax (registers) ----
        float alpha_[2][4];
        #pragma unroll
        for (int i = 0; i < 2; i++)
            #pragma unroll
            for (int r = 0; r < 4; r++) {
                float mx = fmaxf(fmaxf(sacc[i][0][r], sacc[i][1][r]),
                                 fmaxf(sacc[i][2][r], sacc[i][3][r]));
                mx = fmaxf(mx, __shfl_xor(mx, 1));
                mx = fmaxf(mx, __shfl_xor(mx, 2));
                mx = fmaxf(mx, __shfl_xor(mx, 4));
                mx = fmaxf(mx, __shfl_xor(mx, 8));
                const float mold = m_[i][r];
                const float mnew = fmaxf(mold, mx);
                const float al = __expf(mold - mnew);
                m_[i][r] = mnew;
                alpha_[i][r] = al;
                float rs = 0.f;
                #pragma unroll
                for (int jf = 0; jf < 4; jf++) {
                    float p = __expf(sacc[i][jf][r] - mnew);
                    sacc[i][jf][r] = p;
                    rs += p;
                }
                rs += __shfl_xor(rs, 1);
                rs += __shfl_xor(rs, 2);
                rs += __shfl_xor(rs, 4);
                rs += __shfl_xor(rs, 8);
                l_[i][r] = l_[i][r] * al + rs;
            }
        #pragma unroll
        for (int i = 0; i < 2; i++)
            #pragma unroll
            for (int df = 0; df < 8; df++)
                #pragma unroll
                for (int r = 0; r < 4; r++)
                    oacc[i][df][r] *= alpha_[i][r];

        // ---- P -> bf16 into Ps (own rows; wave-local ordering, no barrier) ----
        #pragma unroll
        for (int i = 0; i < 2; i++)
            #pragma unroll
            for (int jf = 0; jf < 4; jf++)
                #pragma unroll
                for (int r = 0; r < 4; r++) {
                    const int row = w * 32 + i * 16 + quad * 4 + r;
                    const int chunk = jf * 2 + (fm >> 3);
                    const int colp = ((chunk ^ (row & 7)) << 3) | (fm & 7);
                    Ps[row * 64 + colp] = bf16_bits(sacc[i][jf][r]);
                }

        // ---- O += P V from buffer cur ----
        #pragma unroll
        for (int kc2 = 0; kc2 < 2; kc2++) {
            short8 ap[2];
            #pragma unroll
            for (int i = 0; i < 2; i++) {
                const int row = w * 32 + i * 16 + fm;
                ap[i] = *(const short8*)&Ps[row * 64 + (((kc2 * 4 + quad) ^ (row & 7)) << 3)];
            }
            #pragma unroll
            for (int df = 0; df < 8; df++) {
                const int d = df * 16 + fm;
                short8 bv = *(const short8*)&Vts[cur][d * 64 + (((kc2 * 4 + quad) ^ (d & 7)) << 3)];
                #pragma unroll
                for (int i = 0; i < 2; i++)
                    oacc[i][df] = __builtin_amdgcn_mfma_f32_16x16x32_bf16(ap[i], bv, oacc[i][df], 0, 0, 0);
            }
        }

        // single barrier per tile: drains prefetch + protects buffer swap
        __syncthreads();
    }

    // ---- epilogue: AO bf16 [b,s,h,d] ----
    const size_t obase = ((size_t)b * SEQ * NH + h) * HD;
    const size_t rstr = (size_t)NH * HD;
    float linv[2][4];
    #pragma unroll
    for (int i = 0; i < 2; i++)
        #pragma unroll
        for (int r = 0; r < 4; r++) linv[i][r] = 1.0f / l_[i][r];
    #pragma unroll
    for (int i = 0; i < 2; i++)
        #pragma unroll
        for (int df = 0; df < 8; df++)
            #pragma unroll
            for (int r = 0; r < 4; r++) {
                const int row = q0 + w * 32 + i * 16 + quad * 4 + r;
                const int d = df * 16 + fm;
                AO[obase + (size_t)row * rstr + d] = __float2bfloat16(oacc[i][df][r] * linv[i][r]);
            }
}

// ======================= launch =======================
extern "C" void kernel_launch(void* const* d_in, const int* in_sizes, int n_in,
                              void* d_out, int out_size, void* d_ws, size_t ws_size,
                              hipStream_t stream) {
    const float* x  = (const float*)d_in[0];
    const float* wq = (const float*)d_in[1];
    const float* wk = (const float*)d_in[2];
    const float* wv = (const float*)d_in[3];
    const float* wo = (const float*)d_in[4];
    const float* q_scale = (const float*)d_in[5];
    const float* k_scale = (const float*)d_in[6];
    float* out = (float*)d_out;

    const size_t T = (size_t)BATCH * SEQ * NH * HD;   // 8388608
    const size_t W = (size_t)EMB * NH * HD;           // 4194304

    float* q = (float*)d_ws;                          // fp32 [b,s,h,d]
    float* k = q + T;
    float* v = k + T;
    unsigned short* xh   = (unsigned short*)(v + T);  // reused as Qh after GEMMs
    unsigned short* xl   = xh + T;                    // reused as Ql
    unsigned short* aob  = xl + T;
    unsigned short* Kh   = aob + T;
    unsigned short* Kl   = Kh + T;
    unsigned short* Vtb  = Kl + T;
    unsigned short* wqTh = Vtb + T;
    unsigned short* wqTl = wqTh + W;
    unsigned short* wkTh = wqTl + W;
    unsigned short* wkTl = wkTh + W;
    unsigned short* wvT  = wkTl + W;
    unsigned short* woT  = wvT + W;

    const int M = BATCH * SEQ;   // 4096
    const int N = NH * HD;       // 2048
    const int K = EMB;           // 2048

    cast_split_f32<<<(int)(T / 4 + 255) / 256, 256, 0, stream>>>(x, xh, xl, (int)T);
    dim3 tblk(32, 8);
    transpose_cast_split<<<dim3(N / 32, K / 32), tblk, 0, stream>>>(wq, wqTh, wqTl, K, N);
    transpose_cast_split<<<dim3(N / 32, K / 32), tblk, 0, stream>>>(wk, wkTh, wkTl, K, N);
    transpose_cast<<<dim3(N / 32, K / 32), tblk, 0, stream>>>(wv, wvT, K, N);
    transpose_cast<<<dim3(EMB / 32, (NH * HD) / 32), tblk, 0, stream>>>(wo, woT, NH * HD, EMB);

    // fused Q+K split projection (shared A staging), then V projection
    gemm_qk_split<<<dim3(N / GT, M / GT), 512, 0, stream>>>(xh, xl, wqTh, wqTl, wkTh, wkTl, q, k, M, N, K);
    gemm_bf16<<<dim3(N / GT, M / GT), 256, 0, stream>>>(xh, wvT, v, M, N, K);

    unsigned short* Qh = xh;
    unsigned short* Ql = xl;
    prep_qk<<<(int)(T / 128 / 2), 256, 0, stream>>>(q, q_scale, Qh, Ql, 0);
    prep_qk<<<(int)(T / 128 / 2), 256, 0, stream>>>(k, k_scale, Kh, Kl, 1);
    prep_v<<<dim3(SEQ / ATK, BATCH * NH), 256, 0, stream>>>(v, Vtb);

    attn4<<<dim3(SEQ / ATQ, BATCH * NH), 512, 0, stream>>>(Qh, Ql, Kh, Kl, Vtb, (__hip_bfloat16*)aob);

    gemm_bf16<<<dim3(EMB / GT, M / GT), 256, 0, stream>>>(aob, woT, out, M, EMB, NH * HD);
}

// Round 7
// 735.481 us; speedup vs baseline: 1.3513x; 1.1173x over previous
//
#include <hip/hip_runtime.h>
#include <hip/hip_bf16.h>
#include <math.h>

#define BATCH 2
#define SEQ   2048
#define EMB   2048
#define NH    16
#define HD    128

typedef __attribute__((ext_vector_type(8))) short short8;
typedef __attribute__((ext_vector_type(4))) float floatx4;

__device__ inline void async_load16(const void* g, void* l) {
    __builtin_amdgcn_global_load_lds(
        (const __attribute__((address_space(1))) unsigned int*)g,
        (__attribute__((address_space(3))) unsigned int*)l, 16, 0, 0);
}

__device__ inline unsigned short bf16_bits(float f) {
    __hip_bfloat16 b = __float2bfloat16(f);
    return *(unsigned short*)&b;
}
__device__ inline void split_bf16(float f, unsigned short& h, unsigned short& l) {
    __hip_bfloat16 hb = __float2bfloat16(f);
    h = *(unsigned short*)&hb;
    float r = f - __bfloat162float(hb);
    __hip_bfloat16 lb = __float2bfloat16(r);
    l = *(unsigned short*)&lb;
}

// ======================= plain bf16 MFMA GEMM (m97 structure) =======================
#define GT 128
#define GK 32

__global__ __launch_bounds__(256) void gemm_bf16(
    const unsigned short* __restrict__ A,
    const unsigned short* __restrict__ Bt,
    float* __restrict__ C, int M, int N, int K)
{
    __shared__ unsigned short As[GT * GK];
    __shared__ unsigned short Bs[GT * GK];

    const int tid  = threadIdx.x;
    const int w    = tid >> 6;
    const int lane = tid & 63;
    const int wr   = w >> 1, wc = w & 1;
    const int row0 = blockIdx.y * GT;
    const int col0 = blockIdx.x * GT;

    floatx4 acc[4][4];
    #pragma unroll
    for (int i = 0; i < 4; i++)
        #pragma unroll
        for (int j = 0; j < 4; j++)
            acc[i][j] = (floatx4){0.f, 0.f, 0.f, 0.f};

    const int srow  = lane >> 2;
    const int skoff = (lane & 3) * 8;
    const int fm = lane & 15;
    const int fk = (lane >> 4) * 8;

    for (int k0 = 0; k0 < K; k0 += GK) {
        #pragma unroll
        for (int t = 0; t < 2; t++) {
            const int c = w * 2 + t;
            async_load16(A  + (size_t)(row0 + c * 16 + srow) * K + k0 + skoff, (char*)As + c * 1024);
            async_load16(Bt + (size_t)(col0 + c * 16 + srow) * K + k0 + skoff, (char*)Bs + c * 1024);
        }
        __syncthreads();

        short8 af[4], bf[4];
        #pragma unroll
        for (int i = 0; i < 4; i++) {
            af[i] = *(const short8*)&As[(wr * 64 + i * 16 + fm) * GK + fk];
            bf[i] = *(const short8*)&Bs[(wc * 64 + i * 16 + fm) * GK + fk];
        }
        #pragma unroll
        for (int i = 0; i < 4; i++)
            #pragma unroll
            for (int j = 0; j < 4; j++)
                acc[i][j] = __builtin_amdgcn_mfma_f32_16x16x32_bf16(af[i], bf[j], acc[i][j], 0, 0, 0);
        __syncthreads();
    }

    const int quad = lane >> 4;
    #pragma unroll
    for (int i = 0; i < 4; i++)
        #pragma unroll
        for (int j = 0; j < 4; j++) {
            const size_t base = (size_t)(row0 + wr * 64 + i * 16 + quad * 4) * N
                              + col0 + wc * 64 + j * 16 + fm;
            #pragma unroll
            for (int r = 0; r < 4; r++)
                C[base + (size_t)r * N] = acc[i][j][r];
        }
}

// ======================= split GEMM + fused RMSNorm epilogue (Q/K projection) =======================
// K-loop byte-identical to the proven gemm_bf16_split. Epilogue: since GT=128=HD and
// N=2048, each block's 128 output columns are exactly one head's d-range, so the
// row-wise sum of squares is computed in-block (16-lane shfl tree + 1KB LDS exchange
// between wc=0/wc=1 waves), then RMSNorm + bf16 hi/lo split + head-major relayout
// are applied directly -- eliminating the fp32 intermediate and the prep_qk dispatch.
__global__ __launch_bounds__(256) void gemm_qk_rms(
    const unsigned short* __restrict__ Ah, const unsigned short* __restrict__ Al,
    const unsigned short* __restrict__ Bh, const unsigned short* __restrict__ Bl,
    const float* __restrict__ scale,
    unsigned short* __restrict__ hi, unsigned short* __restrict__ lo,
    int swz, int K)
{
    __shared__ unsigned short AsH[GT * GK], AsL[GT * GK];
    __shared__ unsigned short BsH[GT * GK], BsL[GT * GK];
    __shared__ float ws2[2][GT];

    const int tid  = threadIdx.x;
    const int w    = tid >> 6;
    const int lane = tid & 63;
    const int wr   = w >> 1, wc = w & 1;
    const int row0 = blockIdx.y * GT;
    const int col0 = blockIdx.x * GT;

    floatx4 acc[4][4];
    #pragma unroll
    for (int i = 0; i < 4; i++)
        #pragma unroll
        for (int j = 0; j < 4; j++)
            acc[i][j] = (floatx4){0.f, 0.f, 0.f, 0.f};

    const int srow  = lane >> 2;
    const int skoff = (lane & 3) * 8;
    const int fm = lane & 15;
    const int fk = (lane >> 4) * 8;

    for (int k0 = 0; k0 < K; k0 += GK) {
        #pragma unroll
        for (int t = 0; t < 2; t++) {
            const int c = w * 2 + t;
            const size_t ao = (size_t)(row0 + c * 16 + srow) * K + k0 + skoff;
            const size_t bo = (size_t)(col0 + c * 16 + srow) * K + k0 + skoff;
            async_load16(Ah + ao, (char*)AsH + c * 1024);
            async_load16(Al + ao, (char*)AsL + c * 1024);
            async_load16(Bh + bo, (char*)BsH + c * 1024);
            async_load16(Bl + bo, (char*)BsL + c * 1024);
        }
        __syncthreads();

        short8 afh[4], afl[4], bfh[4], bfl[4];
        #pragma unroll
        for (int i = 0; i < 4; i++) {
            const int arow = (wr * 64 + i * 16 + fm) * GK + fk;
            const int brow = (wc * 64 + i * 16 + fm) * GK + fk;
            afh[i] = *(const short8*)&AsH[arow];
            afl[i] = *(const short8*)&AsL[arow];
            bfh[i] = *(const short8*)&BsH[brow];
            bfl[i] = *(const short8*)&BsL[brow];
        }
        #pragma unroll
        for (int i = 0; i < 4; i++)
            #pragma unroll
            for (int j = 0; j < 4; j++) {
                acc[i][j] = __builtin_amdgcn_mfma_f32_16x16x32_bf16(afh[i], bfh[j], acc[i][j], 0, 0, 0);
                acc[i][j] = __builtin_amdgcn_mfma_f32_16x16x32_bf16(afh[i], bfl[j], acc[i][j], 0, 0, 0);
                acc[i][j] = __builtin_amdgcn_mfma_f32_16x16x32_bf16(afl[i], bfh[j], acc[i][j], 0, 0, 0);
            }
        __syncthreads();
    }

    // ---- fused epilogue ----
    const int quad = lane >> 4;

    // per-row sum of squares over this wave's 64 columns (4 j-cols x 16 fm-lanes)
    float sq[4][4];
    #pragma unroll
    for (int i = 0; i < 4; i++)
        #pragma unroll
        for (int r = 0; r < 4; r++) {
            float s2 = 0.f;
            #pragma unroll
            for (int j = 0; j < 4; j++) s2 += acc[i][j][r] * acc[i][j][r];
            s2 += __shfl_xor(s2, 1);
            s2 += __shfl_xor(s2, 2);
            s2 += __shfl_xor(s2, 4);
            s2 += __shfl_xor(s2, 8);
            sq[i][r] = s2;
        }
    if (fm == 0) {
        #pragma unroll
        for (int i = 0; i < 4; i++)
            #pragma unroll
            for (int r = 0; r < 4; r++)
                ws2[wc][wr * 64 + i * 16 + quad * 4 + r] = sq[i][r];
    }
    __syncthreads();

    const int hh = col0 >> 7;   // head index (GT == HD)
    float scv[4];
    #pragma unroll
    for (int j = 0; j < 4; j++) scv[j] = scale[wc * 64 + j * 16 + fm];

    #pragma unroll
    for (int i = 0; i < 4; i++)
        #pragma unroll
        for (int r = 0; r < 4; r++) {
            const int lrow = wr * 64 + i * 16 + quad * 4 + r;
            const int row  = row0 + lrow;            // global m = b*SEQ + s
            const int bb = row >> 11, s = row & 2047;
            const float inv = rsqrtf((ws2[0][lrow] + ws2[1][lrow]) * (1.0f / HD) + 1e-6f);
            const size_t ob = ((size_t)(bb * NH + hh) * SEQ + s) * 128;
            #pragma unroll
            for (int j = 0; j < 4; j++) {
                const int d = wc * 64 + j * 16 + fm;
                const float val = acc[i][j][r] * inv * scv[j];
                unsigned short hb, lb;
                split_bf16(val, hb, lb);
                const int dd = swz ? ((((d >> 3) ^ (s & 15)) << 3) | (d & 7)) : d;
                hi[ob + dd] = hb;
                lo[ob + dd] = lb;
            }
        }
}

// ======================= casts / weight prep =======================
__global__ __launch_bounds__(256) void cast_split_f32(
    const float* __restrict__ in, unsigned short* __restrict__ hi,
    unsigned short* __restrict__ lo, int n)
{
    int i = (blockIdx.x * 256 + threadIdx.x) * 4;
    if (i >= n) return;
    float4 v = *(const float4*)&in[i];
    ushort4 h, l;
    split_bf16(v.x, h.x, l.x);
    split_bf16(v.y, h.y, l.y);
    split_bf16(v.z, h.z, l.z);
    split_bf16(v.w, h.w, l.w);
    *(ushort4*)&hi[i] = h;
    *(ushort4*)&lo[i] = l;
}

__global__ __launch_bounds__(256) void transpose_cast(
    const float* __restrict__ W, unsigned short* __restrict__ Wt, int K, int N)
{
    __shared__ float tile[32][33];
    const int k0 = blockIdx.y * 32, n0 = blockIdx.x * 32;
    const int tx = threadIdx.x, ty = threadIdx.y;
    #pragma unroll
    for (int i = 0; i < 4; i++)
        tile[ty + i * 8][tx] = W[(size_t)(k0 + ty + i * 8) * N + n0 + tx];
    __syncthreads();
    #pragma unroll
    for (int i = 0; i < 4; i++)
        Wt[(size_t)(n0 + ty + i * 8) * K + k0 + tx] = bf16_bits(tile[tx][ty + i * 8]);
}

__global__ __launch_bounds__(256) void transpose_cast_split(
    const float* __restrict__ W, unsigned short* __restrict__ WtH,
    unsigned short* __restrict__ WtL, int K, int N)
{
    __shared__ float tile[32][33];
    const int k0 = blockIdx.y * 32, n0 = blockIdx.x * 32;
    const int tx = threadIdx.x, ty = threadIdx.y;
    #pragma unroll
    for (int i = 0; i < 4; i++)
        tile[ty + i * 8][tx] = W[(size_t)(k0 + ty + i * 8) * N + n0 + tx];
    __syncthreads();
    #pragma unroll
    for (int i = 0; i < 4; i++) {
        unsigned short h, l;
        split_bf16(tile[tx][ty + i * 8], h, l);
        size_t idx = (size_t)(n0 + ty + i * 8) * K + k0 + tx;
        WtH[idx] = h;
        WtL[idx] = l;
    }
}

// ======================= prep_v =======================
__global__ __launch_bounds__(256) void prep_v(
    const float* __restrict__ v, unsigned short* __restrict__ Vt)
{
    __shared__ unsigned short T[128][72];
    const int bh = blockIdx.y, ktile = blockIdx.x;
    const int b = bh >> 4, h = bh & 15;
    const int key = threadIdx.x >> 2, dg = threadIdx.x & 3;
    const size_t vrow = ((size_t)(b * SEQ + ktile * 64 + key) * NH + h) * 128;
    #pragma unroll
    for (int i2 = 0; i2 < 8; i2++) {
        const int d0 = dg * 4 + i2 * 16;
        float4 x = *(const float4*)&v[vrow + d0];
        T[d0 + 0][key] = bf16_bits(x.x);
        T[d0 + 1][key] = bf16_bits(x.y);
        T[d0 + 2][key] = bf16_bits(x.z);
        T[d0 + 3][key] = bf16_bits(x.w);
    }
    __syncthreads();
    const int d = threadIdx.x >> 1, half = threadIdx.x & 1;
    const size_t obase = ((size_t)bh * 32 + ktile) * 8192 + (size_t)d * 64;
    #pragma unroll
    for (int cc = 0; cc < 4; cc++) {
        const int cs = half * 4 + cc;
        const int kb = (cs ^ (d & 7)) << 3;
        short8 val = *(const short8*)&T[d][kb];
        *(short8*)&Vt[obase + cs * 8] = val;
    }
}

// ======================= MFMA flash attention v4 (verbatim round-0) =======================
// 512 threads = 8 waves (2/SIMD for latency hiding), ATQ=256 (32 q-rows/wave),
// double-buffered KV staging, ONE barrier per tile. Grid (8, 32) = 256 blocks = 1/CU.
// NO setprio / NO defer-max: performance rests on undisturbed MFMA/VALU wave
// co-scheduling (v5-v9 all regressed when this schedule was perturbed).
#define ATQ 256
#define ATK 64

__global__ __launch_bounds__(512, 1) void attn4(
    const unsigned short* __restrict__ Qh, const unsigned short* __restrict__ Ql,
    const unsigned short* __restrict__ Kh, const unsigned short* __restrict__ Kl,
    const unsigned short* __restrict__ Vt, __hip_bfloat16* __restrict__ AO)
{
    __shared__ unsigned short KsH[2][ATK * 128];   // 32 KB  [key][d'] (chunk ^= key&15)
    __shared__ unsigned short KsL[2][ATK * 128];   // 32 KB
    __shared__ unsigned short Vts[2][HD * 64];     // 32 KB  [d][key'] (chunk ^= d&7)
    __shared__ unsigned short Ps[ATQ * 64];        // 32 KB  P[row][key'] (chunk ^= row&7)

    const int tid  = threadIdx.x;
    const int w    = tid >> 6;        // 0..7
    const int lane = tid & 63;
    const int quad = lane >> 4;
    const int fm   = lane & 15;
    const int bh = blockIdx.y;
    const int b = bh >> 4, h = bh & 15;
    const int q0 = blockIdx.x * ATQ;

    const size_t hbase = (size_t)(b * NH + h) * SEQ;

    // ---- Q fragments (pre-split bf16); wave owns rows w*32..w*32+31 ----
    short8 qh[2][4], ql[2][4];
    #pragma unroll
    for (int i = 0; i < 2; i++) {
        const size_t row = hbase + q0 + w * 32 + i * 16 + fm;
        #pragma unroll
        for (int kc = 0; kc < 4; kc++) {
            const size_t off = row * 128 + kc * 32 + quad * 8;
            qh[i][kc] = *(const short8*)&Qh[off];
            ql[i][kc] = *(const short8*)&Ql[off];
        }
    }

    floatx4 oacc[2][8];
    #pragma unroll
    for (int i = 0; i < 2; i++)
        #pragma unroll
        for (int df = 0; df < 8; df++)
            oacc[i][df] = (floatx4){0.f, 0.f, 0.f, 0.f};
    float m_[2][4], l_[2][4];
    #pragma unroll
    for (int i = 0; i < 2; i++)
        #pragma unroll
        for (int r = 0; r < 4; r++) { m_[i][r] = -1e30f; l_[i][r] = 0.f; }

    const unsigned short* gkh0 = Kh + hbase * 128;
    const unsigned short* gkl0 = Kl + hbase * 128;
    const unsigned short* gvt0 = Vt + (size_t)bh * 32 * 8192;

    // staging: 48 chunks of 1 KB (KsH 16, KsL 16, Vts 16); wave w -> chunks w*6..w*6+5
    const int ch0 = w * 6;

    // ---- prologue: stage tile 0 into buffer 0 ----
    #pragma unroll
    for (int c = 0; c < 6; c++) {
        const int ch = ch0 + c;
        const size_t go = (size_t)(ch & 15) * 512 + lane * 8;
        if (ch < 16)      async_load16(gkh0 + go, (char*)KsH[0] + ch * 1024);
        else if (ch < 32) async_load16(gkl0 + go, (char*)KsL[0] + (ch - 16) * 1024);
        else              async_load16(gvt0 + go, (char*)Vts[0] + (ch - 32) * 1024);
    }
    __syncthreads();   // drain: tile 0 staged

    for (int ktile = 0; ktile < SEQ / ATK; ktile++) {
        const int cur = ktile & 1;

        // ---- prefetch tile t+1 into other buffer (drained by end-of-tile barrier) ----
        if (ktile + 1 < SEQ / ATK) {
            const unsigned short* gkh = gkh0 + (size_t)(ktile + 1) * ATK * 128;
            const unsigned short* gkl = gkl0 + (size_t)(ktile + 1) * ATK * 128;
            const unsigned short* gvt = gvt0 + (size_t)(ktile + 1) * 8192;
            #pragma unroll
            for (int c = 0; c < 6; c++) {
                const int ch = ch0 + c;
                const size_t go = (size_t)(ch & 15) * 512 + lane * 8;
                if (ch < 16)      async_load16(gkh + go, (char*)KsH[1 - cur] + ch * 1024);
                else if (ch < 32) async_load16(gkl + go, (char*)KsL[1 - cur] + (ch - 16) * 1024);
                else              async_load16(gvt + go, (char*)Vts[1 - cur] + (ch - 32) * 1024);
            }
        }

        // ---- S = Q K^T (3-term hi/lo) from buffer cur ----
        floatx4 sacc[2][4];
        #pragma unroll
        for (int i = 0; i < 2; i++)
            #pragma unroll
            for (int jf = 0; jf < 4; jf++)
                sacc[i][jf] = (floatx4){0.f, 0.f, 0.f, 0.f};
        #pragma unroll
        for (int kc = 0; kc < 4; kc++)
            #pragma unroll
            for (int jf = 0; jf < 4; jf++) {
                const int koff = (jf * 16 + fm) * 128 + (((kc * 4 + quad) ^ fm) << 3);
                short8 kh8 = *(const short8*)&KsH[cur][koff];
                short8 kl8 = *(const short8*)&KsL[cur][koff];
                #pragma unroll
                for (int i = 0; i < 2; i++) {
                    sacc[i][jf] = __builtin_amdgcn_mfma_f32_16x16x32_bf16(qh[i][kc], kh8, sacc[i][jf], 0, 0, 0);
                    sacc[i][jf] = __builtin_amdgcn_mfma_f32_16x16x32_bf16(qh[i][kc], kl8, sacc[i][jf], 0, 0, 0);
                    sacc[i][jf] = __builtin_amdgcn_mfma_f32_16x16x32_bf16(ql[i][kc], kh8, sacc[i][jf], 0, 0, 0);
                }
            }

        // ---- online softmax (registers) ----
        float alpha_[2][4];
        #pragma unroll
        for (int i = 0; i < 2; i++)
            #pragma unroll
            for (int r = 0; r < 4; r++) {
                float mx = fmaxf(fmaxf(sacc[i][0][r], sacc[i][1][r]),
                                 fmaxf(sacc[i][2][r], sacc[i][3][r]));
                mx = fmaxf(mx, __shfl_xor(mx, 1));
                mx = fmaxf(mx, __shfl_xor(mx, 2));
                mx = fmaxf(mx, __shfl_xor(mx, 4));
                mx = fmaxf(mx, __shfl_xor(mx, 8));
                const float mold = m_[i][r];
                const float mnew = fmaxf(mold, mx);
                const float al = __expf(mold - mnew);
                m_[i][r] = mnew;
                alpha_[i][r] = al;
                float rs = 0.f;
                #pragma unroll
                for (int jf = 0; jf < 4; jf++) {
                    float p = __expf(sacc[i][jf][r] - mnew);
                    sacc[i][jf][r] = p;
                    rs += p;
                }
                rs += __shfl_xor(rs, 1);
                rs += __shfl_xor(rs, 2);
                rs += __shfl_xor(rs, 4);
                rs += __shfl_xor(rs, 8);
                l_[i][r] = l_[i][r] * al + rs;
            }
        #pragma unroll
        for (int i = 0; i < 2; i++)
            #pragma unroll
            for (int df = 0; df < 8; df++)
                #pragma unroll
                for (int r = 0; r < 4; r++)
                    oacc[i][df][r] *= alpha_[i][r];

        // ---- P -> bf16 into Ps (own rows; wave-local ordering, no barrier) ----
        #pragma unroll
        for (int i = 0; i < 2; i++)
            #pragma unroll
            for (int jf = 0; jf < 4; jf++)
                #pragma unroll
                for (int r = 0; r < 4; r++) {
                    const int row = w * 32 + i * 16 + quad * 4 + r;
                    const int chunk = jf * 2 + (fm >> 3);
                    const int colp = ((chunk ^ (row & 7)) << 3) | (fm & 7);
                    Ps[row * 64 + colp] = bf16_bits(sacc[i][jf][r]);
                }

        // ---- O += P V from buffer cur ----
        #pragma unroll
        for (int kc2 = 0; kc2 < 2; kc2++) {
            short8 ap[2];
            #pragma unroll
            for (int i = 0; i < 2; i++) {
                const int row = w * 32 + i * 16 + fm;
                ap[i] = *(const short8*)&Ps[row * 64 + (((kc2 * 4 + quad) ^ (row & 7)) << 3)];
            }
            #pragma unroll
            for (int df = 0; df < 8; df++) {
                const int d = df * 16 + fm;
                short8 bv = *(const short8*)&Vts[cur][d * 64 + (((kc2 * 4 + quad) ^ (d & 7)) << 3)];
                #pragma unroll
                for (int i = 0; i < 2; i++)
                    oacc[i][df] = __builtin_amdgcn_mfma_f32_16x16x32_bf16(ap[i], bv, oacc[i][df], 0, 0, 0);
            }
        }

        // single barrier per tile: drains prefetch + protects buffer swap
        __syncthreads();
    }

    // ---- epilogue: AO bf16 [b,s,h,d] ----
    const size_t obase = ((size_t)b * SEQ * NH + h) * HD;
    const size_t rstr = (size_t)NH * HD;
    float linv[2][4];
    #pragma unroll
    for (int i = 0; i < 2; i++)
        #pragma unroll
        for (int r = 0; r < 4; r++) linv[i][r] = 1.0f / l_[i][r];
    #pragma unroll
    for (int i = 0; i < 2; i++)
        #pragma unroll
        for (int df = 0; df < 8; df++)
            #pragma unroll
            for (int r = 0; r < 4; r++) {
                const int row = q0 + w * 32 + i * 16 + quad * 4 + r;
                const int d = df * 16 + fm;
                AO[obase + (size_t)row * rstr + d] = __float2bfloat16(oacc[i][df][r] * linv[i][r]);
            }
}

// ======================= launch =======================
extern "C" void kernel_launch(void* const* d_in, const int* in_sizes, int n_in,
                              void* d_out, int out_size, void* d_ws, size_t ws_size,
                              hipStream_t stream) {
    const float* x  = (const float*)d_in[0];
    const float* wq = (const float*)d_in[1];
    const float* wk = (const float*)d_in[2];
    const float* wv = (const float*)d_in[3];
    const float* wo = (const float*)d_in[4];
    const float* q_scale = (const float*)d_in[5];
    const float* k_scale = (const float*)d_in[6];
    float* out = (float*)d_out;

    const size_t T = (size_t)BATCH * SEQ * NH * HD;   // 8388608
    const size_t W = (size_t)EMB * NH * HD;           // 4194304

    float* v = (float*)d_ws;                          // fp32 [b,s,h,d]
    unsigned short* xh   = (unsigned short*)(v + T);
    unsigned short* xl   = xh + T;
    unsigned short* aob  = xl + T;
    unsigned short* Qh   = aob + T;                   // separate (NOT aliased to xh:
    unsigned short* Ql   = Qh + T;                    //  fused epilogue writes while
    unsigned short* Kh   = Ql + T;                    //  other blocks still read A)
    unsigned short* Kl   = Kh + T;
    unsigned short* Vtb  = Kl + T;
    unsigned short* wqTh = Vtb + T;
    unsigned short* wqTl = wqTh + W;
    unsigned short* wkTh = wqTl + W;
    unsigned short* wkTl = wkTh + W;
    unsigned short* wvT  = wkTl + W;
    unsigned short* woT  = wvT + W;

    const int M = BATCH * SEQ;   // 4096
    const int N = NH * HD;       // 2048
    const int K = EMB;           // 2048

    cast_split_f32<<<(int)(T / 4 + 255) / 256, 256, 0, stream>>>(x, xh, xl, (int)T);
    dim3 tblk(32, 8);
    transpose_cast_split<<<dim3(N / 32, K / 32), tblk, 0, stream>>>(wq, wqTh, wqTl, K, N);
    transpose_cast_split<<<dim3(N / 32, K / 32), tblk, 0, stream>>>(wk, wkTh, wkTl, K, N);
    transpose_cast<<<dim3(N / 32, K / 32), tblk, 0, stream>>>(wv, wvT, K, N);
    transpose_cast<<<dim3(EMB / 32, (NH * HD) / 32), tblk, 0, stream>>>(wo, woT, NH * HD, EMB);

    dim3 ggrid(N / GT, M / GT);
    // Q/K projections with fused RMSNorm + split + relayout epilogue (replaces
    // gemm_bf16_split + prep_qk pairs; K-loop structure identical)
    gemm_qk_rms<<<ggrid, 256, 0, stream>>>(xh, xl, wqTh, wqTl, q_scale, Qh, Ql, 0, K);
    gemm_qk_rms<<<ggrid, 256, 0, stream>>>(xh, xl, wkTh, wkTl, k_scale, Kh, Kl, 1, K);
    gemm_bf16<<<ggrid, 256, 0, stream>>>(xh, wvT, v, M, N, K);

    prep_v<<<dim3(SEQ / ATK, BATCH * NH), 256, 0, stream>>>(v, Vtb);

    attn4<<<dim3(SEQ / ATQ, BATCH * NH), 512, 0, stream>>>(Qh, Ql, Kh, Kl, Vtb, (__hip_bfloat16*)aob);

    gemm_bf16<<<dim3(EMB / GT, M / GT), 256, 0, stream>>>(aob, woT, out, M, EMB, NH * HD);
}

// Round 8
// 687.618 us; speedup vs baseline: 1.4454x; 1.0696x over previous
//
#include <hip/hip_runtime.h>
#include <hip/hip_bf16.h>
#include <math.h>

#define BATCH 2
#define SEQ   2048
#define EMB   2048
#define NH    16
#define HD    128

typedef __attribute__((ext_vector_type(8))) short short8;
typedef __attribute__((ext_vector_type(4))) float floatx4;

__device__ inline void async_load16(const void* g, void* l) {
    __builtin_amdgcn_global_load_lds(
        (const __attribute__((address_space(1))) unsigned int*)g,
        (__attribute__((address_space(3))) unsigned int*)l, 16, 0, 0);
}

__device__ inline unsigned short bf16_bits(float f) {
    __hip_bfloat16 b = __float2bfloat16(f);
    return *(unsigned short*)&b;
}
__device__ inline void split_bf16(float f, unsigned short& h, unsigned short& l) {
    __hip_bfloat16 hb = __float2bfloat16(f);
    h = *(unsigned short*)&hb;
    float r = f - __bfloat162float(hb);
    __hip_bfloat16 lb = __float2bfloat16(r);
    l = *(unsigned short*)&lb;
}

// ======================= plain bf16 MFMA GEMM (m97 structure) =======================
#define GT 128
#define GK 32

__global__ __launch_bounds__(256) void gemm_bf16(
    const unsigned short* __restrict__ A,
    const unsigned short* __restrict__ Bt,
    float* __restrict__ C, int M, int N, int K)
{
    __shared__ unsigned short As[GT * GK];
    __shared__ unsigned short Bs[GT * GK];

    const int tid  = threadIdx.x;
    const int w    = tid >> 6;
    const int lane = tid & 63;
    const int wr   = w >> 1, wc = w & 1;
    const int row0 = blockIdx.y * GT;
    const int col0 = blockIdx.x * GT;

    floatx4 acc[4][4];
    #pragma unroll
    for (int i = 0; i < 4; i++)
        #pragma unroll
        for (int j = 0; j < 4; j++)
            acc[i][j] = (floatx4){0.f, 0.f, 0.f, 0.f};

    const int srow  = lane >> 2;
    const int skoff = (lane & 3) * 8;
    const int fm = lane & 15;
    const int fk = (lane >> 4) * 8;

    for (int k0 = 0; k0 < K; k0 += GK) {
        #pragma unroll
        for (int t = 0; t < 2; t++) {
            const int c = w * 2 + t;
            async_load16(A  + (size_t)(row0 + c * 16 + srow) * K + k0 + skoff, (char*)As + c * 1024);
            async_load16(Bt + (size_t)(col0 + c * 16 + srow) * K + k0 + skoff, (char*)Bs + c * 1024);
        }
        __syncthreads();

        short8 af[4], bf[4];
        #pragma unroll
        for (int i = 0; i < 4; i++) {
            af[i] = *(const short8*)&As[(wr * 64 + i * 16 + fm) * GK + fk];
            bf[i] = *(const short8*)&Bs[(wc * 64 + i * 16 + fm) * GK + fk];
        }
        #pragma unroll
        for (int i = 0; i < 4; i++)
            #pragma unroll
            for (int j = 0; j < 4; j++)
                acc[i][j] = __builtin_amdgcn_mfma_f32_16x16x32_bf16(af[i], bf[j], acc[i][j], 0, 0, 0);
        __syncthreads();
    }

    const int quad = lane >> 4;
    #pragma unroll
    for (int i = 0; i < 4; i++)
        #pragma unroll
        for (int j = 0; j < 4; j++) {
            const size_t base = (size_t)(row0 + wr * 64 + i * 16 + quad * 4) * N
                              + col0 + wc * 64 + j * 16 + fm;
            #pragma unroll
            for (int r = 0; r < 4; r++)
                C[base + (size_t)r * N] = acc[i][j][r];
        }
}

// ======================= V projection GEMM + fused Vt epilogue =======================
// Plain bf16 GEMM (A=xh, B=wvT), but instead of writing fp32 V then running prep_v,
// the epilogue transposes acc in LDS (aliased over As/Bs, safe post-barrier) and
// writes the attn kernel's Vt layout directly: tile (bh,ktile) of [d][key'] with
// chunk swizzle cs = (key>>3) ^ (d&7). Eliminates 64 MB fp32 roundtrip + a dispatch.
__global__ __launch_bounds__(256) void gemm_v_vt(
    const unsigned short* __restrict__ A,
    const unsigned short* __restrict__ Bt,
    unsigned short* __restrict__ Vt, int K)
{
    __shared__ char smem[2 * 128 * 72 * 2] __attribute__((aligned(16)));  // 36 KB
    unsigned short* As = (unsigned short*)smem;                // 8 KB (K-loop)
    unsigned short* Bs = (unsigned short*)(smem + 8192);       // 8 KB (K-loop)
    typedef unsigned short stage_row[72];
    stage_row* stage0 = (stage_row*)smem;                      // [2][128][72] (epilogue)

    const int tid  = threadIdx.x;
    const int w    = tid >> 6;
    const int lane = tid & 63;
    const int wr   = w >> 1, wc = w & 1;
    const int row0 = blockIdx.y * GT;
    const int col0 = blockIdx.x * GT;

    floatx4 acc[4][4];
    #pragma unroll
    for (int i = 0; i < 4; i++)
        #pragma unroll
        for (int j = 0; j < 4; j++)
            acc[i][j] = (floatx4){0.f, 0.f, 0.f, 0.f};

    const int srow  = lane >> 2;
    const int skoff = (lane & 3) * 8;
    const int fm = lane & 15;
    const int fk = (lane >> 4) * 8;

    for (int k0 = 0; k0 < K; k0 += GK) {
        #pragma unroll
        for (int t = 0; t < 2; t++) {
            const int c = w * 2 + t;
            async_load16(A  + (size_t)(row0 + c * 16 + srow) * K + k0 + skoff, (char*)As + c * 1024);
            async_load16(Bt + (size_t)(col0 + c * 16 + srow) * K + k0 + skoff, (char*)Bs + c * 1024);
        }
        __syncthreads();

        short8 af[4], bf[4];
        #pragma unroll
        for (int i = 0; i < 4; i++) {
            af[i] = *(const short8*)&As[(wr * 64 + i * 16 + fm) * GK + fk];
            bf[i] = *(const short8*)&Bs[(wc * 64 + i * 16 + fm) * GK + fk];
        }
        #pragma unroll
        for (int i = 0; i < 4; i++)
            #pragma unroll
            for (int j = 0; j < 4; j++)
                acc[i][j] = __builtin_amdgcn_mfma_f32_16x16x32_bf16(af[i], bf[j], acc[i][j], 0, 0, 0);
        __syncthreads();   // also makes As/Bs dead -> stage aliasing safe
    }

    // ---- fused epilogue: transpose to Vt layout ----
    const int quad = lane >> 4;
    const int b  = row0 >> 11;            // batch (128 | 2048, no straddle)
    const int h  = col0 >> 7;             // head (GT == HD)
    const int bh = b * NH + h;
    const int kt_base = (row0 & 2047) >> 6;

    // fill: stage[wr][d][key]  (key = local row within this wave's 64-row half)
    #pragma unroll
    for (int i = 0; i < 4; i++)
        #pragma unroll
        for (int r = 0; r < 4; r++) {
            const int key = i * 16 + quad * 4 + r;           // 0..63
            #pragma unroll
            for (int j = 0; j < 4; j++) {
                const int d = wc * 64 + j * 16 + fm;
                stage0[wr * 128 + d][key] = bf16_bits(acc[i][j][r]);
            }
        }
    __syncthreads();

    // write-out: mirror prep_v exactly
    const int d = tid >> 1, half = tid & 1;
    #pragma unroll
    for (int kt = 0; kt < 2; kt++) {
        const size_t ob = ((size_t)(bh * 32 + kt_base + kt)) * 8192 + (size_t)d * 64;
        #pragma unroll
        for (int cc = 0; cc < 4; cc++) {
            const int cs = half * 4 + cc;
            const int kb = (cs ^ (d & 7)) << 3;
            *(short8*)&Vt[ob + cs * 8] = *(const short8*)&stage0[kt * 128 + d][kb];
        }
    }
}

// ======================= split GEMM + fused RMSNorm epilogue (Q and K, z-fused) =======================
// blockIdx.z selects Q (z=0) or K (z=1). K-loop byte-identical to the proven
// gemm_bf16_split. Epilogue: GT=128=HD so each block's 128 output columns are one
// head's d-range; row-wise sum-of-squares via 16-lane shfl tree + LDS exchange,
// then RMSNorm + bf16 hi/lo split + head-major relayout written directly.
__global__ __launch_bounds__(256) void gemm_qk_rms(
    const unsigned short* __restrict__ Ah, const unsigned short* __restrict__ Al,
    const unsigned short* __restrict__ BqH, const unsigned short* __restrict__ BqL,
    const unsigned short* __restrict__ BkH, const unsigned short* __restrict__ BkL,
    const float* __restrict__ q_scale, const float* __restrict__ k_scale,
    unsigned short* __restrict__ Qh, unsigned short* __restrict__ Ql,
    unsigned short* __restrict__ Kh, unsigned short* __restrict__ Kl,
    int K)
{
    __shared__ unsigned short AsH[GT * GK], AsL[GT * GK];
    __shared__ unsigned short BsH[GT * GK], BsL[GT * GK];
    __shared__ float ws2[2][GT];

    const int z = blockIdx.z;
    const unsigned short* __restrict__ Bh = z ? BkH : BqH;
    const unsigned short* __restrict__ Bl = z ? BkL : BqL;
    const float* __restrict__ scale = z ? k_scale : q_scale;
    unsigned short* __restrict__ hi = z ? Kh : Qh;
    unsigned short* __restrict__ lo = z ? Kl : Ql;
    const int swz = z;

    const int tid  = threadIdx.x;
    const int w    = tid >> 6;
    const int lane = tid & 63;
    const int wr   = w >> 1, wc = w & 1;
    const int row0 = blockIdx.y * GT;
    const int col0 = blockIdx.x * GT;

    floatx4 acc[4][4];
    #pragma unroll
    for (int i = 0; i < 4; i++)
        #pragma unroll
        for (int j = 0; j < 4; j++)
            acc[i][j] = (floatx4){0.f, 0.f, 0.f, 0.f};

    const int srow  = lane >> 2;
    const int skoff = (lane & 3) * 8;
    const int fm = lane & 15;
    const int fk = (lane >> 4) * 8;

    for (int k0 = 0; k0 < K; k0 += GK) {
        #pragma unroll
        for (int t = 0; t < 2; t++) {
            const int c = w * 2 + t;
            const size_t ao = (size_t)(row0 + c * 16 + srow) * K + k0 + skoff;
            const size_t bo = (size_t)(col0 + c * 16 + srow) * K + k0 + skoff;
            async_load16(Ah + ao, (char*)AsH + c * 1024);
            async_load16(Al + ao, (char*)AsL + c * 1024);
            async_load16(Bh + bo, (char*)BsH + c * 1024);
            async_load16(Bl + bo, (char*)BsL + c * 1024);
        }
        __syncthreads();

        short8 afh[4], afl[4], bfh[4], bfl[4];
        #pragma unroll
        for (int i = 0; i < 4; i++) {
            const int arow = (wr * 64 + i * 16 + fm) * GK + fk;
            const int brow = (wc * 64 + i * 16 + fm) * GK + fk;
            afh[i] = *(const short8*)&AsH[arow];
            afl[i] = *(const short8*)&AsL[arow];
            bfh[i] = *(const short8*)&BsH[brow];
            bfl[i] = *(const short8*)&BsL[brow];
        }
        #pragma unroll
        for (int i = 0; i < 4; i++)
            #pragma unroll
            for (int j = 0; j < 4; j++) {
                acc[i][j] = __builtin_amdgcn_mfma_f32_16x16x32_bf16(afh[i], bfh[j], acc[i][j], 0, 0, 0);
                acc[i][j] = __builtin_amdgcn_mfma_f32_16x16x32_bf16(afh[i], bfl[j], acc[i][j], 0, 0, 0);
                acc[i][j] = __builtin_amdgcn_mfma_f32_16x16x32_bf16(afl[i], bfh[j], acc[i][j], 0, 0, 0);
            }
        __syncthreads();
    }

    // ---- fused epilogue ----
    const int quad = lane >> 4;

    float sq[4][4];
    #pragma unroll
    for (int i = 0; i < 4; i++)
        #pragma unroll
        for (int r = 0; r < 4; r++) {
            float s2 = 0.f;
            #pragma unroll
            for (int j = 0; j < 4; j++) s2 += acc[i][j][r] * acc[i][j][r];
            s2 += __shfl_xor(s2, 1);
            s2 += __shfl_xor(s2, 2);
            s2 += __shfl_xor(s2, 4);
            s2 += __shfl_xor(s2, 8);
            sq[i][r] = s2;
        }
    if (fm == 0) {
        #pragma unroll
        for (int i = 0; i < 4; i++)
            #pragma unroll
            for (int r = 0; r < 4; r++)
                ws2[wc][wr * 64 + i * 16 + quad * 4 + r] = sq[i][r];
    }
    __syncthreads();

    const int hh = col0 >> 7;   // head index (GT == HD)
    float scv[4];
    #pragma unroll
    for (int j = 0; j < 4; j++) scv[j] = scale[wc * 64 + j * 16 + fm];

    #pragma unroll
    for (int i = 0; i < 4; i++)
        #pragma unroll
        for (int r = 0; r < 4; r++) {
            const int lrow = wr * 64 + i * 16 + quad * 4 + r;
            const int row  = row0 + lrow;            // global m = b*SEQ + s
            const int bb = row >> 11, s = row & 2047;
            const float inv = rsqrtf((ws2[0][lrow] + ws2[1][lrow]) * (1.0f / HD) + 1e-6f);
            const size_t ob = ((size_t)(bb * NH + hh) * SEQ + s) * 128;
            #pragma unroll
            for (int j = 0; j < 4; j++) {
                const int d = wc * 64 + j * 16 + fm;
                const float val = acc[i][j][r] * inv * scv[j];
                unsigned short hb, lb;
                split_bf16(val, hb, lb);
                const int dd = swz ? ((((d >> 3) ^ (s & 15)) << 3) | (d & 7)) : d;
                hi[ob + dd] = hb;
                lo[ob + dd] = lb;
            }
        }
}

// ======================= casts / weight prep =======================
__global__ __launch_bounds__(256) void cast_split_f32(
    const float* __restrict__ in, unsigned short* __restrict__ hi,
    unsigned short* __restrict__ lo, int n)
{
    int i = (blockIdx.x * 256 + threadIdx.x) * 4;
    if (i >= n) return;
    float4 v = *(const float4*)&in[i];
    ushort4 h, l;
    split_bf16(v.x, h.x, l.x);
    split_bf16(v.y, h.y, l.y);
    split_bf16(v.z, h.z, l.z);
    split_bf16(v.w, h.w, l.w);
    *(ushort4*)&hi[i] = h;
    *(ushort4*)&lo[i] = l;
}

// all four weight transposes (wq/wk split, wv/wo plain) in ONE dispatch, z-selected.
// All matrices are 2048x2048; blocks are uniform in z so the branch is free.
__global__ __launch_bounds__(256) void prep_weights(
    const float* __restrict__ wq, const float* __restrict__ wk,
    const float* __restrict__ wv, const float* __restrict__ wo,
    unsigned short* __restrict__ wqTh, unsigned short* __restrict__ wqTl,
    unsigned short* __restrict__ wkTh, unsigned short* __restrict__ wkTl,
    unsigned short* __restrict__ wvT, unsigned short* __restrict__ woT)
{
    __shared__ float tile[32][33];
    const int z = blockIdx.z;
    const int KK = 2048;
    const float* __restrict__ W = (z == 0) ? wq : (z == 1) ? wk : (z == 2) ? wv : wo;
    const int k0 = blockIdx.y * 32, n0 = blockIdx.x * 32;
    const int tx = threadIdx.x, ty = threadIdx.y;
    #pragma unroll
    for (int i = 0; i < 4; i++)
        tile[ty + i * 8][tx] = W[(size_t)(k0 + ty + i * 8) * 2048 + n0 + tx];
    __syncthreads();
    if (z < 2) {
        unsigned short* __restrict__ th = z ? wkTh : wqTh;
        unsigned short* __restrict__ tl = z ? wkTl : wqTl;
        #pragma unroll
        for (int i = 0; i < 4; i++) {
            unsigned short h, l;
            split_bf16(tile[tx][ty + i * 8], h, l);
            size_t idx = (size_t)(n0 + ty + i * 8) * KK + k0 + tx;
            th[idx] = h;
            tl[idx] = l;
        }
    } else {
        unsigned short* __restrict__ t = (z == 2) ? wvT : woT;
        #pragma unroll
        for (int i = 0; i < 4; i++)
            t[(size_t)(n0 + ty + i * 8) * KK + k0 + tx] = bf16_bits(tile[tx][ty + i * 8]);
    }
}

// ======================= MFMA flash attention v4 (verbatim round-0) =======================
// 512 threads = 8 waves (2/SIMD for latency hiding), ATQ=256 (32 q-rows/wave),
// double-buffered KV staging, ONE barrier per tile. Grid (8, 32) = 256 blocks = 1/CU.
// NO setprio / NO defer-max: performance rests on undisturbed MFMA/VALU wave
// co-scheduling (v5-v9 all regressed when this schedule was perturbed).
#define ATQ 256
#define ATK 64

__global__ __launch_bounds__(512, 1) void attn4(
    const unsigned short* __restrict__ Qh, const unsigned short* __restrict__ Ql,
    const unsigned short* __restrict__ Kh, const unsigned short* __restrict__ Kl,
    const unsigned short* __restrict__ Vt, __hip_bfloat16* __restrict__ AO)
{
    __shared__ unsigned short KsH[2][ATK * 128];   // 32 KB  [key][d'] (chunk ^= key&15)
    __shared__ unsigned short KsL[2][ATK * 128];   // 32 KB
    __shared__ unsigned short Vts[2][HD * 64];     // 32 KB  [d][key'] (chunk ^= d&7)
    __shared__ unsigned short Ps[ATQ * 64];        // 32 KB  P[row][key'] (chunk ^= row&7)

    const int tid  = threadIdx.x;
    const int w    = tid >> 6;        // 0..7
    const int lane = tid & 63;
    const int quad = lane >> 4;
    const int fm   = lane & 15;
    const int bh = blockIdx.y;
    const int b = bh >> 4, h = bh & 15;
    const int q0 = blockIdx.x * ATQ;

    const size_t hbase = (size_t)(b * NH + h) * SEQ;

    // ---- Q fragments (pre-split bf16); wave owns rows w*32..w*32+31 ----
    short8 qh[2][4], ql[2][4];
    #pragma unroll
    for (int i = 0; i < 2; i++) {
        const size_t row = hbase + q0 + w * 32 + i * 16 + fm;
        #pragma unroll
        for (int kc = 0; kc < 4; kc++) {
            const size_t off = row * 128 + kc * 32 + quad * 8;
            qh[i][kc] = *(const short8*)&Qh[off];
            ql[i][kc] = *(const short8*)&Ql[off];
        }
    }

    floatx4 oacc[2][8];
    #pragma unroll
    for (int i = 0; i < 2; i++)
        #pragma unroll
        for (int df = 0; df < 8; df++)
            oacc[i][df] = (floatx4){0.f, 0.f, 0.f, 0.f};
    float m_[2][4], l_[2][4];
    #pragma unroll
    for (int i = 0; i < 2; i++)
        #pragma unroll
        for (int r = 0; r < 4; r++) { m_[i][r] = -1e30f; l_[i][r] = 0.f; }

    const unsigned short* gkh0 = Kh + hbase * 128;
    const unsigned short* gkl0 = Kl + hbase * 128;
    const unsigned short* gvt0 = Vt + (size_t)bh * 32 * 8192;

    // staging: 48 chunks of 1 KB (KsH 16, KsL 16, Vts 16); wave w -> chunks w*6..w*6+5
    const int ch0 = w * 6;

    // ---- prologue: stage tile 0 into buffer 0 ----
    #pragma unroll
    for (int c = 0; c < 6; c++) {
        const int ch = ch0 + c;
        const size_t go = (size_t)(ch & 15) * 512 + lane * 8;
        if (ch < 16)      async_load16(gkh0 + go, (char*)KsH[0] + ch * 1024);
        else if (ch < 32) async_load16(gkl0 + go, (char*)KsL[0] + (ch - 16) * 1024);
        else              async_load16(gvt0 + go, (char*)Vts[0] + (ch - 32) * 1024);
    }
    __syncthreads();   // drain: tile 0 staged

    for (int ktile = 0; ktile < SEQ / ATK; ktile++) {
        const int cur = ktile & 1;

        // ---- prefetch tile t+1 into other buffer (drained by end-of-tile barrier) ----
        if (ktile + 1 < SEQ / ATK) {
            const unsigned short* gkh = gkh0 + (size_t)(ktile + 1) * ATK * 128;
            const unsigned short* gkl = gkl0 + (size_t)(ktile + 1) * ATK * 128;
            const unsigned short* gvt = gvt0 + (size_t)(ktile + 1) * 8192;
            #pragma unroll
            for (int c = 0; c < 6; c++) {
                const int ch = ch0 + c;
                const size_t go = (size_t)(ch & 15) * 512 + lane * 8;
                if (ch < 16)      async_load16(gkh + go, (char*)KsH[1 - cur] + ch * 1024);
                else if (ch < 32) async_load16(gkl + go, (char*)KsL[1 - cur] + (ch - 16) * 1024);
                else              async_load16(gvt + go, (char*)Vts[1 - cur] + (ch - 32) * 1024);
            }
        }

        // ---- S = Q K^T (3-term hi/lo) from buffer cur ----
        floatx4 sacc[2][4];
        #pragma unroll
        for (int i = 0; i < 2; i++)
            #pragma unroll
            for (int jf = 0; jf < 4; jf++)
                sacc[i][jf] = (floatx4){0.f, 0.f, 0.f, 0.f};
        #pragma unroll
        for (int kc = 0; kc < 4; kc++)
            #pragma unroll
            for (int jf = 0; jf < 4; jf++) {
                const int koff = (jf * 16 + fm) * 128 + (((kc * 4 + quad) ^ fm) << 3);
                short8 kh8 = *(const short8*)&KsH[cur][koff];
                short8 kl8 = *(const short8*)&KsL[cur][koff];
                #pragma unroll
                for (int i = 0; i < 2; i++) {
                    sacc[i][jf] = __builtin_amdgcn_mfma_f32_16x16x32_bf16(qh[i][kc], kh8, sacc[i][jf], 0, 0, 0);
                    sacc[i][jf] = __builtin_amdgcn_mfma_f32_16x16x32_bf16(qh[i][kc], kl8, sacc[i][jf], 0, 0, 0);
                    sacc[i][jf] = __builtin_amdgcn_mfma_f32_16x16x32_bf16(ql[i][kc], kh8, sacc[i][jf], 0, 0, 0);
                }
            }

        // ---- online softmax (registers) ----
        float alpha_[2][4];
        #pragma unroll
        for (int i = 0; i < 2; i++)
            #pragma unroll
            for (int r = 0; r < 4; r++) {
                float mx = fmaxf(fmaxf(sacc[i][0][r], sacc[i][1][r]),
                                 fmaxf(sacc[i][2][r], sacc[i][3][r]));
                mx = fmaxf(mx, __shfl_xor(mx, 1));
                mx = fmaxf(mx, __shfl_xor(mx, 2));
                mx = fmaxf(mx, __shfl_xor(mx, 4));
                mx = fmaxf(mx, __shfl_xor(mx, 8));
                const float mold = m_[i][r];
                const float mnew = fmaxf(mold, mx);
                const float al = __expf(mold - mnew);
                m_[i][r] = mnew;
                alpha_[i][r] = al;
                float rs = 0.f;
                #pragma unroll
                for (int jf = 0; jf < 4; jf++) {
                    float p = __expf(sacc[i][jf][r] - mnew);
                    sacc[i][jf][r] = p;
                    rs += p;
                }
                rs += __shfl_xor(rs, 1);
                rs += __shfl_xor(rs, 2);
                rs += __shfl_xor(rs, 4);
                rs += __shfl_xor(rs, 8);
                l_[i][r] = l_[i][r] * al + rs;
            }
        #pragma unroll
        for (int i = 0; i < 2; i++)
            #pragma unroll
            for (int df = 0; df < 8; df++)
                #pragma unroll
                for (int r = 0; r < 4; r++)
                    oacc[i][df][r] *= alpha_[i][r];

        // ---- P -> bf16 into Ps (own rows; wave-local ordering, no barrier) ----
        #pragma unroll
        for (int i = 0; i < 2; i++)
            #pragma unroll
            for (int jf = 0; jf < 4; jf++)
                #pragma unroll
                for (int r = 0; r < 4; r++) {
                    const int row = w * 32 + i * 16 + quad * 4 + r;
                    const int chunk = jf * 2 + (fm >> 3);
                    const int colp = ((chunk ^ (row & 7)) << 3) | (fm & 7);
                    Ps[row * 64 + colp] = bf16_bits(sacc[i][jf][r]);
                }

        // ---- O += P V from buffer cur ----
        #pragma unroll
        for (int kc2 = 0; kc2 < 2; kc2++) {
            short8 ap[2];
            #pragma unroll
            for (int i = 0; i < 2; i++) {
                const int row = w * 32 + i * 16 + fm;
                ap[i] = *(const short8*)&Ps[row * 64 + (((kc2 * 4 + quad) ^ (row & 7)) << 3)];
            }
            #pragma unroll
            for (int df = 0; df < 8; df++) {
                const int d = df * 16 + fm;
                short8 bv = *(const short8*)&Vts[cur][d * 64 + (((kc2 * 4 + quad) ^ (d & 7)) << 3)];
                #pragma unroll
                for (int i = 0; i < 2; i++)
                    oacc[i][df] = __builtin_amdgcn_mfma_f32_16x16x32_bf16(ap[i], bv, oacc[i][df], 0, 0, 0);
            }
        }

        // single barrier per tile: drains prefetch + protects buffer swap
        __syncthreads();
    }

    // ---- epilogue: AO bf16 [b,s,h,d] ----
    const size_t obase = ((size_t)b * SEQ * NH + h) * HD;
    const size_t rstr = (size_t)NH * HD;
    float linv[2][4];
    #pragma unroll
    for (int i = 0; i < 2; i++)
        #pragma unroll
        for (int r = 0; r < 4; r++) linv[i][r] = 1.0f / l_[i][r];
    #pragma unroll
    for (int i = 0; i < 2; i++)
        #pragma unroll
        for (int df = 0; df < 8; df++)
            #pragma unroll
            for (int r = 0; r < 4; r++) {
                const int row = q0 + w * 32 + i * 16 + quad * 4 + r;
                const int d = df * 16 + fm;
                AO[obase + (size_t)row * rstr + d] = __float2bfloat16(oacc[i][df][r] * linv[i][r]);
            }
}

// ======================= launch =======================
extern "C" void kernel_launch(void* const* d_in, const int* in_sizes, int n_in,
                              void* d_out, int out_size, void* d_ws, size_t ws_size,
                              hipStream_t stream) {
    const float* x  = (const float*)d_in[0];
    const float* wq = (const float*)d_in[1];
    const float* wk = (const float*)d_in[2];
    const float* wv = (const float*)d_in[3];
    const float* wo = (const float*)d_in[4];
    const float* q_scale = (const float*)d_in[5];
    const float* k_scale = (const float*)d_in[6];
    float* out = (float*)d_out;

    const size_t T = (size_t)BATCH * SEQ * NH * HD;   // 8388608
    const size_t W = (size_t)EMB * NH * HD;           // 4194304

    unsigned short* xh   = (unsigned short*)d_ws;
    unsigned short* xl   = xh + T;
    unsigned short* aob  = xl + T;
    unsigned short* Qh   = aob + T;
    unsigned short* Ql   = Qh + T;
    unsigned short* Kh   = Ql + T;
    unsigned short* Kl   = Kh + T;
    unsigned short* Vtb  = Kl + T;
    unsigned short* wqTh = Vtb + T;
    unsigned short* wqTl = wqTh + W;
    unsigned short* wkTh = wqTl + W;
    unsigned short* wkTl = wkTh + W;
    unsigned short* wvT  = wkTl + W;
    unsigned short* woT  = wvT + W;

    const int M = BATCH * SEQ;   // 4096
    const int N = NH * HD;       // 2048
    const int K = EMB;           // 2048

    cast_split_f32<<<(int)(T / 4 + 255) / 256, 256, 0, stream>>>(x, xh, xl, (int)T);
    prep_weights<<<dim3(64, 64, 4), dim3(32, 8), 0, stream>>>(
        wq, wk, wv, wo, wqTh, wqTl, wkTh, wkTl, wvT, woT);

    // Q and K projections (z-fused) with fused RMSNorm + split + relayout epilogue
    gemm_qk_rms<<<dim3(N / GT, M / GT, 2), 256, 0, stream>>>(
        xh, xl, wqTh, wqTl, wkTh, wkTl, q_scale, k_scale, Qh, Ql, Kh, Kl, K);
    // V projection with fused Vt-transpose epilogue (replaces V GEMM + prep_v)
    gemm_v_vt<<<dim3(N / GT, M / GT), 256, 0, stream>>>(xh, wvT, Vtb, K);

    attn4<<<dim3(SEQ / ATQ, BATCH * NH), 512, 0, stream>>>(Qh, Ql, Kh, Kl, Vtb, (__hip_bfloat16*)aob);

    gemm_bf16<<<dim3(EMB / GT, M / GT), 256, 0, stream>>>(aob, woT, out, M, EMB, NH * HD);
}

// Round 9
// 598.136 us; speedup vs baseline: 1.6616x; 1.1496x over previous
//
#include <hip/hip_runtime.h>
#include <hip/hip_bf16.h>
#include <math.h>

#define BATCH 2
#define SEQ   2048
#define EMB   2048
#define NH    16
#define HD    128

typedef __attribute__((ext_vector_type(8))) short short8;
typedef __attribute__((ext_vector_type(8))) _Float16 half8;
typedef __attribute__((ext_vector_type(4))) float floatx4;

__device__ inline void async_load16(const void* g, void* l) {
    __builtin_amdgcn_global_load_lds(
        (const __attribute__((address_space(1))) unsigned int*)g,
        (__attribute__((address_space(3))) unsigned int*)l, 16, 0, 0);
}

__device__ inline unsigned short bf16_bits(float f) {
    __hip_bfloat16 b = __float2bfloat16(f);
    return *(unsigned short*)&b;
}
__device__ inline unsigned short fp16_bits(float f) {
    _Float16 h = (_Float16)f;
    return *(unsigned short*)&h;
}
__device__ inline void split_bf16(float f, unsigned short& h, unsigned short& l) {
    __hip_bfloat16 hb = __float2bfloat16(f);
    h = *(unsigned short*)&hb;
    float r = f - __bfloat162float(hb);
    __hip_bfloat16 lb = __float2bfloat16(r);
    l = *(unsigned short*)&lb;
}

// ======================= plain bf16 MFMA GEMM (m97 structure) — out projection =======================
#define GT 128
#define GK 32

__global__ __launch_bounds__(256) void gemm_bf16(
    const unsigned short* __restrict__ A,
    const unsigned short* __restrict__ Bt,
    float* __restrict__ C, int M, int N, int K)
{
    __shared__ unsigned short As[GT * GK];
    __shared__ unsigned short Bs[GT * GK];

    const int tid  = threadIdx.x;
    const int w    = tid >> 6;
    const int lane = tid & 63;
    const int wr   = w >> 1, wc = w & 1;
    const int row0 = blockIdx.y * GT;
    const int col0 = blockIdx.x * GT;

    floatx4 acc[4][4];
    #pragma unroll
    for (int i = 0; i < 4; i++)
        #pragma unroll
        for (int j = 0; j < 4; j++)
            acc[i][j] = (floatx4){0.f, 0.f, 0.f, 0.f};

    const int srow  = lane >> 2;
    const int skoff = (lane & 3) * 8;
    const int fm = lane & 15;
    const int fk = (lane >> 4) * 8;

    for (int k0 = 0; k0 < K; k0 += GK) {
        #pragma unroll
        for (int t = 0; t < 2; t++) {
            const int c = w * 2 + t;
            async_load16(A  + (size_t)(row0 + c * 16 + srow) * K + k0 + skoff, (char*)As + c * 1024);
            async_load16(Bt + (size_t)(col0 + c * 16 + srow) * K + k0 + skoff, (char*)Bs + c * 1024);
        }
        __syncthreads();

        short8 af[4], bf[4];
        #pragma unroll
        for (int i = 0; i < 4; i++) {
            af[i] = *(const short8*)&As[(wr * 64 + i * 16 + fm) * GK + fk];
            bf[i] = *(const short8*)&Bs[(wc * 64 + i * 16 + fm) * GK + fk];
        }
        #pragma unroll
        for (int i = 0; i < 4; i++)
            #pragma unroll
            for (int j = 0; j < 4; j++)
                acc[i][j] = __builtin_amdgcn_mfma_f32_16x16x32_bf16(af[i], bf[j], acc[i][j], 0, 0, 0);
        __syncthreads();
    }

    const int quad = lane >> 4;
    #pragma unroll
    for (int i = 0; i < 4; i++)
        #pragma unroll
        for (int j = 0; j < 4; j++) {
            const size_t base = (size_t)(row0 + wr * 64 + i * 16 + quad * 4) * N
                              + col0 + wc * 64 + j * 16 + fm;
            #pragma unroll
            for (int r = 0; r < 4; r++)
                C[base + (size_t)r * N] = acc[i][j][r];
        }
}

// ======================= fp16 V projection GEMM + fused Vt epilogue =======================
// Single-term fp16 GEMM (A=xf, B=wvF — MORE accurate than the old truncated-bf16-x form).
// Epilogue transposes acc in LDS (aliased over As/Bs, safe post-barrier) and writes
// the attn kernel's Vt layout directly: tile (bh,ktile) of [d][key'], cs = (key>>3)^(d&7).
__global__ __launch_bounds__(256) void gemm_v_vt(
    const unsigned short* __restrict__ A,
    const unsigned short* __restrict__ Bt,
    unsigned short* __restrict__ Vt, int K)
{
    __shared__ char smem[2 * 128 * 72 * 2] __attribute__((aligned(16)));  // 36 KB
    unsigned short* As = (unsigned short*)smem;                // 8 KB (K-loop)
    unsigned short* Bs = (unsigned short*)(smem + 8192);       // 8 KB (K-loop)
    typedef unsigned short stage_row[72];
    stage_row* stage0 = (stage_row*)smem;                      // [2][128][72] (epilogue)

    const int tid  = threadIdx.x;
    const int w    = tid >> 6;
    const int lane = tid & 63;
    const int wr   = w >> 1, wc = w & 1;
    const int row0 = blockIdx.y * GT;
    const int col0 = blockIdx.x * GT;

    floatx4 acc[4][4];
    #pragma unroll
    for (int i = 0; i < 4; i++)
        #pragma unroll
        for (int j = 0; j < 4; j++)
            acc[i][j] = (floatx4){0.f, 0.f, 0.f, 0.f};

    const int srow  = lane >> 2;
    const int skoff = (lane & 3) * 8;
    const int fm = lane & 15;
    const int fk = (lane >> 4) * 8;

    for (int k0 = 0; k0 < K; k0 += GK) {
        #pragma unroll
        for (int t = 0; t < 2; t++) {
            const int c = w * 2 + t;
            async_load16(A  + (size_t)(row0 + c * 16 + srow) * K + k0 + skoff, (char*)As + c * 1024);
            async_load16(Bt + (size_t)(col0 + c * 16 + srow) * K + k0 + skoff, (char*)Bs + c * 1024);
        }
        __syncthreads();

        half8 af[4], bf[4];
        #pragma unroll
        for (int i = 0; i < 4; i++) {
            af[i] = *(const half8*)&As[(wr * 64 + i * 16 + fm) * GK + fk];
            bf[i] = *(const half8*)&Bs[(wc * 64 + i * 16 + fm) * GK + fk];
        }
        #pragma unroll
        for (int i = 0; i < 4; i++)
            #pragma unroll
            for (int j = 0; j < 4; j++)
                acc[i][j] = __builtin_amdgcn_mfma_f32_16x16x32_f16(af[i], bf[j], acc[i][j], 0, 0, 0);
        __syncthreads();   // also makes As/Bs dead -> stage aliasing safe
    }

    // ---- fused epilogue: transpose to Vt layout ----
    const int quad = lane >> 4;
    const int b  = row0 >> 11;            // batch (128 | 2048, no straddle)
    const int h  = col0 >> 7;             // head (GT == HD)
    const int bh = b * NH + h;
    const int kt_base = (row0 & 2047) >> 6;

    #pragma unroll
    for (int i = 0; i < 4; i++)
        #pragma unroll
        for (int r = 0; r < 4; r++) {
            const int key = i * 16 + quad * 4 + r;           // 0..63
            #pragma unroll
            for (int j = 0; j < 4; j++) {
                const int d = wc * 64 + j * 16 + fm;
                stage0[wr * 128 + d][key] = bf16_bits(acc[i][j][r]);
            }
        }
    __syncthreads();

    const int d = tid >> 1, half = tid & 1;
    #pragma unroll
    for (int kt = 0; kt < 2; kt++) {
        const size_t ob = ((size_t)(bh * 32 + kt_base + kt)) * 8192 + (size_t)d * 64;
        #pragma unroll
        for (int cc = 0; cc < 4; cc++) {
            const int cs = half * 4 + cc;
            const int kb = (cs ^ (d & 7)) << 3;
            *(short8*)&Vt[ob + cs * 8] = *(const short8*)&stage0[kt * 128 + d][kb];
        }
    }
}

// ======================= fp16 Q/K projection GEMM + fused RMSNorm epilogue (z-fused) =======================
// Single-term fp16 GEMM (operand error 2^-12, 10x below the pipeline's existing bf16
// error sources) replaces the 3-term bf16 hi/lo split: 1/3 the MFMA work, half the
// staging. blockIdx.z selects Q (z=0) or K (z=1). Epilogue (unchanged from v12):
// GT=128=HD so each block's columns are one head; row-wise sum-of-squares via shfl
// tree + LDS exchange, then RMSNorm + bf16 hi/lo split + head-major relayout.
__global__ __launch_bounds__(256) void gemm_qk_rms(
    const unsigned short* __restrict__ A,
    const unsigned short* __restrict__ Bq, const unsigned short* __restrict__ Bk,
    const float* __restrict__ q_scale, const float* __restrict__ k_scale,
    unsigned short* __restrict__ Qh, unsigned short* __restrict__ Ql,
    unsigned short* __restrict__ Kh, unsigned short* __restrict__ Kl,
    int K)
{
    __shared__ unsigned short As[GT * GK];
    __shared__ unsigned short Bs[GT * GK];
    __shared__ float ws2[2][GT];

    const int z = blockIdx.z;
    const unsigned short* __restrict__ Bt = z ? Bk : Bq;
    const float* __restrict__ scale = z ? k_scale : q_scale;
    unsigned short* __restrict__ hi = z ? Kh : Qh;
    unsigned short* __restrict__ lo = z ? Kl : Ql;
    const int swz = z;

    const int tid  = threadIdx.x;
    const int w    = tid >> 6;
    const int lane = tid & 63;
    const int wr   = w >> 1, wc = w & 1;
    const int row0 = blockIdx.y * GT;
    const int col0 = blockIdx.x * GT;

    floatx4 acc[4][4];
    #pragma unroll
    for (int i = 0; i < 4; i++)
        #pragma unroll
        for (int j = 0; j < 4; j++)
            acc[i][j] = (floatx4){0.f, 0.f, 0.f, 0.f};

    const int srow  = lane >> 2;
    const int skoff = (lane & 3) * 8;
    const int fm = lane & 15;
    const int fk = (lane >> 4) * 8;

    for (int k0 = 0; k0 < K; k0 += GK) {
        #pragma unroll
        for (int t = 0; t < 2; t++) {
            const int c = w * 2 + t;
            async_load16(A  + (size_t)(row0 + c * 16 + srow) * K + k0 + skoff, (char*)As + c * 1024);
            async_load16(Bt + (size_t)(col0 + c * 16 + srow) * K + k0 + skoff, (char*)Bs + c * 1024);
        }
        __syncthreads();

        half8 af[4], bf[4];
        #pragma unroll
        for (int i = 0; i < 4; i++) {
            af[i] = *(const half8*)&As[(wr * 64 + i * 16 + fm) * GK + fk];
            bf[i] = *(const half8*)&Bs[(wc * 64 + i * 16 + fm) * GK + fk];
        }
        #pragma unroll
        for (int i = 0; i < 4; i++)
            #pragma unroll
            for (int j = 0; j < 4; j++)
                acc[i][j] = __builtin_amdgcn_mfma_f32_16x16x32_f16(af[i], bf[j], acc[i][j], 0, 0, 0);
        __syncthreads();
    }

    // ---- fused epilogue (identical to v12) ----
    const int quad = lane >> 4;

    float sq[4][4];
    #pragma unroll
    for (int i = 0; i < 4; i++)
        #pragma unroll
        for (int r = 0; r < 4; r++) {
            float s2 = 0.f;
            #pragma unroll
            for (int j = 0; j < 4; j++) s2 += acc[i][j][r] * acc[i][j][r];
            s2 += __shfl_xor(s2, 1);
            s2 += __shfl_xor(s2, 2);
            s2 += __shfl_xor(s2, 4);
            s2 += __shfl_xor(s2, 8);
            sq[i][r] = s2;
        }
    if (fm == 0) {
        #pragma unroll
        for (int i = 0; i < 4; i++)
            #pragma unroll
            for (int r = 0; r < 4; r++)
                ws2[wc][wr * 64 + i * 16 + quad * 4 + r] = sq[i][r];
    }
    __syncthreads();

    const int hh = col0 >> 7;   // head index (GT == HD)
    float scv[4];
    #pragma unroll
    for (int j = 0; j < 4; j++) scv[j] = scale[wc * 64 + j * 16 + fm];

    #pragma unroll
    for (int i = 0; i < 4; i++)
        #pragma unroll
        for (int r = 0; r < 4; r++) {
            const int lrow = wr * 64 + i * 16 + quad * 4 + r;
            const int row  = row0 + lrow;            // global m = b*SEQ + s
            const int bb = row >> 11, s = row & 2047;
            const float inv = rsqrtf((ws2[0][lrow] + ws2[1][lrow]) * (1.0f / HD) + 1e-6f);
            const size_t ob = ((size_t)(bb * NH + hh) * SEQ + s) * 128;
            #pragma unroll
            for (int j = 0; j < 4; j++) {
                const int d = wc * 64 + j * 16 + fm;
                const float val = acc[i][j][r] * inv * scv[j];
                unsigned short hb, lb;
                split_bf16(val, hb, lb);
                const int dd = swz ? ((((d >> 3) ^ (s & 15)) << 3) | (d & 7)) : d;
                hi[ob + dd] = hb;
                lo[ob + dd] = lb;
            }
        }
}

// ======================= casts / weight prep =======================
__global__ __launch_bounds__(256) void cast_f16(
    const float* __restrict__ in, unsigned short* __restrict__ o, int n)
{
    int i = (blockIdx.x * 256 + threadIdx.x) * 4;
    if (i >= n) return;
    float4 v = *(const float4*)&in[i];
    ushort4 h;
    h.x = fp16_bits(v.x);
    h.y = fp16_bits(v.y);
    h.z = fp16_bits(v.z);
    h.w = fp16_bits(v.w);
    *(ushort4*)&o[i] = h;
}

// all four weight transposes in ONE dispatch, z-selected: wq/wk/wv -> fp16, wo -> bf16.
__global__ __launch_bounds__(256) void prep_weights(
    const float* __restrict__ wq, const float* __restrict__ wk,
    const float* __restrict__ wv, const float* __restrict__ wo,
    unsigned short* __restrict__ wqF, unsigned short* __restrict__ wkF,
    unsigned short* __restrict__ wvF, unsigned short* __restrict__ woT)
{
    __shared__ float tile[32][33];
    const int z = blockIdx.z;
    const float* __restrict__ W = (z == 0) ? wq : (z == 1) ? wk : (z == 2) ? wv : wo;
    const int k0 = blockIdx.y * 32, n0 = blockIdx.x * 32;
    const int tx = threadIdx.x, ty = threadIdx.y;
    #pragma unroll
    for (int i = 0; i < 4; i++)
        tile[ty + i * 8][tx] = W[(size_t)(k0 + ty + i * 8) * 2048 + n0 + tx];
    __syncthreads();
    if (z < 3) {
        unsigned short* __restrict__ t = (z == 0) ? wqF : (z == 1) ? wkF : wvF;
        #pragma unroll
        for (int i = 0; i < 4; i++)
            t[(size_t)(n0 + ty + i * 8) * 2048 + k0 + tx] = fp16_bits(tile[tx][ty + i * 8]);
    } else {
        #pragma unroll
        for (int i = 0; i < 4; i++)
            woT[(size_t)(n0 + ty + i * 8) * 2048 + k0 + tx] = bf16_bits(tile[tx][ty + i * 8]);
    }
}

// ======================= MFMA flash attention v4 (verbatim round-0) =======================
// 512 threads = 8 waves (2/SIMD for latency hiding), ATQ=256 (32 q-rows/wave),
// double-buffered KV staging, ONE barrier per tile. Grid (8, 32) = 256 blocks = 1/CU.
// NO setprio / NO defer-max: performance rests on undisturbed MFMA/VALU wave
// co-scheduling (v5-v9 all regressed when this schedule was perturbed).
#define ATQ 256
#define ATK 64

__global__ __launch_bounds__(512, 1) void attn4(
    const unsigned short* __restrict__ Qh, const unsigned short* __restrict__ Ql,
    const unsigned short* __restrict__ Kh, const unsigned short* __restrict__ Kl,
    const unsigned short* __restrict__ Vt, __hip_bfloat16* __restrict__ AO)
{
    __shared__ unsigned short KsH[2][ATK * 128];   // 32 KB  [key][d'] (chunk ^= key&15)
    __shared__ unsigned short KsL[2][ATK * 128];   // 32 KB
    __shared__ unsigned short Vts[2][HD * 64];     // 32 KB  [d][key'] (chunk ^= d&7)
    __shared__ unsigned short Ps[ATQ * 64];        // 32 KB  P[row][key'] (chunk ^= row&7)

    const int tid  = threadIdx.x;
    const int w    = tid >> 6;        // 0..7
    const int lane = tid & 63;
    const int quad = lane >> 4;
    const int fm   = lane & 15;
    const int bh = blockIdx.y;
    const int b = bh >> 4, h = bh & 15;
    const int q0 = blockIdx.x * ATQ;

    const size_t hbase = (size_t)(b * NH + h) * SEQ;

    // ---- Q fragments (pre-split bf16); wave owns rows w*32..w*32+31 ----
    short8 qh[2][4], ql[2][4];
    #pragma unroll
    for (int i = 0; i < 2; i++) {
        const size_t row = hbase + q0 + w * 32 + i * 16 + fm;
        #pragma unroll
        for (int kc = 0; kc < 4; kc++) {
            const size_t off = row * 128 + kc * 32 + quad * 8;
            qh[i][kc] = *(const short8*)&Qh[off];
            ql[i][kc] = *(const short8*)&Ql[off];
        }
    }

    floatx4 oacc[2][8];
    #pragma unroll
    for (int i = 0; i < 2; i++)
        #pragma unroll
        for (int df = 0; df < 8; df++)
            oacc[i][df] = (floatx4){0.f, 0.f, 0.f, 0.f};
    float m_[2][4], l_[2][4];
    #pragma unroll
    for (int i = 0; i < 2; i++)
        #pragma unroll
        for (int r = 0; r < 4; r++) { m_[i][r] = -1e30f; l_[i][r] = 0.f; }

    const unsigned short* gkh0 = Kh + hbase * 128;
    const unsigned short* gkl0 = Kl + hbase * 128;
    const unsigned short* gvt0 = Vt + (size_t)bh * 32 * 8192;

    // staging: 48 chunks of 1 KB (KsH 16, KsL 16, Vts 16); wave w -> chunks w*6..w*6+5
    const int ch0 = w * 6;

    // ---- prologue: stage tile 0 into buffer 0 ----
    #pragma unroll
    for (int c = 0; c < 6; c++) {
        const int ch = ch0 + c;
        const size_t go = (size_t)(ch & 15) * 512 + lane * 8;
        if (ch < 16)      async_load16(gkh0 + go, (char*)KsH[0] + ch * 1024);
        else if (ch < 32) async_load16(gkl0 + go, (char*)KsL[0] + (ch - 16) * 1024);
        else              async_load16(gvt0 + go, (char*)Vts[0] + (ch - 32) * 1024);
    }
    __syncthreads();   // drain: tile 0 staged

    for (int ktile = 0; ktile < SEQ / ATK; ktile++) {
        const int cur = ktile & 1;

        // ---- prefetch tile t+1 into other buffer (drained by end-of-tile barrier) ----
        if (ktile + 1 < SEQ / ATK) {
            const unsigned short* gkh = gkh0 + (size_t)(ktile + 1) * ATK * 128;
            const unsigned short* gkl = gkl0 + (size_t)(ktile + 1) * ATK * 128;
            const unsigned short* gvt = gvt0 + (size_t)(ktile + 1) * 8192;
            #pragma unroll
            for (int c = 0; c < 6; c++) {
                const int ch = ch0 + c;
                const size_t go = (size_t)(ch & 15) * 512 + lane * 8;
                if (ch < 16)      async_load16(gkh + go, (char*)KsH[1 - cur] + ch * 1024);
                else if (ch < 32) async_load16(gkl + go, (char*)KsL[1 - cur] + (ch - 16) * 1024);
                else              async_load16(gvt + go, (char*)Vts[1 - cur] + (ch - 32) * 1024);
            }
        }

        // ---- S = Q K^T (3-term hi/lo) from buffer cur ----
        floatx4 sacc[2][4];
        #pragma unroll
        for (int i = 0; i < 2; i++)
            #pragma unroll
            for (int jf = 0; jf < 4; jf++)
                sacc[i][jf] = (floatx4){0.f, 0.f, 0.f, 0.f};
        #pragma unroll
        for (int kc = 0; kc < 4; kc++)
            #pragma unroll
            for (int jf = 0; jf < 4; jf++) {
                const int koff = (jf * 16 + fm) * 128 + (((kc * 4 + quad) ^ fm) << 3);
                short8 kh8 = *(const short8*)&KsH[cur][koff];
                short8 kl8 = *(const short8*)&KsL[cur][koff];
                #pragma unroll
                for (int i = 0; i < 2; i++) {
                    sacc[i][jf] = __builtin_amdgcn_mfma_f32_16x16x32_bf16(qh[i][kc], kh8, sacc[i][jf], 0, 0, 0);
                    sacc[i][jf] = __builtin_amdgcn_mfma_f32_16x16x32_bf16(qh[i][kc], kl8, sacc[i][jf], 0, 0, 0);
                    sacc[i][jf] = __builtin_amdgcn_mfma_f32_16x16x32_bf16(ql[i][kc], kh8, sacc[i][jf], 0, 0, 0);
                }
            }

        // ---- online softmax (registers) ----
        float alpha_[2][4];
        #pragma unroll
        for (int i = 0; i < 2; i++)
            #pragma unroll
            for (int r = 0; r < 4; r++) {
                float mx = fmaxf(fmaxf(sacc[i][0][r], sacc[i][1][r]),
                                 fmaxf(sacc[i][2][r], sacc[i][3][r]));
                mx = fmaxf(mx, __shfl_xor(mx, 1));
                mx = fmaxf(mx, __shfl_xor(mx, 2));
                mx = fmaxf(mx, __shfl_xor(mx, 4));
                mx = fmaxf(mx, __shfl_xor(mx, 8));
                const float mold = m_[i][r];
                const float mnew = fmaxf(mold, mx);
                const float al = __expf(mold - mnew);
                m_[i][r] = mnew;
                alpha_[i][r] = al;
                float rs = 0.f;
                #pragma unroll
                for (int jf = 0; jf < 4; jf++) {
                    float p = __expf(sacc[i][jf][r] - mnew);
                    sacc[i][jf][r] = p;
                    rs += p;
                }
                rs += __shfl_xor(rs, 1);
                rs += __shfl_xor(rs, 2);
                rs += __shfl_xor(rs, 4);
                rs += __shfl_xor(rs, 8);
                l_[i][r] = l_[i][r] * al + rs;
            }
        #pragma unroll
        for (int i = 0; i < 2; i++)
            #pragma unroll
            for (int df = 0; df < 8; df++)
                #pragma unroll
                for (int r = 0; r < 4; r++)
                    oacc[i][df][r] *= alpha_[i][r];

        // ---- P -> bf16 into Ps (own rows; wave-local ordering, no barrier) ----
        #pragma unroll
        for (int i = 0; i < 2; i++)
            #pragma unroll
            for (int jf = 0; jf < 4; jf++)
                #pragma unroll
                for (int r = 0; r < 4; r++) {
                    const int row = w * 32 + i * 16 + quad * 4 + r;
                    const int chunk = jf * 2 + (fm >> 3);
                    const int colp = ((chunk ^ (row & 7)) << 3) | (fm & 7);
                    Ps[row * 64 + colp] = bf16_bits(sacc[i][jf][r]);
                }

        // ---- O += P V from buffer cur ----
        #pragma unroll
        for (int kc2 = 0; kc2 < 2; kc2++) {
            short8 ap[2];
            #pragma unroll
            for (int i = 0; i < 2; i++) {
                const int row = w * 32 + i * 16 + fm;
                ap[i] = *(const short8*)&Ps[row * 64 + (((kc2 * 4 + quad) ^ (row & 7)) << 3)];
            }
            #pragma unroll
            for (int df = 0; df < 8; df++) {
                const int d = df * 16 + fm;
                short8 bv = *(const short8*)&Vts[cur][d * 64 + (((kc2 * 4 + quad) ^ (d & 7)) << 3)];
                #pragma unroll
                for (int i = 0; i < 2; i++)
                    oacc[i][df] = __builtin_amdgcn_mfma_f32_16x16x32_bf16(ap[i], bv, oacc[i][df], 0, 0, 0);
            }
        }

        // single barrier per tile: drains prefetch + protects buffer swap
        __syncthreads();
    }

    // ---- epilogue: AO bf16 [b,s,h,d] ----
    const size_t obase = ((size_t)b * SEQ * NH + h) * HD;
    const size_t rstr = (size_t)NH * HD;
    float linv[2][4];
    #pragma unroll
    for (int i = 0; i < 2; i++)
        #pragma unroll
        for (int r = 0; r < 4; r++) linv[i][r] = 1.0f / l_[i][r];
    #pragma unroll
    for (int i = 0; i < 2; i++)
        #pragma unroll
        for (int df = 0; df < 8; df++)
            #pragma unroll
            for (int r = 0; r < 4; r++) {
                const int row = q0 + w * 32 + i * 16 + quad * 4 + r;
                const int d = df * 16 + fm;
                AO[obase + (size_t)row * rstr + d] = __float2bfloat16(oacc[i][df][r] * linv[i][r]);
            }
}

// ======================= launch =======================
extern "C" void kernel_launch(void* const* d_in, const int* in_sizes, int n_in,
                              void* d_out, int out_size, void* d_ws, size_t ws_size,
                              hipStream_t stream) {
    const float* x  = (const float*)d_in[0];
    const float* wq = (const float*)d_in[1];
    const float* wk = (const float*)d_in[2];
    const float* wv = (const float*)d_in[3];
    const float* wo = (const float*)d_in[4];
    const float* q_scale = (const float*)d_in[5];
    const float* k_scale = (const float*)d_in[6];
    float* out = (float*)d_out;

    const size_t T = (size_t)BATCH * SEQ * NH * HD;   // 8388608
    const size_t W = (size_t)EMB * NH * HD;           // 4194304

    unsigned short* xf   = (unsigned short*)d_ws;     // fp16 x
    unsigned short* aob  = xf + T;
    unsigned short* Qh   = aob + T;
    unsigned short* Ql   = Qh + T;
    unsigned short* Kh   = Ql + T;
    unsigned short* Kl   = Kh + T;
    unsigned short* Vtb  = Kl + T;
    unsigned short* wqF  = Vtb + T;                   // fp16 [n][k]
    unsigned short* wkF  = wqF + W;
    unsigned short* wvF  = wkF + W;
    unsigned short* woT  = wvF + W;                   // bf16 [n][k]

    const int M = BATCH * SEQ;   // 4096
    const int N = NH * HD;       // 2048
    const int K = EMB;           // 2048

    cast_f16<<<(int)(T / 4 + 255) / 256, 256, 0, stream>>>(x, xf, (int)T);
    prep_weights<<<dim3(64, 64, 4), dim3(32, 8), 0, stream>>>(
        wq, wk, wv, wo, wqF, wkF, wvF, woT);

    // Q and K projections (z-fused, single-term fp16) with fused RMSNorm epilogue
    gemm_qk_rms<<<dim3(N / GT, M / GT, 2), 256, 0, stream>>>(
        xf, wqF, wkF, q_scale, k_scale, Qh, Ql, Kh, Kl, K);
    // V projection (fp16) with fused Vt-transpose epilogue
    gemm_v_vt<<<dim3(N / GT, M / GT), 256, 0, stream>>>(xf, wvF, Vtb, K);

    attn4<<<dim3(SEQ / ATQ, BATCH * NH), 512, 0, stream>>>(Qh, Ql, Kh, Kl, Vtb, (__hip_bfloat16*)aob);

    gemm_bf16<<<dim3(EMB / GT, M / GT), 256, 0, stream>>>(aob, woT, out, M, EMB, NH * HD);
}

// Round 10
// 505.886 us; speedup vs baseline: 1.9646x; 1.1824x over previous
//
#include <hip/hip_runtime.h>
#include <hip/hip_bf16.h>
#include <math.h>

#define BATCH 2
#define SEQ   2048
#define EMB   2048
#define NH    16
#define HD    128

typedef __attribute__((ext_vector_type(8))) short short8;
typedef __attribute__((ext_vector_type(8))) _Float16 half8;
typedef __attribute__((ext_vector_type(4))) float floatx4;

__device__ inline void async_load16(const void* g, void* l) {
    __builtin_amdgcn_global_load_lds(
        (const __attribute__((address_space(1))) unsigned int*)g,
        (__attribute__((address_space(3))) unsigned int*)l, 16, 0, 0);
}

__device__ inline unsigned short bf16_bits(float f) {
    __hip_bfloat16 b = __float2bfloat16(f);
    return *(unsigned short*)&b;
}
__device__ inline unsigned short fp16_bits(float f) {
    _Float16 h = (_Float16)f;
    return *(unsigned short*)&h;
}

// ======================= plain bf16 MFMA GEMM (m97 structure) — out projection =======================
#define GT 128
#define GK 32

__global__ __launch_bounds__(256) void gemm_bf16(
    const unsigned short* __restrict__ A,
    const unsigned short* __restrict__ Bt,
    float* __restrict__ C, int M, int N, int K)
{
    __shared__ unsigned short As[GT * GK];
    __shared__ unsigned short Bs[GT * GK];

    const int tid  = threadIdx.x;
    const int w    = tid >> 6;
    const int lane = tid & 63;
    const int wr   = w >> 1, wc = w & 1;
    const int row0 = blockIdx.y * GT;
    const int col0 = blockIdx.x * GT;

    floatx4 acc[4][4];
    #pragma unroll
    for (int i = 0; i < 4; i++)
        #pragma unroll
        for (int j = 0; j < 4; j++)
            acc[i][j] = (floatx4){0.f, 0.f, 0.f, 0.f};

    const int srow  = lane >> 2;
    const int skoff = (lane & 3) * 8;
    const int fm = lane & 15;
    const int fk = (lane >> 4) * 8;

    for (int k0 = 0; k0 < K; k0 += GK) {
        #pragma unroll
        for (int t = 0; t < 2; t++) {
            const int c = w * 2 + t;
            async_load16(A  + (size_t)(row0 + c * 16 + srow) * K + k0 + skoff, (char*)As + c * 1024);
            async_load16(Bt + (size_t)(col0 + c * 16 + srow) * K + k0 + skoff, (char*)Bs + c * 1024);
        }
        __syncthreads();

        short8 af[4], bf[4];
        #pragma unroll
        for (int i = 0; i < 4; i++) {
            af[i] = *(const short8*)&As[(wr * 64 + i * 16 + fm) * GK + fk];
            bf[i] = *(const short8*)&Bs[(wc * 64 + i * 16 + fm) * GK + fk];
        }
        #pragma unroll
        for (int i = 0; i < 4; i++)
            #pragma unroll
            for (int j = 0; j < 4; j++)
                acc[i][j] = __builtin_amdgcn_mfma_f32_16x16x32_bf16(af[i], bf[j], acc[i][j], 0, 0, 0);
        __syncthreads();
    }

    const int quad = lane >> 4;
    #pragma unroll
    for (int i = 0; i < 4; i++)
        #pragma unroll
        for (int j = 0; j < 4; j++) {
            const size_t base = (size_t)(row0 + wr * 64 + i * 16 + quad * 4) * N
                              + col0 + wc * 64 + j * 16 + fm;
            #pragma unroll
            for (int r = 0; r < 4; r++)
                C[base + (size_t)r * N] = acc[i][j][r];
        }
}

// ======================= fp16 V projection GEMM + fused Vt epilogue (fp16 out) =======================
__global__ __launch_bounds__(256) void gemm_v_vt(
    const unsigned short* __restrict__ A,
    const unsigned short* __restrict__ Bt,
    unsigned short* __restrict__ Vt, int K)
{
    __shared__ char smem[2 * 128 * 72 * 2] __attribute__((aligned(16)));  // 36 KB
    unsigned short* As = (unsigned short*)smem;                // 8 KB (K-loop)
    unsigned short* Bs = (unsigned short*)(smem + 8192);       // 8 KB (K-loop)
    typedef unsigned short stage_row[72];
    stage_row* stage0 = (stage_row*)smem;                      // [2][128][72] (epilogue)

    const int tid  = threadIdx.x;
    const int w    = tid >> 6;
    const int lane = tid & 63;
    const int wr   = w >> 1, wc = w & 1;
    const int row0 = blockIdx.y * GT;
    const int col0 = blockIdx.x * GT;

    floatx4 acc[4][4];
    #pragma unroll
    for (int i = 0; i < 4; i++)
        #pragma unroll
        for (int j = 0; j < 4; j++)
            acc[i][j] = (floatx4){0.f, 0.f, 0.f, 0.f};

    const int srow  = lane >> 2;
    const int skoff = (lane & 3) * 8;
    const int fm = lane & 15;
    const int fk = (lane >> 4) * 8;

    for (int k0 = 0; k0 < K; k0 += GK) {
        #pragma unroll
        for (int t = 0; t < 2; t++) {
            const int c = w * 2 + t;
            async_load16(A  + (size_t)(row0 + c * 16 + srow) * K + k0 + skoff, (char*)As + c * 1024);
            async_load16(Bt + (size_t)(col0 + c * 16 + srow) * K + k0 + skoff, (char*)Bs + c * 1024);
        }
        __syncthreads();

        half8 af[4], bf[4];
        #pragma unroll
        for (int i = 0; i < 4; i++) {
            af[i] = *(const half8*)&As[(wr * 64 + i * 16 + fm) * GK + fk];
            bf[i] = *(const half8*)&Bs[(wc * 64 + i * 16 + fm) * GK + fk];
        }
        #pragma unroll
        for (int i = 0; i < 4; i++)
            #pragma unroll
            for (int j = 0; j < 4; j++)
                acc[i][j] = __builtin_amdgcn_mfma_f32_16x16x32_f16(af[i], bf[j], acc[i][j], 0, 0, 0);
        __syncthreads();   // also makes As/Bs dead -> stage aliasing safe
    }

    // ---- fused epilogue: transpose to Vt layout (fp16) ----
    const int quad = lane >> 4;
    const int b  = row0 >> 11;            // batch (128 | 2048, no straddle)
    const int h  = col0 >> 7;             // head (GT == HD)
    const int bh = b * NH + h;
    const int kt_base = (row0 & 2047) >> 6;

    #pragma unroll
    for (int i = 0; i < 4; i++)
        #pragma unroll
        for (int r = 0; r < 4; r++) {
            const int key = i * 16 + quad * 4 + r;           // 0..63
            #pragma unroll
            for (int j = 0; j < 4; j++) {
                const int d = wc * 64 + j * 16 + fm;
                stage0[wr * 128 + d][key] = fp16_bits(acc[i][j][r]);
            }
        }
    __syncthreads();

    const int d = tid >> 1, half = tid & 1;
    #pragma unroll
    for (int kt = 0; kt < 2; kt++) {
        const size_t ob = ((size_t)(bh * 32 + kt_base + kt)) * 8192 + (size_t)d * 64;
        #pragma unroll
        for (int cc = 0; cc < 4; cc++) {
            const int cs = half * 4 + cc;
            const int kb = (cs ^ (d & 7)) << 3;
            *(short8*)&Vt[ob + cs * 8] = *(const short8*)&stage0[kt * 128 + d][kb];
        }
    }
}

// ======================= fp16 Q/K projection GEMM + fused RMSNorm epilogue (z-fused) =======================
// Single-term fp16 GEMM; epilogue emits ONE fp16 plane (no hi/lo split).
__global__ __launch_bounds__(256) void gemm_qk_rms(
    const unsigned short* __restrict__ A,
    const unsigned short* __restrict__ Bq, const unsigned short* __restrict__ Bk,
    const float* __restrict__ q_scale, const float* __restrict__ k_scale,
    unsigned short* __restrict__ Qf, unsigned short* __restrict__ Kf,
    int K)
{
    __shared__ unsigned short As[GT * GK];
    __shared__ unsigned short Bs[GT * GK];
    __shared__ float ws2[2][GT];

    const int z = blockIdx.z;
    const unsigned short* __restrict__ Bt = z ? Bk : Bq;
    const float* __restrict__ scale = z ? k_scale : q_scale;
    unsigned short* __restrict__ o = z ? Kf : Qf;
    const int swz = z;

    const int tid  = threadIdx.x;
    const int w    = tid >> 6;
    const int lane = tid & 63;
    const int wr   = w >> 1, wc = w & 1;
    const int row0 = blockIdx.y * GT;
    const int col0 = blockIdx.x * GT;

    floatx4 acc[4][4];
    #pragma unroll
    for (int i = 0; i < 4; i++)
        #pragma unroll
        for (int j = 0; j < 4; j++)
            acc[i][j] = (floatx4){0.f, 0.f, 0.f, 0.f};

    const int srow  = lane >> 2;
    const int skoff = (lane & 3) * 8;
    const int fm = lane & 15;
    const int fk = (lane >> 4) * 8;

    for (int k0 = 0; k0 < K; k0 += GK) {
        #pragma unroll
        for (int t = 0; t < 2; t++) {
            const int c = w * 2 + t;
            async_load16(A  + (size_t)(row0 + c * 16 + srow) * K + k0 + skoff, (char*)As + c * 1024);
            async_load16(Bt + (size_t)(col0 + c * 16 + srow) * K + k0 + skoff, (char*)Bs + c * 1024);
        }
        __syncthreads();

        half8 af[4], bf[4];
        #pragma unroll
        for (int i = 0; i < 4; i++) {
            af[i] = *(const half8*)&As[(wr * 64 + i * 16 + fm) * GK + fk];
            bf[i] = *(const half8*)&Bs[(wc * 64 + i * 16 + fm) * GK + fk];
        }
        #pragma unroll
        for (int i = 0; i < 4; i++)
            #pragma unroll
            for (int j = 0; j < 4; j++)
                acc[i][j] = __builtin_amdgcn_mfma_f32_16x16x32_f16(af[i], bf[j], acc[i][j], 0, 0, 0);
        __syncthreads();
    }

    // ---- fused epilogue ----
    const int quad = lane >> 4;

    float sq[4][4];
    #pragma unroll
    for (int i = 0; i < 4; i++)
        #pragma unroll
        for (int r = 0; r < 4; r++) {
            float s2 = 0.f;
            #pragma unroll
            for (int j = 0; j < 4; j++) s2 += acc[i][j][r] * acc[i][j][r];
            s2 += __shfl_xor(s2, 1);
            s2 += __shfl_xor(s2, 2);
            s2 += __shfl_xor(s2, 4);
            s2 += __shfl_xor(s2, 8);
            sq[i][r] = s2;
        }
    if (fm == 0) {
        #pragma unroll
        for (int i = 0; i < 4; i++)
            #pragma unroll
            for (int r = 0; r < 4; r++)
                ws2[wc][wr * 64 + i * 16 + quad * 4 + r] = sq[i][r];
    }
    __syncthreads();

    const int hh = col0 >> 7;   // head index (GT == HD)
    float scv[4];
    #pragma unroll
    for (int j = 0; j < 4; j++) scv[j] = scale[wc * 64 + j * 16 + fm];

    #pragma unroll
    for (int i = 0; i < 4; i++)
        #pragma unroll
        for (int r = 0; r < 4; r++) {
            const int lrow = wr * 64 + i * 16 + quad * 4 + r;
            const int row  = row0 + lrow;            // global m = b*SEQ + s
            const int bb = row >> 11, s = row & 2047;
            const float inv = rsqrtf((ws2[0][lrow] + ws2[1][lrow]) * (1.0f / HD) + 1e-6f);
            const size_t ob = ((size_t)(bb * NH + hh) * SEQ + s) * 128;
            #pragma unroll
            for (int j = 0; j < 4; j++) {
                const int d = wc * 64 + j * 16 + fm;
                const float val = acc[i][j][r] * inv * scv[j];
                const int dd = swz ? ((((d >> 3) ^ (s & 15)) << 3) | (d & 7)) : d;
                o[ob + dd] = fp16_bits(val);
            }
        }
}

// ======================= casts / weight prep =======================
__global__ __launch_bounds__(256) void cast_f16(
    const float* __restrict__ in, unsigned short* __restrict__ o, int n)
{
    int i = (blockIdx.x * 256 + threadIdx.x) * 4;
    if (i >= n) return;
    float4 v = *(const float4*)&in[i];
    ushort4 h;
    h.x = fp16_bits(v.x);
    h.y = fp16_bits(v.y);
    h.z = fp16_bits(v.z);
    h.w = fp16_bits(v.w);
    *(ushort4*)&o[i] = h;
}

// all four weight transposes in ONE dispatch, z-selected: wq/wk/wv -> fp16, wo -> bf16.
__global__ __launch_bounds__(256) void prep_weights(
    const float* __restrict__ wq, const float* __restrict__ wk,
    const float* __restrict__ wv, const float* __restrict__ wo,
    unsigned short* __restrict__ wqF, unsigned short* __restrict__ wkF,
    unsigned short* __restrict__ wvF, unsigned short* __restrict__ woT)
{
    __shared__ float tile[32][33];
    const int z = blockIdx.z;
    const float* __restrict__ W = (z == 0) ? wq : (z == 1) ? wk : (z == 2) ? wv : wo;
    const int k0 = blockIdx.y * 32, n0 = blockIdx.x * 32;
    const int tx = threadIdx.x, ty = threadIdx.y;
    #pragma unroll
    for (int i = 0; i < 4; i++)
        tile[ty + i * 8][tx] = W[(size_t)(k0 + ty + i * 8) * 2048 + n0 + tx];
    __syncthreads();
    if (z < 3) {
        unsigned short* __restrict__ t = (z == 0) ? wqF : (z == 1) ? wkF : wvF;
        #pragma unroll
        for (int i = 0; i < 4; i++)
            t[(size_t)(n0 + ty + i * 8) * 2048 + k0 + tx] = fp16_bits(tile[tx][ty + i * 8]);
    } else {
        #pragma unroll
        for (int i = 0; i < 4; i++)
            woT[(size_t)(n0 + ty + i * 8) * 2048 + k0 + tx] = bf16_bits(tile[tx][ty + i * 8]);
    }
}

// ======================= MFMA flash attention v14 =======================
// v4's EXACT structure (512 threads = 8 waves, ATQ=256/32 rows per wave, ATK=64,
// double-buffered KV staging, prefetch at tile start, ONE barrier per tile,
// grid (8,32) = 256 blocks, 1 block/CU) with fp16 single-term Q/K/V/P:
// QK^T 96 -> 32 MFMA/tile/wave, K staging halved (one plane), LDS 128 -> 96 KB.
// Work reduction only -- no schedule/occupancy/priority change (v5-v9 lesson).
#define ATQ 256
#define ATK 64

__global__ __launch_bounds__(512, 1) void attn14(
    const unsigned short* __restrict__ Qf, const unsigned short* __restrict__ Kf,
    const unsigned short* __restrict__ Vt, __hip_bfloat16* __restrict__ AO)
{
    __shared__ unsigned short Ks[2][ATK * 128];    // 32 KB  [key][d'] (chunk ^= key&15)
    __shared__ unsigned short Vts[2][HD * 64];     // 32 KB  [d][key'] (chunk ^= d&7)
    __shared__ unsigned short Ps[ATQ * 64];        // 32 KB  P[row][key'] (chunk ^= row&7)

    const int tid  = threadIdx.x;
    const int w    = tid >> 6;        // 0..7
    const int lane = tid & 63;
    const int quad = lane >> 4;
    const int fm   = lane & 15;
    const int bh = blockIdx.y;
    const int b = bh >> 4, h = bh & 15;
    const int q0 = blockIdx.x * ATQ;

    const size_t hbase = (size_t)(b * NH + h) * SEQ;

    // ---- Q fragments (fp16); wave owns rows w*32..w*32+31 ----
    half8 qf[2][4];
    #pragma unroll
    for (int i = 0; i < 2; i++) {
        const size_t row = hbase + q0 + w * 32 + i * 16 + fm;
        #pragma unroll
        for (int kc = 0; kc < 4; kc++)
            qf[i][kc] = *(const half8*)&Qf[row * 128 + kc * 32 + quad * 8];
    }

    floatx4 oacc[2][8];
    #pragma unroll
    for (int i = 0; i < 2; i++)
        #pragma unroll
        for (int df = 0; df < 8; df++)
            oacc[i][df] = (floatx4){0.f, 0.f, 0.f, 0.f};
    float m_[2][4], l_[2][4];
    #pragma unroll
    for (int i = 0; i < 2; i++)
        #pragma unroll
        for (int r = 0; r < 4; r++) { m_[i][r] = -1e30f; l_[i][r] = 0.f; }

    const unsigned short* gk0  = Kf + hbase * 128;
    const unsigned short* gvt0 = Vt + (size_t)bh * 32 * 8192;

    // staging: 32 chunks of 1 KB (Ks 16, Vts 16); wave w -> chunks w*4..w*4+3
    const int ch0 = w * 4;

    // ---- prologue: stage tile 0 into buffer 0 ----
    #pragma unroll
    for (int c = 0; c < 4; c++) {
        const int ch = ch0 + c;
        const size_t go = (size_t)(ch & 15) * 512 + lane * 8;
        if (ch < 16) async_load16(gk0  + go, (char*)Ks[0]  + ch * 1024);
        else         async_load16(gvt0 + go, (char*)Vts[0] + (ch - 16) * 1024);
    }
    __syncthreads();   // drain: tile 0 staged

    for (int ktile = 0; ktile < SEQ / ATK; ktile++) {
        const int cur = ktile & 1;

        // ---- prefetch tile t+1 into other buffer (drained by end-of-tile barrier) ----
        if (ktile + 1 < SEQ / ATK) {
            const unsigned short* gk  = gk0  + (size_t)(ktile + 1) * ATK * 128;
            const unsigned short* gvt = gvt0 + (size_t)(ktile + 1) * 8192;
            #pragma unroll
            for (int c = 0; c < 4; c++) {
                const int ch = ch0 + c;
                const size_t go = (size_t)(ch & 15) * 512 + lane * 8;
                if (ch < 16) async_load16(gk  + go, (char*)Ks[1 - cur]  + ch * 1024);
                else         async_load16(gvt + go, (char*)Vts[1 - cur] + (ch - 16) * 1024);
            }
        }

        // ---- S = Q K^T (single-term fp16) from buffer cur ----
        floatx4 sacc[2][4];
        #pragma unroll
        for (int i = 0; i < 2; i++)
            #pragma unroll
            for (int jf = 0; jf < 4; jf++)
                sacc[i][jf] = (floatx4){0.f, 0.f, 0.f, 0.f};
        #pragma unroll
        for (int kc = 0; kc < 4; kc++)
            #pragma unroll
            for (int jf = 0; jf < 4; jf++) {
                const int koff = (jf * 16 + fm) * 128 + (((kc * 4 + quad) ^ fm) << 3);
                half8 k8 = *(const half8*)&Ks[cur][koff];
                #pragma unroll
                for (int i = 0; i < 2; i++)
                    sacc[i][jf] = __builtin_amdgcn_mfma_f32_16x16x32_f16(qf[i][kc], k8, sacc[i][jf], 0, 0, 0);
            }

        // ---- online softmax (registers) ----
        float alpha_[2][4];
        #pragma unroll
        for (int i = 0; i < 2; i++)
            #pragma unroll
            for (int r = 0; r < 4; r++) {
                float mx = fmaxf(fmaxf(sacc[i][0][r], sacc[i][1][r]),
                                 fmaxf(sacc[i][2][r], sacc[i][3][r]));
                mx = fmaxf(mx, __shfl_xor(mx, 1));
                mx = fmaxf(mx, __shfl_xor(mx, 2));
                mx = fmaxf(mx, __shfl_xor(mx, 4));
                mx = fmaxf(mx, __shfl_xor(mx, 8));
                const float mold = m_[i][r];
                const float mnew = fmaxf(mold, mx);
                const float al = __expf(mold - mnew);
                m_[i][r] = mnew;
                alpha_[i][r] = al;
                float rs = 0.f;
                #pragma unroll
                for (int jf = 0; jf < 4; jf++) {
                    float p = __expf(sacc[i][jf][r] - mnew);
                    sacc[i][jf][r] = p;
                    rs += p;
                }
                rs += __shfl_xor(rs, 1);
                rs += __shfl_xor(rs, 2);
                rs += __shfl_xor(rs, 4);
                rs += __shfl_xor(rs, 8);
                l_[i][r] = l_[i][r] * al + rs;
            }
        #pragma unroll
        for (int i = 0; i < 2; i++)
            #pragma unroll
            for (int df = 0; df < 8; df++)
                #pragma unroll
                for (int r = 0; r < 4; r++)
                    oacc[i][df][r] *= alpha_[i][r];

        // ---- P -> fp16 into Ps (own rows; wave-local ordering, no barrier) ----
        #pragma unroll
        for (int i = 0; i < 2; i++)
            #pragma unroll
            for (int jf = 0; jf < 4; jf++)
                #pragma unroll
                for (int r = 0; r < 4; r++) {
                    const int row = w * 32 + i * 16 + quad * 4 + r;
                    const int chunk = jf * 2 + (fm >> 3);
                    const int colp = ((chunk ^ (row & 7)) << 3) | (fm & 7);
                    Ps[row * 64 + colp] = fp16_bits(sacc[i][jf][r]);
                }

        // ---- O += P V from buffer cur (fp16) ----
        #pragma unroll
        for (int kc2 = 0; kc2 < 2; kc2++) {
            half8 ap[2];
            #pragma unroll
            for (int i = 0; i < 2; i++) {
                const int row = w * 32 + i * 16 + fm;
                ap[i] = *(const half8*)&Ps[row * 64 + (((kc2 * 4 + quad) ^ (row & 7)) << 3)];
            }
            #pragma unroll
            for (int df = 0; df < 8; df++) {
                const int d = df * 16 + fm;
                half8 bv = *(const half8*)&Vts[cur][d * 64 + (((kc2 * 4 + quad) ^ (d & 7)) << 3)];
                #pragma unroll
                for (int i = 0; i < 2; i++)
                    oacc[i][df] = __builtin_amdgcn_mfma_f32_16x16x32_f16(ap[i], bv, oacc[i][df], 0, 0, 0);
            }
        }

        // single barrier per tile: drains prefetch + protects buffer swap
        __syncthreads();
    }

    // ---- epilogue: AO bf16 [b,s,h,d] ----
    const size_t obase = ((size_t)b * SEQ * NH + h) * HD;
    const size_t rstr = (size_t)NH * HD;
    float linv[2][4];
    #pragma unroll
    for (int i = 0; i < 2; i++)
        #pragma unroll
        for (int r = 0; r < 4; r++) linv[i][r] = 1.0f / l_[i][r];
    #pragma unroll
    for (int i = 0; i < 2; i++)
        #pragma unroll
        for (int df = 0; df < 8; df++)
            #pragma unroll
            for (int r = 0; r < 4; r++) {
                const int row = q0 + w * 32 + i * 16 + quad * 4 + r;
                const int d = df * 16 + fm;
                AO[obase + (size_t)row * rstr + d] = __float2bfloat16(oacc[i][df][r] * linv[i][r]);
            }
}

// ======================= launch =======================
extern "C" void kernel_launch(void* const* d_in, const int* in_sizes, int n_in,
                              void* d_out, int out_size, void* d_ws, size_t ws_size,
                              hipStream_t stream) {
    const float* x  = (const float*)d_in[0];
    const float* wq = (const float*)d_in[1];
    const float* wk = (const float*)d_in[2];
    const float* wv = (const float*)d_in[3];
    const float* wo = (const float*)d_in[4];
    const float* q_scale = (const float*)d_in[5];
    const float* k_scale = (const float*)d_in[6];
    float* out = (float*)d_out;

    const size_t T = (size_t)BATCH * SEQ * NH * HD;   // 8388608
    const size_t W = (size_t)EMB * NH * HD;           // 4194304

    unsigned short* xf   = (unsigned short*)d_ws;     // fp16 x
    unsigned short* aob  = xf + T;                    // bf16 attn out
    unsigned short* Qf   = aob + T;                   // fp16 Q (head-major)
    unsigned short* Kf   = Qf + T;                    // fp16 K (head-major, swizzled)
    unsigned short* Vtb  = Kf + T;                    // fp16 Vt tiles
    unsigned short* wqF  = Vtb + T;                   // fp16 [n][k]
    unsigned short* wkF  = wqF + W;
    unsigned short* wvF  = wkF + W;
    unsigned short* woT  = wvF + W;                   // bf16 [n][k]

    const int M = BATCH * SEQ;   // 4096
    const int N = NH * HD;       // 2048
    const int K = EMB;           // 2048

    cast_f16<<<(int)(T / 4 + 255) / 256, 256, 0, stream>>>(x, xf, (int)T);
    prep_weights<<<dim3(64, 64, 4), dim3(32, 8), 0, stream>>>(
        wq, wk, wv, wo, wqF, wkF, wvF, woT);

    // Q and K projections (z-fused, single-term fp16) with fused RMSNorm epilogue
    gemm_qk_rms<<<dim3(N / GT, M / GT, 2), 256, 0, stream>>>(
        xf, wqF, wkF, q_scale, k_scale, Qf, Kf, K);
    // V projection (fp16) with fused Vt-transpose epilogue
    gemm_v_vt<<<dim3(N / GT, M / GT), 256, 0, stream>>>(xf, wvF, Vtb, K);

    attn14<<<dim3(SEQ / ATQ, BATCH * NH), 512, 0, stream>>>(Qf, Kf, Vtb, (__hip_bfloat16*)aob);

    gemm_bf16<<<dim3(EMB / GT, M / GT), 256, 0, stream>>>(aob, woT, out, M, EMB, NH * HD);
}

// Round 11
// 494.414 us; speedup vs baseline: 2.0102x; 1.0232x over previous
//
#include <hip/hip_runtime.h>
#include <hip/hip_bf16.h>
#include <math.h>

#define BATCH 2
#define SEQ   2048
#define EMB   2048
#define NH    16
#define HD    128

typedef __attribute__((ext_vector_type(8))) short short8;
typedef __attribute__((ext_vector_type(8))) _Float16 half8;
typedef __attribute__((ext_vector_type(4))) float floatx4;

__device__ inline void async_load16(const void* g, void* l) {
    __builtin_amdgcn_global_load_lds(
        (const __attribute__((address_space(1))) unsigned int*)g,
        (__attribute__((address_space(3))) unsigned int*)l, 16, 0, 0);
}

__device__ inline unsigned short bf16_bits(float f) {
    __hip_bfloat16 b = __float2bfloat16(f);
    return *(unsigned short*)&b;
}
__device__ inline unsigned short fp16_bits(float f) {
    _Float16 h = (_Float16)f;
    return *(unsigned short*)&h;
}

// ======================= plain bf16 MFMA GEMM (m97 structure) — out projection =======================
#define GT 128
#define GK 32

__global__ __launch_bounds__(256) void gemm_bf16(
    const unsigned short* __restrict__ A,
    const unsigned short* __restrict__ Bt,
    float* __restrict__ C, int M, int N, int K)
{
    __shared__ unsigned short As[GT * GK];
    __shared__ unsigned short Bs[GT * GK];

    const int tid  = threadIdx.x;
    const int w    = tid >> 6;
    const int lane = tid & 63;
    const int wr   = w >> 1, wc = w & 1;
    const int row0 = blockIdx.y * GT;
    const int col0 = blockIdx.x * GT;

    floatx4 acc[4][4];
    #pragma unroll
    for (int i = 0; i < 4; i++)
        #pragma unroll
        for (int j = 0; j < 4; j++)
            acc[i][j] = (floatx4){0.f, 0.f, 0.f, 0.f};

    const int srow  = lane >> 2;
    const int skoff = (lane & 3) * 8;
    const int fm = lane & 15;
    const int fk = (lane >> 4) * 8;

    for (int k0 = 0; k0 < K; k0 += GK) {
        #pragma unroll
        for (int t = 0; t < 2; t++) {
            const int c = w * 2 + t;
            async_load16(A  + (size_t)(row0 + c * 16 + srow) * K + k0 + skoff, (char*)As + c * 1024);
            async_load16(Bt + (size_t)(col0 + c * 16 + srow) * K + k0 + skoff, (char*)Bs + c * 1024);
        }
        __syncthreads();

        short8 af[4], bf[4];
        #pragma unroll
        for (int i = 0; i < 4; i++) {
            af[i] = *(const short8*)&As[(wr * 64 + i * 16 + fm) * GK + fk];
            bf[i] = *(const short8*)&Bs[(wc * 64 + i * 16 + fm) * GK + fk];
        }
        #pragma unroll
        for (int i = 0; i < 4; i++)
            #pragma unroll
            for (int j = 0; j < 4; j++)
                acc[i][j] = __builtin_amdgcn_mfma_f32_16x16x32_bf16(af[i], bf[j], acc[i][j], 0, 0, 0);
        __syncthreads();
    }

    const int quad = lane >> 4;
    #pragma unroll
    for (int i = 0; i < 4; i++)
        #pragma unroll
        for (int j = 0; j < 4; j++) {
            const size_t base = (size_t)(row0 + wr * 64 + i * 16 + quad * 4) * N
                              + col0 + wc * 64 + j * 16 + fm;
            #pragma unroll
            for (int r = 0; r < 4; r++)
                C[base + (size_t)r * N] = acc[i][j][r];
        }
}

// ======================= merged Q/K/V projection GEMM (z-fused, shared A panels) =======================
// blockIdx.z: 0=Q (rms epilogue), 1=K (rms epilogue, swizzled), 2=V (Vt epilogue).
// All three share A=xf; co-resident z-slices with equal (x,y) hit the same A panel
// in L2 (A is half of staged bytes -> ~33% ideal fetch reduction vs split dispatch).
// K-loop is the proven m97 fp16 loop, byte-identical across z.
__global__ __launch_bounds__(256) void gemm_qkv(
    const unsigned short* __restrict__ A,
    const unsigned short* __restrict__ Bq, const unsigned short* __restrict__ Bk,
    const unsigned short* __restrict__ Bv,
    const float* __restrict__ q_scale, const float* __restrict__ k_scale,
    unsigned short* __restrict__ Qf, unsigned short* __restrict__ Kf,
    unsigned short* __restrict__ Vt, int K)
{
    __shared__ char smem[2 * 128 * 72 * 2] __attribute__((aligned(16)));  // 36 KB
    unsigned short* As = (unsigned short*)smem;                // 8 KB (K-loop)
    unsigned short* Bs = (unsigned short*)(smem + 8192);       // 8 KB (K-loop)
    float* ws2f = (float*)(smem + 16384);                      // 1 KB  [2][128] (rms epi)
    typedef unsigned short stage_row[72];
    stage_row* stage0 = (stage_row*)smem;                      // [2][128][72] (vt epi)

    const int z = blockIdx.z;
    const unsigned short* __restrict__ Bt = (z == 0) ? Bq : (z == 1) ? Bk : Bv;

    const int tid  = threadIdx.x;
    const int w    = tid >> 6;
    const int lane = tid & 63;
    const int wr   = w >> 1, wc = w & 1;
    const int row0 = blockIdx.y * GT;
    const int col0 = blockIdx.x * GT;

    floatx4 acc[4][4];
    #pragma unroll
    for (int i = 0; i < 4; i++)
        #pragma unroll
        for (int j = 0; j < 4; j++)
            acc[i][j] = (floatx4){0.f, 0.f, 0.f, 0.f};

    const int srow  = lane >> 2;
    const int skoff = (lane & 3) * 8;
    const int fm = lane & 15;
    const int fk = (lane >> 4) * 8;

    for (int k0 = 0; k0 < K; k0 += GK) {
        #pragma unroll
        for (int t = 0; t < 2; t++) {
            const int c = w * 2 + t;
            async_load16(A  + (size_t)(row0 + c * 16 + srow) * K + k0 + skoff, (char*)As + c * 1024);
            async_load16(Bt + (size_t)(col0 + c * 16 + srow) * K + k0 + skoff, (char*)Bs + c * 1024);
        }
        __syncthreads();

        half8 af[4], bf[4];
        #pragma unroll
        for (int i = 0; i < 4; i++) {
            af[i] = *(const half8*)&As[(wr * 64 + i * 16 + fm) * GK + fk];
            bf[i] = *(const half8*)&Bs[(wc * 64 + i * 16 + fm) * GK + fk];
        }
        #pragma unroll
        for (int i = 0; i < 4; i++)
            #pragma unroll
            for (int j = 0; j < 4; j++)
                acc[i][j] = __builtin_amdgcn_mfma_f32_16x16x32_f16(af[i], bf[j], acc[i][j], 0, 0, 0);
        __syncthreads();   // final iter: As/Bs dead -> epilogue aliasing safe
    }

    const int quad = lane >> 4;
    const int hh = col0 >> 7;   // head index (GT == HD)

    if (z < 2) {
        // ---- RMSNorm + relayout epilogue (fp16 out) ----
        const float* __restrict__ scale = z ? k_scale : q_scale;
        unsigned short* __restrict__ o = z ? Kf : Qf;

        float sq[4][4];
        #pragma unroll
        for (int i = 0; i < 4; i++)
            #pragma unroll
            for (int r = 0; r < 4; r++) {
                float s2 = 0.f;
                #pragma unroll
                for (int j = 0; j < 4; j++) s2 += acc[i][j][r] * acc[i][j][r];
                s2 += __shfl_xor(s2, 1);
                s2 += __shfl_xor(s2, 2);
                s2 += __shfl_xor(s2, 4);
                s2 += __shfl_xor(s2, 8);
                sq[i][r] = s2;
            }
        if (fm == 0) {
            #pragma unroll
            for (int i = 0; i < 4; i++)
                #pragma unroll
                for (int r = 0; r < 4; r++)
                    ws2f[wc * 128 + wr * 64 + i * 16 + quad * 4 + r] = sq[i][r];
        }
        __syncthreads();

        float scv[4];
        #pragma unroll
        for (int j = 0; j < 4; j++) scv[j] = scale[wc * 64 + j * 16 + fm];

        #pragma unroll
        for (int i = 0; i < 4; i++)
            #pragma unroll
            for (int r = 0; r < 4; r++) {
                const int lrow = wr * 64 + i * 16 + quad * 4 + r;
                const int row  = row0 + lrow;            // global m = b*SEQ + s
                const int bb = row >> 11, s = row & 2047;
                const float inv = rsqrtf((ws2f[lrow] + ws2f[128 + lrow]) * (1.0f / HD) + 1e-6f);
                const size_t ob = ((size_t)(bb * NH + hh) * SEQ + s) * 128;
                #pragma unroll
                for (int j = 0; j < 4; j++) {
                    const int d = wc * 64 + j * 16 + fm;
                    const float val = acc[i][j][r] * inv * scv[j];
                    const int dd = z ? ((((d >> 3) ^ (s & 15)) << 3) | (d & 7)) : d;
                    o[ob + dd] = fp16_bits(val);
                }
            }
    } else {
        // ---- Vt-transpose epilogue (fp16 out) ----
        const int b  = row0 >> 11;
        const int bh = b * NH + hh;
        const int kt_base = (row0 & 2047) >> 6;

        #pragma unroll
        for (int i = 0; i < 4; i++)
            #pragma unroll
            for (int r = 0; r < 4; r++) {
                const int key = i * 16 + quad * 4 + r;           // 0..63
                #pragma unroll
                for (int j = 0; j < 4; j++) {
                    const int d = wc * 64 + j * 16 + fm;
                    stage0[wr * 128 + d][key] = fp16_bits(acc[i][j][r]);
                }
            }
        __syncthreads();

        const int d = tid >> 1, half = tid & 1;
        #pragma unroll
        for (int kt = 0; kt < 2; kt++) {
            const size_t ob = ((size_t)(bh * 32 + kt_base + kt)) * 8192 + (size_t)d * 64;
            #pragma unroll
            for (int cc = 0; cc < 4; cc++) {
                const int cs = half * 4 + cc;
                const int kb = (cs ^ (d & 7)) << 3;
                *(short8*)&Vt[ob + cs * 8] = *(const short8*)&stage0[kt * 128 + d][kb];
            }
        }
    }
}

// ======================= weight prep + x cast, single dispatch =======================
// z=0..2: transpose+cast wq/wk/wv -> fp16 [n][k]; z=3: transpose+cast wo -> bf16;
// z=4: cast x -> fp16 (linear, no transpose). Blocks uniform in z.
__global__ __launch_bounds__(256) void prep_all(
    const float* __restrict__ wq, const float* __restrict__ wk,
    const float* __restrict__ wv, const float* __restrict__ wo,
    const float* __restrict__ x,
    unsigned short* __restrict__ wqF, unsigned short* __restrict__ wkF,
    unsigned short* __restrict__ wvF, unsigned short* __restrict__ woT,
    unsigned short* __restrict__ xf)
{
    __shared__ float tile[32][33];
    const int z = blockIdx.z;
    const int tx = threadIdx.x, ty = threadIdx.y;

    if (z == 4) {
        // cast x: 4096 blocks x 2048 elems
        const int blk = blockIdx.y * 64 + blockIdx.x;
        const size_t base = (size_t)blk * 2048 + (ty * 32 + tx) * 8;
        float4 a = *(const float4*)&x[base];
        float4 b = *(const float4*)&x[base + 4];
        ushort4 ha, hb;
        ha.x = fp16_bits(a.x); ha.y = fp16_bits(a.y); ha.z = fp16_bits(a.z); ha.w = fp16_bits(a.w);
        hb.x = fp16_bits(b.x); hb.y = fp16_bits(b.y); hb.z = fp16_bits(b.z); hb.w = fp16_bits(b.w);
        *(ushort4*)&xf[base] = ha;
        *(ushort4*)&xf[base + 4] = hb;
        return;
    }

    const float* __restrict__ W = (z == 0) ? wq : (z == 1) ? wk : (z == 2) ? wv : wo;
    const int k0 = blockIdx.y * 32, n0 = blockIdx.x * 32;
    #pragma unroll
    for (int i = 0; i < 4; i++)
        tile[ty + i * 8][tx] = W[(size_t)(k0 + ty + i * 8) * 2048 + n0 + tx];
    __syncthreads();
    if (z < 3) {
        unsigned short* __restrict__ t = (z == 0) ? wqF : (z == 1) ? wkF : wvF;
        #pragma unroll
        for (int i = 0; i < 4; i++)
            t[(size_t)(n0 + ty + i * 8) * 2048 + k0 + tx] = fp16_bits(tile[tx][ty + i * 8]);
    } else {
        #pragma unroll
        for (int i = 0; i < 4; i++)
            woT[(size_t)(n0 + ty + i * 8) * 2048 + k0 + tx] = bf16_bits(tile[tx][ty + i * 8]);
    }
}

// ======================= MFMA flash attention v14 (verbatim round-10) =======================
// v4's EXACT structure (512 threads = 8 waves, ATQ=256/32 rows per wave, ATK=64,
// double-buffered KV staging, prefetch at tile start, ONE barrier per tile,
// grid (8,32) = 256 blocks, 1 block/CU) with fp16 single-term Q/K/V/P.
// NO setprio / NO defer-max: schedule perturbations regressed 5/5 (v5-v9).
#define ATQ 256
#define ATK 64

__global__ __launch_bounds__(512, 1) void attn14(
    const unsigned short* __restrict__ Qf, const unsigned short* __restrict__ Kf,
    const unsigned short* __restrict__ Vt, __hip_bfloat16* __restrict__ AO)
{
    __shared__ unsigned short Ks[2][ATK * 128];    // 32 KB  [key][d'] (chunk ^= key&15)
    __shared__ unsigned short Vts[2][HD * 64];     // 32 KB  [d][key'] (chunk ^= d&7)
    __shared__ unsigned short Ps[ATQ * 64];        // 32 KB  P[row][key'] (chunk ^= row&7)

    const int tid  = threadIdx.x;
    const int w    = tid >> 6;        // 0..7
    const int lane = tid & 63;
    const int quad = lane >> 4;
    const int fm   = lane & 15;
    const int bh = blockIdx.y;
    const int b = bh >> 4, h = bh & 15;
    const int q0 = blockIdx.x * ATQ;

    const size_t hbase = (size_t)(b * NH + h) * SEQ;

    // ---- Q fragments (fp16); wave owns rows w*32..w*32+31 ----
    half8 qf[2][4];
    #pragma unroll
    for (int i = 0; i < 2; i++) {
        const size_t row = hbase + q0 + w * 32 + i * 16 + fm;
        #pragma unroll
        for (int kc = 0; kc < 4; kc++)
            qf[i][kc] = *(const half8*)&Qf[row * 128 + kc * 32 + quad * 8];
    }

    floatx4 oacc[2][8];
    #pragma unroll
    for (int i = 0; i < 2; i++)
        #pragma unroll
        for (int df = 0; df < 8; df++)
            oacc[i][df] = (floatx4){0.f, 0.f, 0.f, 0.f};
    float m_[2][4], l_[2][4];
    #pragma unroll
    for (int i = 0; i < 2; i++)
        #pragma unroll
        for (int r = 0; r < 4; r++) { m_[i][r] = -1e30f; l_[i][r] = 0.f; }

    const unsigned short* gk0  = Kf + hbase * 128;
    const unsigned short* gvt0 = Vt + (size_t)bh * 32 * 8192;

    // staging: 32 chunks of 1 KB (Ks 16, Vts 16); wave w -> chunks w*4..w*4+3
    const int ch0 = w * 4;

    // ---- prologue: stage tile 0 into buffer 0 ----
    #pragma unroll
    for (int c = 0; c < 4; c++) {
        const int ch = ch0 + c;
        const size_t go = (size_t)(ch & 15) * 512 + lane * 8;
        if (ch < 16) async_load16(gk0  + go, (char*)Ks[0]  + ch * 1024);
        else         async_load16(gvt0 + go, (char*)Vts[0] + (ch - 16) * 1024);
    }
    __syncthreads();   // drain: tile 0 staged

    for (int ktile = 0; ktile < SEQ / ATK; ktile++) {
        const int cur = ktile & 1;

        // ---- prefetch tile t+1 into other buffer (drained by end-of-tile barrier) ----
        if (ktile + 1 < SEQ / ATK) {
            const unsigned short* gk  = gk0  + (size_t)(ktile + 1) * ATK * 128;
            const unsigned short* gvt = gvt0 + (size_t)(ktile + 1) * 8192;
            #pragma unroll
            for (int c = 0; c < 4; c++) {
                const int ch = ch0 + c;
                const size_t go = (size_t)(ch & 15) * 512 + lane * 8;
                if (ch < 16) async_load16(gk  + go, (char*)Ks[1 - cur]  + ch * 1024);
                else         async_load16(gvt + go, (char*)Vts[1 - cur] + (ch - 16) * 1024);
            }
        }

        // ---- S = Q K^T (single-term fp16) from buffer cur ----
        floatx4 sacc[2][4];
        #pragma unroll
        for (int i = 0; i < 2; i++)
            #pragma unroll
            for (int jf = 0; jf < 4; jf++)
                sacc[i][jf] = (floatx4){0.f, 0.f, 0.f, 0.f};
        #pragma unroll
        for (int kc = 0; kc < 4; kc++)
            #pragma unroll
            for (int jf = 0; jf < 4; jf++) {
                const int koff = (jf * 16 + fm) * 128 + (((kc * 4 + quad) ^ fm) << 3);
                half8 k8 = *(const half8*)&Ks[cur][koff];
                #pragma unroll
                for (int i = 0; i < 2; i++)
                    sacc[i][jf] = __builtin_amdgcn_mfma_f32_16x16x32_f16(qf[i][kc], k8, sacc[i][jf], 0, 0, 0);
            }

        // ---- online softmax (registers) ----
        float alpha_[2][4];
        #pragma unroll
        for (int i = 0; i < 2; i++)
            #pragma unroll
            for (int r = 0; r < 4; r++) {
                float mx = fmaxf(fmaxf(sacc[i][0][r], sacc[i][1][r]),
                                 fmaxf(sacc[i][2][r], sacc[i][3][r]));
                mx = fmaxf(mx, __shfl_xor(mx, 1));
                mx = fmaxf(mx, __shfl_xor(mx, 2));
                mx = fmaxf(mx, __shfl_xor(mx, 4));
                mx = fmaxf(mx, __shfl_xor(mx, 8));
                const float mold = m_[i][r];
                const float mnew = fmaxf(mold, mx);
                const float al = __expf(mold - mnew);
                m_[i][r] = mnew;
                alpha_[i][r] = al;
                float rs = 0.f;
                #pragma unroll
                for (int jf = 0; jf < 4; jf++) {
                    float p = __expf(sacc[i][jf][r] - mnew);
                    sacc[i][jf][r] = p;
                    rs += p;
                }
                rs += __shfl_xor(rs, 1);
                rs += __shfl_xor(rs, 2);
                rs += __shfl_xor(rs, 4);
                rs += __shfl_xor(rs, 8);
                l_[i][r] = l_[i][r] * al + rs;
            }
        #pragma unroll
        for (int i = 0; i < 2; i++)
            #pragma unroll
            for (int df = 0; df < 8; df++)
                #pragma unroll
                for (int r = 0; r < 4; r++)
                    oacc[i][df][r] *= alpha_[i][r];

        // ---- P -> fp16 into Ps (own rows; wave-local ordering, no barrier) ----
        #pragma unroll
        for (int i = 0; i < 2; i++)
            #pragma unroll
            for (int jf = 0; jf < 4; jf++)
                #pragma unroll
                for (int r = 0; r < 4; r++) {
                    const int row = w * 32 + i * 16 + quad * 4 + r;
                    const int chunk = jf * 2 + (fm >> 3);
                    const int colp = ((chunk ^ (row & 7)) << 3) | (fm & 7);
                    Ps[row * 64 + colp] = fp16_bits(sacc[i][jf][r]);
                }

        // ---- O += P V from buffer cur (fp16) ----
        #pragma unroll
        for (int kc2 = 0; kc2 < 2; kc2++) {
            half8 ap[2];
            #pragma unroll
            for (int i = 0; i < 2; i++) {
                const int row = w * 32 + i * 16 + fm;
                ap[i] = *(const half8*)&Ps[row * 64 + (((kc2 * 4 + quad) ^ (row & 7)) << 3)];
            }
            #pragma unroll
            for (int df = 0; df < 8; df++) {
                const int d = df * 16 + fm;
                half8 bv = *(const half8*)&Vts[cur][d * 64 + (((kc2 * 4 + quad) ^ (d & 7)) << 3)];
                #pragma unroll
                for (int i = 0; i < 2; i++)
                    oacc[i][df] = __builtin_amdgcn_mfma_f32_16x16x32_f16(ap[i], bv, oacc[i][df], 0, 0, 0);
            }
        }

        // single barrier per tile: drains prefetch + protects buffer swap
        __syncthreads();
    }

    // ---- epilogue: AO bf16 [b,s,h,d] ----
    const size_t obase = ((size_t)b * SEQ * NH + h) * HD;
    const size_t rstr = (size_t)NH * HD;
    float linv[2][4];
    #pragma unroll
    for (int i = 0; i < 2; i++)
        #pragma unroll
        for (int r = 0; r < 4; r++) linv[i][r] = 1.0f / l_[i][r];
    #pragma unroll
    for (int i = 0; i < 2; i++)
        #pragma unroll
        for (int df = 0; df < 8; df++)
            #pragma unroll
            for (int r = 0; r < 4; r++) {
                const int row = q0 + w * 32 + i * 16 + quad * 4 + r;
                const int d = df * 16 + fm;
                AO[obase + (size_t)row * rstr + d] = __float2bfloat16(oacc[i][df][r] * linv[i][r]);
            }
}

// ======================= launch =======================
extern "C" void kernel_launch(void* const* d_in, const int* in_sizes, int n_in,
                              void* d_out, int out_size, void* d_ws, size_t ws_size,
                              hipStream_t stream) {
    const float* x  = (const float*)d_in[0];
    const float* wq = (const float*)d_in[1];
    const float* wk = (const float*)d_in[2];
    const float* wv = (const float*)d_in[3];
    const float* wo = (const float*)d_in[4];
    const float* q_scale = (const float*)d_in[5];
    const float* k_scale = (const float*)d_in[6];
    float* out = (float*)d_out;

    const size_t T = (size_t)BATCH * SEQ * NH * HD;   // 8388608
    const size_t W = (size_t)EMB * NH * HD;           // 4194304

    unsigned short* xf   = (unsigned short*)d_ws;     // fp16 x
    unsigned short* aob  = xf + T;                    // bf16 attn out
    unsigned short* Qf   = aob + T;                   // fp16 Q (head-major)
    unsigned short* Kf   = Qf + T;                    // fp16 K (head-major, swizzled)
    unsigned short* Vtb  = Kf + T;                    // fp16 Vt tiles
    unsigned short* wqF  = Vtb + T;                   // fp16 [n][k]
    unsigned short* wkF  = wqF + W;
    unsigned short* wvF  = wkF + W;
    unsigned short* woT  = wvF + W;                   // bf16 [n][k]

    const int M = BATCH * SEQ;   // 4096
    const int N = NH * HD;       // 2048
    const int K = EMB;           // 2048

    // weight transposes (wq/wk/wv->fp16, wo->bf16) + x->fp16 cast, one dispatch
    prep_all<<<dim3(64, 64, 5), dim3(32, 8), 0, stream>>>(
        wq, wk, wv, wo, x, wqF, wkF, wvF, woT, xf);

    // merged Q/K/V projections (z=0..2) sharing A panels in L2;
    // z<2 -> RMSNorm+relayout epilogue, z=2 -> Vt-transpose epilogue
    gemm_qkv<<<dim3(N / GT, M / GT, 3), 256, 0, stream>>>(
        xf, wqF, wkF, wvF, q_scale, k_scale, Qf, Kf, Vtb, K);

    attn14<<<dim3(SEQ / ATQ, BATCH * NH), 512, 0, stream>>>(Qf, Kf, Vtb, (__hip_bfloat16*)aob);

    gemm_bf16<<<dim3(EMB / GT, M / GT), 256, 0, stream>>>(aob, woT, out, M, EMB, NH * HD);
}

// Round 12
// 467.411 us; speedup vs baseline: 2.1263x; 1.0578x over previous
//
#include <hip/hip_runtime.h>
#include <hip/hip_bf16.h>
#include <math.h>

#define BATCH 2
#define SEQ   2048
#define EMB   2048
#define NH    16
#define HD    128

typedef __attribute__((ext_vector_type(8))) short short8;
typedef __attribute__((ext_vector_type(8))) _Float16 half8;
typedef __attribute__((ext_vector_type(4))) float floatx4;

__device__ inline void async_load16(const void* g, void* l) {
    __builtin_amdgcn_global_load_lds(
        (const __attribute__((address_space(1))) unsigned int*)g,
        (__attribute__((address_space(3))) unsigned int*)l, 16, 0, 0);
}

__device__ inline unsigned short bf16_bits(float f) {
    __hip_bfloat16 b = __float2bfloat16(f);
    return *(unsigned short*)&b;
}
__device__ inline unsigned short fp16_bits(float f) {
    _Float16 h = (_Float16)f;
    return *(unsigned short*)&h;
}

// ======================= plain bf16 MFMA GEMM (m97 structure) — out projection =======================
#define GT 128
#define GK 32

__global__ __launch_bounds__(256) void gemm_bf16(
    const unsigned short* __restrict__ A,
    const unsigned short* __restrict__ Bt,
    float* __restrict__ C, int M, int N, int K)
{
    __shared__ unsigned short As[GT * GK];
    __shared__ unsigned short Bs[GT * GK];

    const int tid  = threadIdx.x;
    const int w    = tid >> 6;
    const int lane = tid & 63;
    const int wr   = w >> 1, wc = w & 1;
    const int row0 = blockIdx.y * GT;
    const int col0 = blockIdx.x * GT;

    floatx4 acc[4][4];
    #pragma unroll
    for (int i = 0; i < 4; i++)
        #pragma unroll
        for (int j = 0; j < 4; j++)
            acc[i][j] = (floatx4){0.f, 0.f, 0.f, 0.f};

    const int srow  = lane >> 2;
    const int skoff = (lane & 3) * 8;
    const int fm = lane & 15;
    const int fk = (lane >> 4) * 8;

    for (int k0 = 0; k0 < K; k0 += GK) {
        #pragma unroll
        for (int t = 0; t < 2; t++) {
            const int c = w * 2 + t;
            async_load16(A  + (size_t)(row0 + c * 16 + srow) * K + k0 + skoff, (char*)As + c * 1024);
            async_load16(Bt + (size_t)(col0 + c * 16 + srow) * K + k0 + skoff, (char*)Bs + c * 1024);
        }
        __syncthreads();

        short8 af[4], bf[4];
        #pragma unroll
        for (int i = 0; i < 4; i++) {
            af[i] = *(const short8*)&As[(wr * 64 + i * 16 + fm) * GK + fk];
            bf[i] = *(const short8*)&Bs[(wc * 64 + i * 16 + fm) * GK + fk];
        }
        #pragma unroll
        for (int i = 0; i < 4; i++)
            #pragma unroll
            for (int j = 0; j < 4; j++)
                acc[i][j] = __builtin_amdgcn_mfma_f32_16x16x32_bf16(af[i], bf[j], acc[i][j], 0, 0, 0);
        __syncthreads();
    }

    const int quad = lane >> 4;
    #pragma unroll
    for (int i = 0; i < 4; i++)
        #pragma unroll
        for (int j = 0; j < 4; j++) {
            const size_t base = (size_t)(row0 + wr * 64 + i * 16 + quad * 4) * N
                              + col0 + wc * 64 + j * 16 + fm;
            #pragma unroll
            for (int r = 0; r < 4; r++)
                C[base + (size_t)r * N] = acc[i][j][r];
        }
}

// ======================= fused Q+K projection: ONE block, shared A staging =======================
// 512 threads = 8 waves: waves 0-3 compute the Q-tile (Bq), waves 4-7 the K-tile (Bk),
// from ONE shared A staging per K-step (24 KB staged for 2 output tiles -> barrier
// drain amortized 2x vs separate blocks). LDS 26 KB, ~90 VGPR -> 2 blocks/CU
// (cross-block overlap preserved; v10's bf16 variant failed only on its 49 KB LDS).
// XCD 8x8-chunk swizzle: L&7 selects an 8y x 8x block chunk -> A-panels fetched by
// one XCD instead of eight. Epilogue: per-half RMSNorm + relayout (fp16 out).
__global__ __launch_bounds__(512) void gemm_qk_fused(
    const unsigned short* __restrict__ A,
    const unsigned short* __restrict__ Bq, const unsigned short* __restrict__ Bk,
    const float* __restrict__ q_scale, const float* __restrict__ k_scale,
    unsigned short* __restrict__ Qf, unsigned short* __restrict__ Kf, int K)
{
    __shared__ unsigned short As[GT * GK];    // 8 KB (shared by both halves)
    __shared__ unsigned short BsQ[GT * GK];   // 8 KB
    __shared__ unsigned short BsK[GT * GK];   // 8 KB
    __shared__ float ws2[2][2][GT];           // 2 KB

    const int tid  = threadIdx.x;
    const int w    = tid >> 6;          // 0..7
    const int lane = tid & 63;
    const int half = w >> 2;            // 0 = Q, 1 = K
    const int wq   = w & 3;
    const int wr   = wq >> 1, wc = wq & 1;

    // XCD-chunk swizzle (hw xcd = linear % 8): xcd owns an 8x8 block tile
    const int L   = blockIdx.x;         // 0..511
    const int xcd = L & 7;
    const int idx = L >> 3;             // 0..63
    const int bx  = (xcd & 1) * 8 + (idx & 7);    // 0..15
    const int by  = (xcd >> 1) * 8 + (idx >> 3);  // 0..31
    const int row0 = by * GT;
    const int col0 = bx * GT;

    floatx4 acc[4][4];
    #pragma unroll
    for (int i = 0; i < 4; i++)
        #pragma unroll
        for (int j = 0; j < 4; j++)
            acc[i][j] = (floatx4){0.f, 0.f, 0.f, 0.f};

    const int srow  = lane >> 2;
    const int skoff = (lane & 3) * 8;
    const int fm = lane & 15;
    const int fk = (lane >> 4) * 8;

    for (int k0 = 0; k0 < K; k0 += GK) {
        // 24 chunks of 1 KB (As 8, BsQ 8, BsK 8); wave w -> chunks w*3..w*3+2
        #pragma unroll
        for (int c = 0; c < 3; c++) {
            const int ch  = w * 3 + c;          // 0..23
            const int sub = ch & 7;
            const int base = (ch < 8) ? row0 : col0;
            const size_t off = (size_t)(base + sub * 16 + srow) * K + k0 + skoff;
            if (ch < 8)       async_load16(A  + off, (char*)As  + sub * 1024);
            else if (ch < 16) async_load16(Bq + off, (char*)BsQ + sub * 1024);
            else              async_load16(Bk + off, (char*)BsK + sub * 1024);
        }
        __syncthreads();

        const unsigned short* __restrict__ Bs = half ? BsK : BsQ;
        half8 af[4], bf[4];
        #pragma unroll
        for (int i = 0; i < 4; i++) {
            af[i] = *(const half8*)&As[(wr * 64 + i * 16 + fm) * GK + fk];
            bf[i] = *(const half8*)&Bs[(wc * 64 + i * 16 + fm) * GK + fk];
        }
        #pragma unroll
        for (int i = 0; i < 4; i++)
            #pragma unroll
            for (int j = 0; j < 4; j++)
                acc[i][j] = __builtin_amdgcn_mfma_f32_16x16x32_f16(af[i], bf[j], acc[i][j], 0, 0, 0);
        __syncthreads();
    }

    // ---- fused epilogue: per-half RMSNorm + relayout (fp16 out) ----
    const int quad = lane >> 4;
    const float* __restrict__ scale = half ? k_scale : q_scale;
    unsigned short* __restrict__ o = half ? Kf : Qf;
    const int hh = col0 >> 7;   // head index (GT == HD)

    float sq[4][4];
    #pragma unroll
    for (int i = 0; i < 4; i++)
        #pragma unroll
        for (int r = 0; r < 4; r++) {
            float s2 = 0.f;
            #pragma unroll
            for (int j = 0; j < 4; j++) s2 += acc[i][j][r] * acc[i][j][r];
            s2 += __shfl_xor(s2, 1);
            s2 += __shfl_xor(s2, 2);
            s2 += __shfl_xor(s2, 4);
            s2 += __shfl_xor(s2, 8);
            sq[i][r] = s2;
        }
    if (fm == 0) {
        #pragma unroll
        for (int i = 0; i < 4; i++)
            #pragma unroll
            for (int r = 0; r < 4; r++)
                ws2[half][wc][wr * 64 + i * 16 + quad * 4 + r] = sq[i][r];
    }
    __syncthreads();

    float scv[4];
    #pragma unroll
    for (int j = 0; j < 4; j++) scv[j] = scale[wc * 64 + j * 16 + fm];

    #pragma unroll
    for (int i = 0; i < 4; i++)
        #pragma unroll
        for (int r = 0; r < 4; r++) {
            const int lrow = wr * 64 + i * 16 + quad * 4 + r;
            const int row  = row0 + lrow;            // global m = b*SEQ + s
            const int bb = row >> 11, s = row & 2047;
            const float inv = rsqrtf((ws2[half][0][lrow] + ws2[half][1][lrow]) * (1.0f / HD) + 1e-6f);
            const size_t ob = ((size_t)(bb * NH + hh) * SEQ + s) * 128;
            #pragma unroll
            for (int j = 0; j < 4; j++) {
                const int d = wc * 64 + j * 16 + fm;
                const float val = acc[i][j][r] * inv * scv[j];
                const int dd = half ? ((((d >> 3) ^ (s & 15)) << 3) | (d & 7)) : d;
                o[ob + dd] = fp16_bits(val);
            }
        }
}

// ======================= fp16 V projection GEMM + fused Vt epilogue (fp16 out) =======================
__global__ __launch_bounds__(256) void gemm_v_vt(
    const unsigned short* __restrict__ A,
    const unsigned short* __restrict__ Bt,
    unsigned short* __restrict__ Vt, int K)
{
    __shared__ char smem[2 * 128 * 72 * 2] __attribute__((aligned(16)));  // 36 KB
    unsigned short* As = (unsigned short*)smem;                // 8 KB (K-loop)
    unsigned short* Bs = (unsigned short*)(smem + 8192);       // 8 KB (K-loop)
    typedef unsigned short stage_row[72];
    stage_row* stage0 = (stage_row*)smem;                      // [2][128][72] (epilogue)

    const int tid  = threadIdx.x;
    const int w    = tid >> 6;
    const int lane = tid & 63;
    const int wr   = w >> 1, wc = w & 1;
    const int row0 = blockIdx.y * GT;
    const int col0 = blockIdx.x * GT;

    floatx4 acc[4][4];
    #pragma unroll
    for (int i = 0; i < 4; i++)
        #pragma unroll
        for (int j = 0; j < 4; j++)
            acc[i][j] = (floatx4){0.f, 0.f, 0.f, 0.f};

    const int srow  = lane >> 2;
    const int skoff = (lane & 3) * 8;
    const int fm = lane & 15;
    const int fk = (lane >> 4) * 8;

    for (int k0 = 0; k0 < K; k0 += GK) {
        #pragma unroll
        for (int t = 0; t < 2; t++) {
            const int c = w * 2 + t;
            async_load16(A  + (size_t)(row0 + c * 16 + srow) * K + k0 + skoff, (char*)As + c * 1024);
            async_load16(Bt + (size_t)(col0 + c * 16 + srow) * K + k0 + skoff, (char*)Bs + c * 1024);
        }
        __syncthreads();

        half8 af[4], bf[4];
        #pragma unroll
        for (int i = 0; i < 4; i++) {
            af[i] = *(const half8*)&As[(wr * 64 + i * 16 + fm) * GK + fk];
            bf[i] = *(const half8*)&Bs[(wc * 64 + i * 16 + fm) * GK + fk];
        }
        #pragma unroll
        for (int i = 0; i < 4; i++)
            #pragma unroll
            for (int j = 0; j < 4; j++)
                acc[i][j] = __builtin_amdgcn_mfma_f32_16x16x32_f16(af[i], bf[j], acc[i][j], 0, 0, 0);
        __syncthreads();   // also makes As/Bs dead -> stage aliasing safe
    }

    // ---- fused epilogue: transpose to Vt layout (fp16) ----
    const int quad = lane >> 4;
    const int b  = row0 >> 11;            // batch (128 | 2048, no straddle)
    const int h  = col0 >> 7;             // head (GT == HD)
    const int bh = b * NH + h;
    const int kt_base = (row0 & 2047) >> 6;

    #pragma unroll
    for (int i = 0; i < 4; i++)
        #pragma unroll
        for (int r = 0; r < 4; r++) {
            const int key = i * 16 + quad * 4 + r;           // 0..63
            #pragma unroll
            for (int j = 0; j < 4; j++) {
                const int d = wc * 64 + j * 16 + fm;
                stage0[wr * 128 + d][key] = fp16_bits(acc[i][j][r]);
            }
        }
    __syncthreads();

    const int d = tid >> 1, half = tid & 1;
    #pragma unroll
    for (int kt = 0; kt < 2; kt++) {
        const size_t ob = ((size_t)(bh * 32 + kt_base + kt)) * 8192 + (size_t)d * 64;
        #pragma unroll
        for (int cc = 0; cc < 4; cc++) {
            const int cs = half * 4 + cc;
            const int kb = (cs ^ (d & 7)) << 3;
            *(short8*)&Vt[ob + cs * 8] = *(const short8*)&stage0[kt * 128 + d][kb];
        }
    }
}

// ======================= weight prep + x cast, single dispatch =======================
__global__ __launch_bounds__(256) void prep_all(
    const float* __restrict__ wq, const float* __restrict__ wk,
    const float* __restrict__ wv, const float* __restrict__ wo,
    const float* __restrict__ x,
    unsigned short* __restrict__ wqF, unsigned short* __restrict__ wkF,
    unsigned short* __restrict__ wvF, unsigned short* __restrict__ woT,
    unsigned short* __restrict__ xf)
{
    __shared__ float tile[32][33];
    const int z = blockIdx.z;
    const int tx = threadIdx.x, ty = threadIdx.y;

    if (z == 4) {
        const int blk = blockIdx.y * 64 + blockIdx.x;
        const size_t base = (size_t)blk * 2048 + (ty * 32 + tx) * 8;
        float4 a = *(const float4*)&x[base];
        float4 b = *(const float4*)&x[base + 4];
        ushort4 ha, hb;
        ha.x = fp16_bits(a.x); ha.y = fp16_bits(a.y); ha.z = fp16_bits(a.z); ha.w = fp16_bits(a.w);
        hb.x = fp16_bits(b.x); hb.y = fp16_bits(b.y); hb.z = fp16_bits(b.z); hb.w = fp16_bits(b.w);
        *(ushort4*)&xf[base] = ha;
        *(ushort4*)&xf[base + 4] = hb;
        return;
    }

    const float* __restrict__ W = (z == 0) ? wq : (z == 1) ? wk : (z == 2) ? wv : wo;
    const int k0 = blockIdx.y * 32, n0 = blockIdx.x * 32;
    #pragma unroll
    for (int i = 0; i < 4; i++)
        tile[ty + i * 8][tx] = W[(size_t)(k0 + ty + i * 8) * 2048 + n0 + tx];
    __syncthreads();
    if (z < 3) {
        unsigned short* __restrict__ t = (z == 0) ? wqF : (z == 1) ? wkF : wvF;
        #pragma unroll
        for (int i = 0; i < 4; i++)
            t[(size_t)(n0 + ty + i * 8) * 2048 + k0 + tx] = fp16_bits(tile[tx][ty + i * 8]);
    } else {
        #pragma unroll
        for (int i = 0; i < 4; i++)
            woT[(size_t)(n0 + ty + i * 8) * 2048 + k0 + tx] = bf16_bits(tile[tx][ty + i * 8]);
    }
}

// ======================= MFMA flash attention v14 (verbatim) =======================
// v4's EXACT structure (512 threads = 8 waves, ATQ=256/32 rows per wave, ATK=64,
// double-buffered KV staging, prefetch at tile start, ONE barrier per tile,
// grid (8,32) = 256 blocks, 1 block/CU) with fp16 single-term Q/K/V/P.
// NO setprio / NO defer-max: schedule perturbations regressed 5/5 (v5-v9).
#define ATQ 256
#define ATK 64

__global__ __launch_bounds__(512, 1) void attn14(
    const unsigned short* __restrict__ Qf, const unsigned short* __restrict__ Kf,
    const unsigned short* __restrict__ Vt, __hip_bfloat16* __restrict__ AO)
{
    __shared__ unsigned short Ks[2][ATK * 128];    // 32 KB  [key][d'] (chunk ^= key&15)
    __shared__ unsigned short Vts[2][HD * 64];     // 32 KB  [d][key'] (chunk ^= d&7)
    __shared__ unsigned short Ps[ATQ * 64];        // 32 KB  P[row][key'] (chunk ^= row&7)

    const int tid  = threadIdx.x;
    const int w    = tid >> 6;        // 0..7
    const int lane = tid & 63;
    const int quad = lane >> 4;
    const int fm   = lane & 15;
    const int bh = blockIdx.y;
    const int b = bh >> 4, h = bh & 15;
    const int q0 = blockIdx.x * ATQ;

    const size_t hbase = (size_t)(b * NH + h) * SEQ;

    // ---- Q fragments (fp16); wave owns rows w*32..w*32+31 ----
    half8 qf[2][4];
    #pragma unroll
    for (int i = 0; i < 2; i++) {
        const size_t row = hbase + q0 + w * 32 + i * 16 + fm;
        #pragma unroll
        for (int kc = 0; kc < 4; kc++)
            qf[i][kc] = *(const half8*)&Qf[row * 128 + kc * 32 + quad * 8];
    }

    floatx4 oacc[2][8];
    #pragma unroll
    for (int i = 0; i < 2; i++)
        #pragma unroll
        for (int df = 0; df < 8; df++)
            oacc[i][df] = (floatx4){0.f, 0.f, 0.f, 0.f};
    float m_[2][4], l_[2][4];
    #pragma unroll
    for (int i = 0; i < 2; i++)
        #pragma unroll
        for (int r = 0; r < 4; r++) { m_[i][r] = -1e30f; l_[i][r] = 0.f; }

    const unsigned short* gk0  = Kf + hbase * 128;
    const unsigned short* gvt0 = Vt + (size_t)bh * 32 * 8192;

    // staging: 32 chunks of 1 KB (Ks 16, Vts 16); wave w -> chunks w*4..w*4+3
    const int ch0 = w * 4;

    // ---- prologue: stage tile 0 into buffer 0 ----
    #pragma unroll
    for (int c = 0; c < 4; c++) {
        const int ch = ch0 + c;
        const size_t go = (size_t)(ch & 15) * 512 + lane * 8;
        if (ch < 16) async_load16(gk0  + go, (char*)Ks[0]  + ch * 1024);
        else         async_load16(gvt0 + go, (char*)Vts[0] + (ch - 16) * 1024);
    }
    __syncthreads();   // drain: tile 0 staged

    for (int ktile = 0; ktile < SEQ / ATK; ktile++) {
        const int cur = ktile & 1;

        // ---- prefetch tile t+1 into other buffer (drained by end-of-tile barrier) ----
        if (ktile + 1 < SEQ / ATK) {
            const unsigned short* gk  = gk0  + (size_t)(ktile + 1) * ATK * 128;
            const unsigned short* gvt = gvt0 + (size_t)(ktile + 1) * 8192;
            #pragma unroll
            for (int c = 0; c < 4; c++) {
                const int ch = ch0 + c;
                const size_t go = (size_t)(ch & 15) * 512 + lane * 8;
                if (ch < 16) async_load16(gk  + go, (char*)Ks[1 - cur]  + ch * 1024);
                else         async_load16(gvt + go, (char*)Vts[1 - cur] + (ch - 16) * 1024);
            }
        }

        // ---- S = Q K^T (single-term fp16) from buffer cur ----
        floatx4 sacc[2][4];
        #pragma unroll
        for (int i = 0; i < 2; i++)
            #pragma unroll
            for (int jf = 0; jf < 4; jf++)
                sacc[i][jf] = (floatx4){0.f, 0.f, 0.f, 0.f};
        #pragma unroll
        for (int kc = 0; kc < 4; kc++)
            #pragma unroll
            for (int jf = 0; jf < 4; jf++) {
                const int koff = (jf * 16 + fm) * 128 + (((kc * 4 + quad) ^ fm) << 3);
                half8 k8 = *(const half8*)&Ks[cur][koff];
                #pragma unroll
                for (int i = 0; i < 2; i++)
                    sacc[i][jf] = __builtin_amdgcn_mfma_f32_16x16x32_f16(qf[i][kc], k8, sacc[i][jf], 0, 0, 0);
            }

        // ---- online softmax (registers) ----
        float alpha_[2][4];
        #pragma unroll
        for (int i = 0; i < 2; i++)
            #pragma unroll
            for (int r = 0; r < 4; r++) {
                float mx = fmaxf(fmaxf(sacc[i][0][r], sacc[i][1][r]),
                                 fmaxf(sacc[i][2][r], sacc[i][3][r]));
                mx = fmaxf(mx, __shfl_xor(mx, 1));
                mx = fmaxf(mx, __shfl_xor(mx, 2));
                mx = fmaxf(mx, __shfl_xor(mx, 4));
                mx = fmaxf(mx, __shfl_xor(mx, 8));
                const float mold = m_[i][r];
                const float mnew = fmaxf(mold, mx);
                const float al = __expf(mold - mnew);
                m_[i][r] = mnew;
                alpha_[i][r] = al;
                float rs = 0.f;
                #pragma unroll
                for (int jf = 0; jf < 4; jf++) {
                    float p = __expf(sacc[i][jf][r] - mnew);
                    sacc[i][jf][r] = p;
                    rs += p;
                }
                rs += __shfl_xor(rs, 1);
                rs += __shfl_xor(rs, 2);
                rs += __shfl_xor(rs, 4);
                rs += __shfl_xor(rs, 8);
                l_[i][r] = l_[i][r] * al + rs;
            }
        #pragma unroll
        for (int i = 0; i < 2; i++)
            #pragma unroll
            for (int df = 0; df < 8; df++)
                #pragma unroll
                for (int r = 0; r < 4; r++)
                    oacc[i][df][r] *= alpha_[i][r];

        // ---- P -> fp16 into Ps (own rows; wave-local ordering, no barrier) ----
        #pragma unroll
        for (int i = 0; i < 2; i++)
            #pragma unroll
            for (int jf = 0; jf < 4; jf++)
                #pragma unroll
                for (int r = 0; r < 4; r++) {
                    const int row = w * 32 + i * 16 + quad * 4 + r;
                    const int chunk = jf * 2 + (fm >> 3);
                    const int colp = ((chunk ^ (row & 7)) << 3) | (fm & 7);
                    Ps[row * 64 + colp] = fp16_bits(sacc[i][jf][r]);
                }

        // ---- O += P V from buffer cur (fp16) ----
        #pragma unroll
        for (int kc2 = 0; kc2 < 2; kc2++) {
            half8 ap[2];
            #pragma unroll
            for (int i = 0; i < 2; i++) {
                const int row = w * 32 + i * 16 + fm;
                ap[i] = *(const half8*)&Ps[row * 64 + (((kc2 * 4 + quad) ^ (row & 7)) << 3)];
            }
            #pragma unroll
            for (int df = 0; df < 8; df++) {
                const int d = df * 16 + fm;
                half8 bv = *(const half8*)&Vts[cur][d * 64 + (((kc2 * 4 + quad) ^ (d & 7)) << 3)];
                #pragma unroll
                for (int i = 0; i < 2; i++)
                    oacc[i][df] = __builtin_amdgcn_mfma_f32_16x16x32_f16(ap[i], bv, oacc[i][df], 0, 0, 0);
            }
        }

        // single barrier per tile: drains prefetch + protects buffer swap
        __syncthreads();
    }

    // ---- epilogue: AO bf16 [b,s,h,d] ----
    const size_t obase = ((size_t)b * SEQ * NH + h) * HD;
    const size_t rstr = (size_t)NH * HD;
    float linv[2][4];
    #pragma unroll
    for (int i = 0; i < 2; i++)
        #pragma unroll
        for (int r = 0; r < 4; r++) linv[i][r] = 1.0f / l_[i][r];
    #pragma unroll
    for (int i = 0; i < 2; i++)
        #pragma unroll
        for (int df = 0; df < 8; df++)
            #pragma unroll
            for (int r = 0; r < 4; r++) {
                const int row = q0 + w * 32 + i * 16 + quad * 4 + r;
                const int d = df * 16 + fm;
                AO[obase + (size_t)row * rstr + d] = __float2bfloat16(oacc[i][df][r] * linv[i][r]);
            }
}

// ======================= launch =======================
extern "C" void kernel_launch(void* const* d_in, const int* in_sizes, int n_in,
                              void* d_out, int out_size, void* d_ws, size_t ws_size,
                              hipStream_t stream) {
    const float* x  = (const float*)d_in[0];
    const float* wq = (const float*)d_in[1];
    const float* wk = (const float*)d_in[2];
    const float* wv = (const float*)d_in[3];
    const float* wo = (const float*)d_in[4];
    const float* q_scale = (const float*)d_in[5];
    const float* k_scale = (const float*)d_in[6];
    float* out = (float*)d_out;

    const size_t T = (size_t)BATCH * SEQ * NH * HD;   // 8388608
    const size_t W = (size_t)EMB * NH * HD;           // 4194304

    unsigned short* xf   = (unsigned short*)d_ws;     // fp16 x
    unsigned short* aob  = xf + T;                    // bf16 attn out
    unsigned short* Qf   = aob + T;                   // fp16 Q (head-major)
    unsigned short* Kf   = Qf + T;                    // fp16 K (head-major, swizzled)
    unsigned short* Vtb  = Kf + T;                    // fp16 Vt tiles
    unsigned short* wqF  = Vtb + T;                   // fp16 [n][k]
    unsigned short* wkF  = wqF + W;
    unsigned short* wvF  = wkF + W;
    unsigned short* woT  = wvF + W;                   // bf16 [n][k]

    const int M = BATCH * SEQ;   // 4096
    const int N = NH * HD;       // 2048
    const int K = EMB;           // 2048

    // weight transposes (wq/wk/wv->fp16, wo->bf16) + x->fp16 cast, one dispatch
    prep_all<<<dim3(64, 64, 5), dim3(32, 8), 0, stream>>>(
        wq, wk, wv, wo, x, wqF, wkF, wvF, woT, xf);

    // fused Q+K projection: one block computes both tiles from shared A staging
    gemm_qk_fused<<<512, 512, 0, stream>>>(
        xf, wqF, wkF, q_scale, k_scale, Qf, Kf, K);
    // V projection with fused Vt-transpose epilogue
    gemm_v_vt<<<dim3(N / GT, M / GT), 256, 0, stream>>>(xf, wvF, Vtb, K);

    attn14<<<dim3(SEQ / ATQ, BATCH * NH), 512, 0, stream>>>(Qf, Kf, Vtb, (__hip_bfloat16*)aob);

    gemm_bf16<<<dim3(EMB / GT, M / GT), 256, 0, stream>>>(aob, woT, out, M, EMB, NH * HD);
}